// Round 2
// baseline (854.995 us; speedup 1.0000x reference)
//
#include <hip/hip_runtime.h>

#define N_NODES 50000
#define N_EDGES 800000
#define D 128
#define BN_EPS 1e-5f

// ---------------- workspace layout (bytes) ----------------
// cnt_in  @ 0        cnt_out @ 262144   row_ptr @ 524288   cursor @ 786432
// rin     @ 1048576  rout    @ 1310720  bn_part @ 1572864  scsh   @ 1576960
// csr_src @ 1581056 (3.2MB)  hwb(bf16 packed) @ 4800000 (12.8MB)

__global__ void zero_kernel(int* __restrict__ a, int* __restrict__ b, float* __restrict__ c) {
    int i = blockIdx.x * blockDim.x + threadIdx.x;
    if (i < N_NODES) { a[i] = 0; b[i] = 0; }
    if (i < 256) c[i] = 0.f;
}

__global__ void deg_kernel(const int* __restrict__ src, const int* __restrict__ dst,
                           int* __restrict__ cnt_out, int* __restrict__ cnt_in) {
    int e = blockIdx.x * blockDim.x + threadIdx.x;
    if (e < N_EDGES) {
        atomicAdd(&cnt_out[src[e]], 1);
        atomicAdd(&cnt_in[dst[e]], 1);
    }
}

// single-block exclusive scan of cnt_in -> row_ptr (+cursor copy), plus rsqrt norms
__global__ __launch_bounds__(1024) void scan_kernel(
        const int* __restrict__ cnt_in, const int* __restrict__ cnt_out,
        int* __restrict__ row_ptr, int* __restrict__ cursor,
        float* __restrict__ rin, float* __restrict__ rout) {
    __shared__ int part[1024];
    int t = threadIdx.x;
    const int C = (N_NODES + 1023) / 1024;   // 49
    int begin = t * C;
    int end = begin + C; if (end > N_NODES) end = N_NODES; if (begin > N_NODES) begin = N_NODES;
    int s = 0;
    for (int i = begin; i < end; i++) s += cnt_in[i];
    part[t] = s;
    __syncthreads();
    for (int off = 1; off < 1024; off <<= 1) {
        int v = (t >= off) ? part[t - off] : 0;
        __syncthreads();
        part[t] += v;
        __syncthreads();
    }
    int run = (t == 0) ? 0 : part[t - 1];
    for (int i = begin; i < end; i++) {
        row_ptr[i] = run;
        cursor[i]  = run;
        int cv = cnt_in[i];
        rin[i] = rsqrtf((float)(cv > 1 ? cv : 1));
        run += cv;
    }
    if (t == 1023) row_ptr[N_NODES] = run;
    for (int i = t; i < N_NODES; i += 1024) {
        int cv = cnt_out[i];
        rout[i] = rsqrtf((float)(cv > 1 ? cv : 1));
    }
}

__global__ void fill_kernel(const int* __restrict__ src, const int* __restrict__ dst,
                            int* __restrict__ cursor, int* __restrict__ csr_src) {
    int e = blockIdx.x * blockDim.x + threadIdx.x;
    if (e < N_EDGES) {
        int d = dst[e];
        int p = atomicAdd(&cursor[d], 1);
        csr_src[p] = src[e];
    }
}

// Dual GEMM, coalesced. Block = 256 threads = 4 waves, tile = 64 rows.
// x tile staged in LDS (coalesced float4). lane = column pair (float2 accs),
// W/Wr read row-wise coalesced (original [k][c] layout). Per wave: 16 rows.
// Outputs: hwb = bf16x2-packed rout*(x@W)  [coalesced 4B/lane]
//          res = relu(x@Wr + br) -> d_out  [coalesced float2]
__global__ __launch_bounds__(256) void gemm_kernel(
        const float* __restrict__ x, const float* __restrict__ W,
        const float* __restrict__ Wr, const float* __restrict__ br,
        const float* __restrict__ rout, unsigned int* __restrict__ hwb,
        float* __restrict__ res) {
    __shared__ float xs[64 * D];
    int tid = threadIdx.x;
    int r0 = blockIdx.x * 64;
    const float4* xg = (const float4*)x;
    float4* xsv = (float4*)xs;
    int base4 = r0 * (D / 4);
    #pragma unroll
    for (int i = 0; i < 8; i++) {
        int idx = base4 + tid + 256 * i;
        xsv[tid + 256 * i] = (idx < N_NODES * (D / 4)) ? xg[idx] : make_float4(0.f, 0.f, 0.f, 0.f);
    }
    __syncthreads();
    int wid = tid >> 6, lane = tid & 63;
    int wrow0 = wid * 16;
    float2 acc[16], accr[16];
    #pragma unroll
    for (int r = 0; r < 16; r++) { acc[r] = make_float2(0.f, 0.f); accr[r] = make_float2(0.f, 0.f); }
    const float2* Wv  = (const float2*)W;
    const float2* Wrv = (const float2*)Wr;
    #pragma unroll 4
    for (int k = 0; k < D; k += 2) {
        float2 wa  = Wv[k * 64 + lane];
        float2 wb  = Wv[(k + 1) * 64 + lane];
        float2 wra = Wrv[k * 64 + lane];
        float2 wrb = Wrv[(k + 1) * 64 + lane];
        #pragma unroll
        for (int r = 0; r < 16; r++) {
            float2 xv = *(const float2*)&xs[(wrow0 + r) * D + k];  // wave-uniform -> LDS broadcast
            acc[r].x  += xv.x * wa.x;   acc[r].y  += xv.x * wa.y;
            acc[r].x  += xv.y * wb.x;   acc[r].y  += xv.y * wb.y;
            accr[r].x += xv.x * wra.x;  accr[r].y += xv.x * wra.y;
            accr[r].x += xv.y * wrb.x;  accr[r].y += xv.y * wrb.y;
        }
    }
    float2 brv = ((const float2*)br)[lane];
    #pragma unroll
    for (int r = 0; r < 16; r++) {
        int row = r0 + wrow0 + r;
        if (row < N_NODES) {
            float ro = rout[row];
            unsigned int u0 = __float_as_uint(acc[r].x * ro);
            unsigned int u1 = __float_as_uint(acc[r].y * ro);
            u0 += 0x7fffu + ((u0 >> 16) & 1u);            // RNE bf16
            u1 += 0x7fffu + ((u1 >> 16) & 1u);
            hwb[row * 64 + lane] = (u0 >> 16) | (u1 & 0xffff0000u);
            float2 rv;
            rv.x = fmaxf(accr[r].x + brv.x, 0.f);
            rv.y = fmaxf(accr[r].y + brv.y, 0.f);
            ((float2*)res)[row * 64 + lane] = rv;
        }
    }
}

__device__ __forceinline__ float bf_lo(unsigned int v) { return __uint_as_float(v << 16); }
__device__ __forceinline__ float bf_hi(unsigned int v) { return __uint_as_float(v & 0xffff0000u); }

// Per-dst aggregation over CSR (bf16 hw rows, 256B each = one coalesced dword/lane),
// 8-deep MLP unroll, fused bias/relu + residual + BN partial stats.
__global__ __launch_bounds__(256) void agg_kernel(
        const unsigned int* __restrict__ hwb, const int* __restrict__ row_ptr,
        const int* __restrict__ csr_src, const float* __restrict__ rin,
        const float* __restrict__ bias, float* __restrict__ y,
        float* __restrict__ bn_part) {
    int lane = threadIdx.x & 63;
    int wave = blockIdx.x * (blockDim.x >> 6) + (threadIdx.x >> 6);
    int nw = gridDim.x * (blockDim.x >> 6);
    float2 bv = ((const float2*)bias)[lane];
    float s10 = 0.f, s11 = 0.f, s20 = 0.f, s21 = 0.f;
    for (int n = wave; n < N_NODES; n += nw) {
        int e0 = row_ptr[n], e1 = row_ptr[n + 1];
        float a0 = 0.f, a1 = 0.f;
        for (int j0 = e0; j0 < e1; j0 += 64) {
            int cnt = e1 - j0; if (cnt > 64) cnt = 64;
            int myidx = (lane < cnt) ? csr_src[j0 + lane] : 0;
            int i = 0;
            for (; i + 8 <= cnt; i += 8) {
                unsigned int v0 = hwb[(size_t)__builtin_amdgcn_readlane(myidx, i + 0) * 64 + lane];
                unsigned int v1 = hwb[(size_t)__builtin_amdgcn_readlane(myidx, i + 1) * 64 + lane];
                unsigned int v2 = hwb[(size_t)__builtin_amdgcn_readlane(myidx, i + 2) * 64 + lane];
                unsigned int v3 = hwb[(size_t)__builtin_amdgcn_readlane(myidx, i + 3) * 64 + lane];
                unsigned int v4 = hwb[(size_t)__builtin_amdgcn_readlane(myidx, i + 4) * 64 + lane];
                unsigned int v5 = hwb[(size_t)__builtin_amdgcn_readlane(myidx, i + 5) * 64 + lane];
                unsigned int v6 = hwb[(size_t)__builtin_amdgcn_readlane(myidx, i + 6) * 64 + lane];
                unsigned int v7 = hwb[(size_t)__builtin_amdgcn_readlane(myidx, i + 7) * 64 + lane];
                a0 += bf_lo(v0) + bf_lo(v1) + bf_lo(v2) + bf_lo(v3)
                    + bf_lo(v4) + bf_lo(v5) + bf_lo(v6) + bf_lo(v7);
                a1 += bf_hi(v0) + bf_hi(v1) + bf_hi(v2) + bf_hi(v3)
                    + bf_hi(v4) + bf_hi(v5) + bf_hi(v6) + bf_hi(v7);
            }
            for (; i + 4 <= cnt; i += 4) {
                unsigned int v0 = hwb[(size_t)__builtin_amdgcn_readlane(myidx, i + 0) * 64 + lane];
                unsigned int v1 = hwb[(size_t)__builtin_amdgcn_readlane(myidx, i + 1) * 64 + lane];
                unsigned int v2 = hwb[(size_t)__builtin_amdgcn_readlane(myidx, i + 2) * 64 + lane];
                unsigned int v3 = hwb[(size_t)__builtin_amdgcn_readlane(myidx, i + 3) * 64 + lane];
                a0 += bf_lo(v0) + bf_lo(v1) + bf_lo(v2) + bf_lo(v3);
                a1 += bf_hi(v0) + bf_hi(v1) + bf_hi(v2) + bf_hi(v3);
            }
            for (; i < cnt; i++) {
                unsigned int v = hwb[(size_t)__builtin_amdgcn_readlane(myidx, i) * 64 + lane];
                a0 += bf_lo(v); a1 += bf_hi(v);
            }
        }
        float ri = rin[n];
        float2 rv = *((const float2*)(y + (size_t)n * D) + lane);   // residual (from gemm)
        float y0 = fmaxf(a0 * ri + bv.x, 0.f) + rv.x;
        float y1 = fmaxf(a1 * ri + bv.y, 0.f) + rv.y;
        *((float2*)(y + (size_t)n * D) + lane) = make_float2(y0, y1);
        s10 += y0; s11 += y1; s20 += y0 * y0; s21 += y1 * y1;
    }
    atomicAdd(&bn_part[2 * lane],           s10);
    atomicAdd(&bn_part[2 * lane + 1],       s11);
    atomicAdd(&bn_part[128 + 2 * lane],     s20);
    atomicAdd(&bn_part[128 + 2 * lane + 1], s21);
}

__global__ void bn_fin(const float* __restrict__ bn_part, const float* __restrict__ gamma,
                       const float* __restrict__ beta, float* __restrict__ scsh) {
    int c = threadIdx.x;
    if (c < D) {
        const float invN = 1.0f / (float)N_NODES;
        float mean = bn_part[c] * invN;
        float var  = bn_part[128 + c] * invN - mean * mean;
        float sc = gamma[c] * rsqrtf(var + BN_EPS);
        scsh[c] = sc;
        scsh[128 + c] = beta[c] - mean * sc;
    }
}

__global__ void norm_kernel(float* __restrict__ y, const float* __restrict__ scsh) {
    int i = blockIdx.x * blockDim.x + threadIdx.x;   // float2 index
    if (i < N_NODES * 64) {
        float2 v = ((float2*)y)[i];
        int c = (i & 63) * 2;
        v.x = v.x * scsh[c]     + scsh[128 + c];
        v.y = v.y * scsh[c + 1] + scsh[128 + c + 1];
        ((float2*)y)[i] = v;
    }
}

extern "C" void kernel_launch(void* const* d_in, const int* in_sizes, int n_in,
                              void* d_out, int out_size, void* d_ws, size_t ws_size,
                              hipStream_t stream) {
    const float* x     = (const float*)d_in[0];
    const int*   src   = (const int*)d_in[1];
    const int*   dst   = (const int*)d_in[2];
    const float* W     = (const float*)d_in[3];
    const float* b     = (const float*)d_in[4];
    const float* Wr    = (const float*)d_in[5];
    const float* br    = (const float*)d_in[6];
    const float* gamma = (const float*)d_in[7];
    const float* beta  = (const float*)d_in[8];
    float* out = (float*)d_out;

    char* ws = (char*)d_ws;
    int*   cnt_in  = (int*)(ws + 0);
    int*   cnt_out = (int*)(ws + 262144);
    int*   row_ptr = (int*)(ws + 524288);
    int*   cursor  = (int*)(ws + 786432);
    float* rin     = (float*)(ws + 1048576);
    float* rout    = (float*)(ws + 1310720);
    float* bn_part = (float*)(ws + 1572864);
    float* scsh    = (float*)(ws + 1576960);
    int*   csr_src = (int*)(ws + 1581056);
    unsigned int* hwb = (unsigned int*)(ws + 4800000);

    zero_kernel<<<(N_NODES + 255) / 256, 256, 0, stream>>>(cnt_in, cnt_out, bn_part);
    deg_kernel<<<(N_EDGES + 255) / 256, 256, 0, stream>>>(src, dst, cnt_out, cnt_in);
    scan_kernel<<<1, 1024, 0, stream>>>(cnt_in, cnt_out, row_ptr, cursor, rin, rout);
    fill_kernel<<<(N_EDGES + 255) / 256, 256, 0, stream>>>(src, dst, cursor, csr_src);
    gemm_kernel<<<(N_NODES + 63) / 64, 256, 0, stream>>>(x, W, Wr, br, rout, hwb, out);
    agg_kernel<<<2048, 256, 0, stream>>>(hwb, row_ptr, csr_src, rin, b, out, bn_part);
    bn_fin<<<1, 128, 0, stream>>>(bn_part, gamma, beta, scsh);
    norm_kernel<<<(N_NODES * 64) / 256, 256, 0, stream>>>(out, scsh);
}

// Round 3
// 472.176 us; speedup vs baseline: 1.8108x; 1.8108x over previous
//
#include <hip/hip_runtime.h>

#define N_NODES 50000
#define N_EDGES 800000
#define D 128
#define BN_EPS 1e-5f
#define AGG_BLOCKS 2048

// ---------------- workspace layout (bytes) ----------------
// cnt_in  @ 0        cnt_out @ 262144   row_ptr @ 524288   cursor @ 786432
// rin     @ 1048576  rout    @ 1310720  scsh    @ 1576960
// csr_src @ 1581056 (3.2MB)  hwb(bf16 packed) @ 4800000 (12.8MB)
// parts   @ 17600000 (2MB: [AGG_BLOCKS][256])

__global__ void zero_kernel(int* __restrict__ a, int* __restrict__ b) {
    int i = blockIdx.x * blockDim.x + threadIdx.x;
    if (i < 53248) { a[i] = 0; b[i] = 0; }   // zero past N so int4 scan reads are clean
}

__global__ void deg_kernel(const int* __restrict__ src, const int* __restrict__ dst,
                           int* __restrict__ cnt_out, int* __restrict__ cnt_in) {
    int e = blockIdx.x * blockDim.x + threadIdx.x;
    if (e < N_EDGES) {
        atomicAdd(&cnt_out[src[e]], 1);
        atomicAdd(&cnt_in[dst[e]], 1);
    }
}

// single-block exclusive scan of cnt_in -> row_ptr (+cursor copy), plus rsqrt norms
__global__ __launch_bounds__(1024) void scan_kernel(
        const int* __restrict__ cnt_in, const int* __restrict__ cnt_out,
        int* __restrict__ row_ptr, int* __restrict__ cursor,
        float* __restrict__ rin, float* __restrict__ rout) {
    __shared__ int part[1024];
    int t = threadIdx.x;
    const int C = 52;                       // 1024*52 = 53248 >= N, 16B-aligned chunks
    int begin = t * C;
    int s = 0;
    const int4* p = (const int4*)(cnt_in + begin);
    #pragma unroll
    for (int j = 0; j < 13; j++) { int4 v = p[j]; s += v.x + v.y + v.z + v.w; }
    part[t] = s;
    __syncthreads();
    for (int off = 1; off < 1024; off <<= 1) {
        int v = (t >= off) ? part[t - off] : 0;
        __syncthreads();
        part[t] += v;
        __syncthreads();
    }
    int run = (t == 0) ? 0 : part[t - 1];
    int end = begin + C; if (end > N_NODES) end = N_NODES;
    for (int i = begin; i < end; i++) {
        row_ptr[i] = run;
        cursor[i]  = run;
        int cv = cnt_in[i];
        rin[i] = rsqrtf((float)(cv > 1 ? cv : 1));
        run += cv;
    }
    if (t == 1023) row_ptr[N_NODES] = run;
    for (int i = t; i < N_NODES; i += 1024) {
        int cv = cnt_out[i];
        rout[i] = rsqrtf((float)(cv > 1 ? cv : 1));
    }
}

__global__ void fill_kernel(const int* __restrict__ src, const int* __restrict__ dst,
                            int* __restrict__ cursor, int* __restrict__ csr_src) {
    int e = blockIdx.x * blockDim.x + threadIdx.x;
    if (e < N_EDGES) {
        int d = dst[e];
        int p = atomicAdd(&cursor[d], 1);
        csr_src[p] = src[e];
    }
}

// Dual GEMM, coalesced. Block = 256 threads = 4 waves, tile = 64 rows.
__global__ __launch_bounds__(256) void gemm_kernel(
        const float* __restrict__ x, const float* __restrict__ W,
        const float* __restrict__ Wr, const float* __restrict__ br,
        const float* __restrict__ rout, unsigned int* __restrict__ hwb,
        float* __restrict__ res) {
    __shared__ float xs[64 * D];
    int tid = threadIdx.x;
    int r0 = blockIdx.x * 64;
    const float4* xg = (const float4*)x;
    float4* xsv = (float4*)xs;
    int base4 = r0 * (D / 4);
    #pragma unroll
    for (int i = 0; i < 8; i++) {
        int idx = base4 + tid + 256 * i;
        xsv[tid + 256 * i] = (idx < N_NODES * (D / 4)) ? xg[idx] : make_float4(0.f, 0.f, 0.f, 0.f);
    }
    __syncthreads();
    int wid = tid >> 6, lane = tid & 63;
    int wrow0 = wid * 16;
    float2 acc[16], accr[16];
    #pragma unroll
    for (int r = 0; r < 16; r++) { acc[r] = make_float2(0.f, 0.f); accr[r] = make_float2(0.f, 0.f); }
    const float2* Wv  = (const float2*)W;
    const float2* Wrv = (const float2*)Wr;
    #pragma unroll 4
    for (int k = 0; k < D; k += 2) {
        float2 wa  = Wv[k * 64 + lane];
        float2 wb  = Wv[(k + 1) * 64 + lane];
        float2 wra = Wrv[k * 64 + lane];
        float2 wrb = Wrv[(k + 1) * 64 + lane];
        #pragma unroll
        for (int r = 0; r < 16; r++) {
            float2 xv = *(const float2*)&xs[(wrow0 + r) * D + k];
            acc[r].x  += xv.x * wa.x;   acc[r].y  += xv.x * wa.y;
            acc[r].x  += xv.y * wb.x;   acc[r].y  += xv.y * wb.y;
            accr[r].x += xv.x * wra.x;  accr[r].y += xv.x * wra.y;
            accr[r].x += xv.y * wrb.x;  accr[r].y += xv.y * wrb.y;
        }
    }
    float2 brv = ((const float2*)br)[lane];
    #pragma unroll
    for (int r = 0; r < 16; r++) {
        int row = r0 + wrow0 + r;
        if (row < N_NODES) {
            float ro = rout[row];
            unsigned int u0 = __float_as_uint(acc[r].x * ro);
            unsigned int u1 = __float_as_uint(acc[r].y * ro);
            u0 += 0x7fffu + ((u0 >> 16) & 1u);            // RNE bf16
            u1 += 0x7fffu + ((u1 >> 16) & 1u);
            hwb[row * 64 + lane] = (u0 >> 16) | (u1 & 0xffff0000u);
            float2 rv;
            rv.x = fmaxf(accr[r].x + brv.x, 0.f);
            rv.y = fmaxf(accr[r].y + brv.y, 0.f);
            ((float2*)res)[row * 64 + lane] = rv;
        }
    }
}

__device__ __forceinline__ float bf_lo(unsigned int v) { return __uint_as_float(v << 16); }
__device__ __forceinline__ float bf_hi(unsigned int v) { return __uint_as_float(v & 0xffff0000u); }

__device__ __forceinline__ void acc8(float* a, const uint4 v) {
    a[0] += bf_lo(v.x); a[1] += bf_hi(v.x);
    a[2] += bf_lo(v.y); a[3] += bf_hi(v.y);
    a[4] += bf_lo(v.z); a[5] += bf_hi(v.z);
    a[6] += bf_lo(v.w); a[7] += bf_hi(v.w);
}
__device__ __forceinline__ void acc8m(float* a, const uint4 v, float m) {
    a[0] = fmaf(m, bf_lo(v.x), a[0]); a[1] = fmaf(m, bf_hi(v.x), a[1]);
    a[2] = fmaf(m, bf_lo(v.y), a[2]); a[3] = fmaf(m, bf_hi(v.y), a[3]);
    a[4] = fmaf(m, bf_lo(v.z), a[4]); a[5] = fmaf(m, bf_hi(v.z), a[5]);
    a[6] = fmaf(m, bf_lo(v.w), a[6]); a[7] = fmaf(m, bf_hi(v.w), a[7]);
}

// idx select for quarter-group qg among 4 SGPR row indices
__device__ __forceinline__ int sel4(int qg, int i0, int i1, int i2, int i3) {
    int a = (qg & 1) ? i1 : i0;
    int b = (qg & 1) ? i3 : i2;
    return (qg & 2) ? b : a;
}

// Per-dst aggregation. Wave processes nodes; each gather instruction fetches FOUR
// rows (16 lanes x uint4 = 64B per row, 256B total, coalesced). Up to 16 edges
// (4 loads) in flight. No global atomics: BN partials -> LDS -> parts[block][256].
__global__ __launch_bounds__(256) void agg_kernel(
        const unsigned int* __restrict__ hwb, const int* __restrict__ row_ptr,
        const int* __restrict__ csr_src, const float* __restrict__ rin,
        const float* __restrict__ bias, float* __restrict__ y,
        float* __restrict__ parts) {
    __shared__ float red[4 * 256];
    int tid = threadIdx.x;
    int lane = tid & 63, wid = tid >> 6;
    int wave = blockIdx.x * 4 + wid;
    int nw = AGG_BLOCKS * 4;
    int qg = lane >> 4;          // which of 4 rows this lane reads
    int ql = lane & 15;          // position within row (uint4 granules)
    float s1[8] = {0,0,0,0,0,0,0,0}, s2[8] = {0,0,0,0,0,0,0,0};
    float4 bv0, bv1;
    if (lane < 16) {
        bv0 = ((const float4*)bias)[2 * lane];
        bv1 = ((const float4*)bias)[2 * lane + 1];
    }
    for (int n = wave; n < N_NODES; n += nw) {
        int e0 = row_ptr[n], e1 = row_ptr[n + 1];
        float a[8] = {0,0,0,0,0,0,0,0};
        for (int j0 = e0; j0 < e1; j0 += 64) {
            int cnt = e1 - j0; if (cnt > 64) cnt = 64;
            int myidx = (lane < cnt) ? csr_src[j0 + lane] : 0;
            int i = 0;
            for (; i + 16 <= cnt; i += 16) {   // 4 independent uint4 gathers = 16 edges
                int p0 = sel4(qg, __builtin_amdgcn_readlane(myidx, i + 0),
                                  __builtin_amdgcn_readlane(myidx, i + 1),
                                  __builtin_amdgcn_readlane(myidx, i + 2),
                                  __builtin_amdgcn_readlane(myidx, i + 3));
                int p1 = sel4(qg, __builtin_amdgcn_readlane(myidx, i + 4),
                                  __builtin_amdgcn_readlane(myidx, i + 5),
                                  __builtin_amdgcn_readlane(myidx, i + 6),
                                  __builtin_amdgcn_readlane(myidx, i + 7));
                int p2 = sel4(qg, __builtin_amdgcn_readlane(myidx, i + 8),
                                  __builtin_amdgcn_readlane(myidx, i + 9),
                                  __builtin_amdgcn_readlane(myidx, i + 10),
                                  __builtin_amdgcn_readlane(myidx, i + 11));
                int p3 = sel4(qg, __builtin_amdgcn_readlane(myidx, i + 12),
                                  __builtin_amdgcn_readlane(myidx, i + 13),
                                  __builtin_amdgcn_readlane(myidx, i + 14),
                                  __builtin_amdgcn_readlane(myidx, i + 15));
                uint4 v0 = *((const uint4*)(hwb + (size_t)p0 * 64) + ql);
                uint4 v1 = *((const uint4*)(hwb + (size_t)p1 * 64) + ql);
                uint4 v2 = *((const uint4*)(hwb + (size_t)p2 * 64) + ql);
                uint4 v3 = *((const uint4*)(hwb + (size_t)p3 * 64) + ql);
                acc8(a, v0); acc8(a, v1); acc8(a, v2); acc8(a, v3);
            }
            for (; i + 4 <= cnt; i += 4) {
                int p0 = sel4(qg, __builtin_amdgcn_readlane(myidx, i + 0),
                                  __builtin_amdgcn_readlane(myidx, i + 1),
                                  __builtin_amdgcn_readlane(myidx, i + 2),
                                  __builtin_amdgcn_readlane(myidx, i + 3));
                uint4 v0 = *((const uint4*)(hwb + (size_t)p0 * 64) + ql);
                acc8(a, v0);
            }
            int t = cnt - i;
            if (t > 0) {                       // masked tail (1..3 edges)
                int lim = cnt - 1;
                int j1 = i + 1 <= lim ? i + 1 : lim;
                int j2 = i + 2 <= lim ? i + 2 : lim;
                int p0 = sel4(qg, __builtin_amdgcn_readlane(myidx, i),
                                  __builtin_amdgcn_readlane(myidx, j1),
                                  __builtin_amdgcn_readlane(myidx, j2),
                                  __builtin_amdgcn_readlane(myidx, lim));
                uint4 v0 = *((const uint4*)(hwb + (size_t)p0 * 64) + ql);
                float m = (qg < t) ? 1.f : 0.f;
                acc8m(a, v0, m);
            }
        }
        #pragma unroll
        for (int k = 0; k < 8; k++) {
            a[k] += __shfl_xor(a[k], 16);
            a[k] += __shfl_xor(a[k], 32);
        }
        if (lane < 16) {
            float ri = rin[n];
            float4* yv = (float4*)(y + (size_t)n * D);
            float4 r0 = yv[2 * lane], r1 = yv[2 * lane + 1];
            float o[8];
            o[0] = fmaxf(a[0] * ri + bv0.x, 0.f) + r0.x;
            o[1] = fmaxf(a[1] * ri + bv0.y, 0.f) + r0.y;
            o[2] = fmaxf(a[2] * ri + bv0.z, 0.f) + r0.z;
            o[3] = fmaxf(a[3] * ri + bv0.w, 0.f) + r0.w;
            o[4] = fmaxf(a[4] * ri + bv1.x, 0.f) + r1.x;
            o[5] = fmaxf(a[5] * ri + bv1.y, 0.f) + r1.y;
            o[6] = fmaxf(a[6] * ri + bv1.z, 0.f) + r1.z;
            o[7] = fmaxf(a[7] * ri + bv1.w, 0.f) + r1.w;
            yv[2 * lane]     = make_float4(o[0], o[1], o[2], o[3]);
            yv[2 * lane + 1] = make_float4(o[4], o[5], o[6], o[7]);
            #pragma unroll
            for (int k = 0; k < 8; k++) { s1[k] += o[k]; s2[k] += o[k] * o[k]; }
        }
    }
    if (lane < 16) {
        int c0 = lane * 8;
        #pragma unroll
        for (int k = 0; k < 8; k++) {
            red[wid * 256 + c0 + k]       = s1[k];
            red[wid * 256 + 128 + c0 + k] = s2[k];
        }
    }
    __syncthreads();
    if (tid < 256) {
        float v = red[tid] + red[256 + tid] + red[512 + tid] + red[768 + tid];
        parts[(size_t)blockIdx.x * 256 + tid] = v;
    }
}

// One block per channel: reduce AGG_BLOCKS partials, produce scale/shift.
__global__ __launch_bounds__(256) void bn_fin2(
        const float* __restrict__ parts, const float* __restrict__ gamma,
        const float* __restrict__ beta, float* __restrict__ scsh) {
    __shared__ float rs1[256], rs2[256];
    int c = blockIdx.x, t = threadIdx.x;
    float s1 = 0.f, s2 = 0.f;
    for (int b = t; b < AGG_BLOCKS; b += 256) {
        s1 += parts[(size_t)b * 256 + c];
        s2 += parts[(size_t)b * 256 + 128 + c];
    }
    rs1[t] = s1; rs2[t] = s2;
    __syncthreads();
    for (int off = 128; off > 0; off >>= 1) {
        if (t < off) { rs1[t] += rs1[t + off]; rs2[t] += rs2[t + off]; }
        __syncthreads();
    }
    if (t == 0) {
        const float invN = 1.0f / (float)N_NODES;
        float mean = rs1[0] * invN;
        float var  = rs2[0] * invN - mean * mean;
        float sc = gamma[c] * rsqrtf(var + BN_EPS);
        scsh[c] = sc;
        scsh[128 + c] = beta[c] - mean * sc;
    }
}

__global__ void norm_kernel(float* __restrict__ y, const float* __restrict__ scsh) {
    int i = blockIdx.x * blockDim.x + threadIdx.x;   // float2 index
    if (i < N_NODES * 64) {
        float2 v = ((float2*)y)[i];
        int c = (i & 63) * 2;
        v.x = v.x * scsh[c]     + scsh[128 + c];
        v.y = v.y * scsh[c + 1] + scsh[128 + c + 1];
        ((float2*)y)[i] = v;
    }
}

extern "C" void kernel_launch(void* const* d_in, const int* in_sizes, int n_in,
                              void* d_out, int out_size, void* d_ws, size_t ws_size,
                              hipStream_t stream) {
    const float* x     = (const float*)d_in[0];
    const int*   src   = (const int*)d_in[1];
    const int*   dst   = (const int*)d_in[2];
    const float* W     = (const float*)d_in[3];
    const float* b     = (const float*)d_in[4];
    const float* Wr    = (const float*)d_in[5];
    const float* br    = (const float*)d_in[6];
    const float* gamma = (const float*)d_in[7];
    const float* beta  = (const float*)d_in[8];
    float* out = (float*)d_out;

    char* ws = (char*)d_ws;
    int*   cnt_in  = (int*)(ws + 0);
    int*   cnt_out = (int*)(ws + 262144);
    int*   row_ptr = (int*)(ws + 524288);
    int*   cursor  = (int*)(ws + 786432);
    float* rin     = (float*)(ws + 1048576);
    float* rout    = (float*)(ws + 1310720);
    float* scsh    = (float*)(ws + 1576960);
    int*   csr_src = (int*)(ws + 1581056);
    unsigned int* hwb = (unsigned int*)(ws + 4800000);
    float* parts   = (float*)(ws + 17600000);

    zero_kernel<<<208, 256, 0, stream>>>(cnt_in, cnt_out);
    deg_kernel<<<(N_EDGES + 255) / 256, 256, 0, stream>>>(src, dst, cnt_out, cnt_in);
    scan_kernel<<<1, 1024, 0, stream>>>(cnt_in, cnt_out, row_ptr, cursor, rin, rout);
    fill_kernel<<<(N_EDGES + 255) / 256, 256, 0, stream>>>(src, dst, cursor, csr_src);
    gemm_kernel<<<(N_NODES + 63) / 64, 256, 0, stream>>>(x, W, Wr, br, rout, hwb, out);
    agg_kernel<<<AGG_BLOCKS, 256, 0, stream>>>(hwb, row_ptr, csr_src, rin, b, out, parts);
    bn_fin2<<<128, 256, 0, stream>>>(parts, gamma, beta, scsh);
    norm_kernel<<<(N_NODES * 64) / 256, 256, 0, stream>>>(out, scsh);
}

// Round 4
// 341.025 us; speedup vs baseline: 2.5071x; 1.3846x over previous
//
#include <hip/hip_runtime.h>

#define N_NODES 50000
#define N_EDGES 800000
#define D 128
#define BN_EPS 1e-5f
#define AGG_BLOCKS 2048
#define SCAN_BLOCKS 196   // 196*256 = 50176 >= N_NODES

// ---------------- workspace layout (bytes) ----------------
// cnt_in  @ 0        cnt_out @ 262144   row_ptr @ 524288   cursor @ 786432
// rin     @ 1048576  rout    @ 1310720  scsh    @ 1576960  blk_sum @ 1579008
// csr_src @ 1581056 (3.2MB)  hwb(bf16 packed) @ 4800000 (12.8MB)
// parts   @ 17600000 (2MB: [AGG_BLOCKS][256])

__global__ void zero_kernel(int* __restrict__ a, int* __restrict__ b) {
    int i = blockIdx.x * blockDim.x + threadIdx.x;
    if (i < 53248) { a[i] = 0; b[i] = 0; }
}

__global__ void deg_kernel(const int* __restrict__ src, const int* __restrict__ dst,
                           int* __restrict__ cnt_out, int* __restrict__ cnt_in) {
    int e = blockIdx.x * blockDim.x + threadIdx.x;
    if (e < N_EDGES) {
        atomicAdd(&cnt_out[src[e]], 1);
        atomicAdd(&cnt_in[dst[e]], 1);
    }
}

// Phase 1: per-block (256-wide) exclusive scan of cnt_in -> row_ptr (local), totals -> blk_sum
__global__ __launch_bounds__(256) void scan1_kernel(
        const int* __restrict__ cnt_in, int* __restrict__ row_ptr, int* __restrict__ blk_sum) {
    __shared__ int sh[256];
    int t = threadIdx.x;
    int i = blockIdx.x * 256 + t;
    int v = cnt_in[i];                 // zeroed past N, safe to 50176
    sh[t] = v;
    __syncthreads();
    int inc = v;
    #pragma unroll
    for (int off = 1; off < 256; off <<= 1) {
        int u = (t >= off) ? sh[t - off] : 0;
        __syncthreads();
        inc += u; sh[t] = inc;
        __syncthreads();
    }
    row_ptr[i] = inc - v;              // local exclusive prefix (temp)
    if (t == 255) blk_sum[blockIdx.x] = inc;
}

// Phase 2: scan the 196 block totals in place (exclusive); write row_ptr[N]
__global__ __launch_bounds__(256) void scan2_kernel(int* __restrict__ blk_sum, int* __restrict__ row_ptr) {
    __shared__ int sh[256];
    int t = threadIdx.x;
    int v = (t < SCAN_BLOCKS) ? blk_sum[t] : 0;
    sh[t] = v;
    __syncthreads();
    int inc = v;
    #pragma unroll
    for (int off = 1; off < 256; off <<= 1) {
        int u = (t >= off) ? sh[t - off] : 0;
        __syncthreads();
        inc += u; sh[t] = inc;
        __syncthreads();
    }
    if (t < SCAN_BLOCKS) blk_sum[t] = inc - v;   // exclusive
    if (t == 0) row_ptr[N_NODES] = N_EDGES;
}

// Phase 3: add block offset, emit row_ptr/cursor and the rsqrt norms
__global__ __launch_bounds__(256) void scan3_kernel(
        const int* __restrict__ cnt_in, const int* __restrict__ cnt_out,
        const int* __restrict__ blk_sum, int* __restrict__ row_ptr,
        int* __restrict__ cursor, float* __restrict__ rin, float* __restrict__ rout) {
    int i = blockIdx.x * 256 + threadIdx.x;
    if (i < N_NODES) {
        int rp = row_ptr[i] + blk_sum[blockIdx.x];
        row_ptr[i] = rp;
        cursor[i]  = rp;
        int ci = cnt_in[i], co = cnt_out[i];
        rin[i]  = rsqrtf((float)(ci > 1 ? ci : 1));
        rout[i] = rsqrtf((float)(co > 1 ? co : 1));
    }
}

__global__ void fill_kernel(const int* __restrict__ src, const int* __restrict__ dst,
                            int* __restrict__ cursor, int* __restrict__ csr_src) {
    int e = blockIdx.x * blockDim.x + threadIdx.x;
    if (e < N_EDGES) {
        int d = dst[e];
        int p = atomicAdd(&cursor[d], 1);
        csr_src[p] = src[e];
    }
}

// Dual GEMM, coalesced. Block = 256 threads = 4 waves, tile = 64 rows.
__global__ __launch_bounds__(256) void gemm_kernel(
        const float* __restrict__ x, const float* __restrict__ W,
        const float* __restrict__ Wr, const float* __restrict__ br,
        const float* __restrict__ rout, unsigned int* __restrict__ hwb,
        float* __restrict__ res) {
    __shared__ float xs[64 * D];
    int tid = threadIdx.x;
    int r0 = blockIdx.x * 64;
    const float4* xg = (const float4*)x;
    float4* xsv = (float4*)xs;
    int base4 = r0 * (D / 4);
    #pragma unroll
    for (int i = 0; i < 8; i++) {
        int idx = base4 + tid + 256 * i;
        xsv[tid + 256 * i] = (idx < N_NODES * (D / 4)) ? xg[idx] : make_float4(0.f, 0.f, 0.f, 0.f);
    }
    __syncthreads();
    int wid = tid >> 6, lane = tid & 63;
    int wrow0 = wid * 16;
    float2 acc[16], accr[16];
    #pragma unroll
    for (int r = 0; r < 16; r++) { acc[r] = make_float2(0.f, 0.f); accr[r] = make_float2(0.f, 0.f); }
    const float2* Wv  = (const float2*)W;
    const float2* Wrv = (const float2*)Wr;
    #pragma unroll 4
    for (int k = 0; k < D; k += 2) {
        float2 wa  = Wv[k * 64 + lane];
        float2 wb  = Wv[(k + 1) * 64 + lane];
        float2 wra = Wrv[k * 64 + lane];
        float2 wrb = Wrv[(k + 1) * 64 + lane];
        #pragma unroll
        for (int r = 0; r < 16; r++) {
            float2 xv = *(const float2*)&xs[(wrow0 + r) * D + k];
            acc[r].x  += xv.x * wa.x;   acc[r].y  += xv.x * wa.y;
            acc[r].x  += xv.y * wb.x;   acc[r].y  += xv.y * wb.y;
            accr[r].x += xv.x * wra.x;  accr[r].y += xv.x * wra.y;
            accr[r].x += xv.y * wrb.x;  accr[r].y += xv.y * wrb.y;
        }
    }
    float2 brv = ((const float2*)br)[lane];
    #pragma unroll
    for (int r = 0; r < 16; r++) {
        int row = r0 + wrow0 + r;
        if (row < N_NODES) {
            float ro = rout[row];
            unsigned int u0 = __float_as_uint(acc[r].x * ro);
            unsigned int u1 = __float_as_uint(acc[r].y * ro);
            u0 += 0x7fffu + ((u0 >> 16) & 1u);            // RNE bf16
            u1 += 0x7fffu + ((u1 >> 16) & 1u);
            hwb[row * 64 + lane] = (u0 >> 16) | (u1 & 0xffff0000u);
            float2 rv;
            rv.x = fmaxf(accr[r].x + brv.x, 0.f);
            rv.y = fmaxf(accr[r].y + brv.y, 0.f);
            ((float2*)res)[row * 64 + lane] = rv;
        }
    }
}

__device__ __forceinline__ float bf_lo(unsigned int v) { return __uint_as_float(v << 16); }
__device__ __forceinline__ float bf_hi(unsigned int v) { return __uint_as_float(v & 0xffff0000u); }

__device__ __forceinline__ void acc8(float* a, const uint4 v) {
    a[0] += bf_lo(v.x); a[1] += bf_hi(v.x);
    a[2] += bf_lo(v.y); a[3] += bf_hi(v.y);
    a[4] += bf_lo(v.z); a[5] += bf_hi(v.z);
    a[6] += bf_lo(v.w); a[7] += bf_hi(v.w);
}
__device__ __forceinline__ void acc8m(float* a, const uint4 v, float m) {
    a[0] = fmaf(m, bf_lo(v.x), a[0]); a[1] = fmaf(m, bf_hi(v.x), a[1]);
    a[2] = fmaf(m, bf_lo(v.y), a[2]); a[3] = fmaf(m, bf_hi(v.y), a[3]);
    a[4] = fmaf(m, bf_lo(v.z), a[4]); a[5] = fmaf(m, bf_hi(v.z), a[5]);
    a[6] = fmaf(m, bf_lo(v.w), a[6]); a[7] = fmaf(m, bf_hi(v.w), a[7]);
}

__device__ __forceinline__ int sel4(int qg, int i0, int i1, int i2, int i3) {
    int a = (qg & 1) ? i1 : i0;
    int b = (qg & 1) ? i3 : i2;
    return (qg & 2) ? b : a;
}

// Per-dst aggregation. Each gather instruction fetches FOUR rows (16 lanes x uint4
// = 64B per row, 256B total, coalesced). Up to 16 edges (4 loads) in flight.
// No global atomics: BN partials -> LDS -> parts[block][256].
__global__ __launch_bounds__(256) void agg_kernel(
        const unsigned int* __restrict__ hwb, const int* __restrict__ row_ptr,
        const int* __restrict__ csr_src, const float* __restrict__ rin,
        const float* __restrict__ bias, float* __restrict__ y,
        float* __restrict__ parts) {
    __shared__ float red[4 * 256];
    int tid = threadIdx.x;
    int lane = tid & 63, wid = tid >> 6;
    int wave = blockIdx.x * 4 + wid;
    int nw = AGG_BLOCKS * 4;
    int qg = lane >> 4;
    int ql = lane & 15;
    float s1[8] = {0,0,0,0,0,0,0,0}, s2[8] = {0,0,0,0,0,0,0,0};
    float4 bv0, bv1;
    if (lane < 16) {
        bv0 = ((const float4*)bias)[2 * lane];
        bv1 = ((const float4*)bias)[2 * lane + 1];
    }
    for (int n = wave; n < N_NODES; n += nw) {
        int e0 = row_ptr[n], e1 = row_ptr[n + 1];
        float a[8] = {0,0,0,0,0,0,0,0};
        for (int j0 = e0; j0 < e1; j0 += 64) {
            int cnt = e1 - j0; if (cnt > 64) cnt = 64;
            int myidx = (lane < cnt) ? csr_src[j0 + lane] : 0;
            int i = 0;
            for (; i + 16 <= cnt; i += 16) {
                int p0 = sel4(qg, __builtin_amdgcn_readlane(myidx, i + 0),
                                  __builtin_amdgcn_readlane(myidx, i + 1),
                                  __builtin_amdgcn_readlane(myidx, i + 2),
                                  __builtin_amdgcn_readlane(myidx, i + 3));
                int p1 = sel4(qg, __builtin_amdgcn_readlane(myidx, i + 4),
                                  __builtin_amdgcn_readlane(myidx, i + 5),
                                  __builtin_amdgcn_readlane(myidx, i + 6),
                                  __builtin_amdgcn_readlane(myidx, i + 7));
                int p2 = sel4(qg, __builtin_amdgcn_readlane(myidx, i + 8),
                                  __builtin_amdgcn_readlane(myidx, i + 9),
                                  __builtin_amdgcn_readlane(myidx, i + 10),
                                  __builtin_amdgcn_readlane(myidx, i + 11));
                int p3 = sel4(qg, __builtin_amdgcn_readlane(myidx, i + 12),
                                  __builtin_amdgcn_readlane(myidx, i + 13),
                                  __builtin_amdgcn_readlane(myidx, i + 14),
                                  __builtin_amdgcn_readlane(myidx, i + 15));
                uint4 v0 = *((const uint4*)(hwb + (size_t)p0 * 64) + ql);
                uint4 v1 = *((const uint4*)(hwb + (size_t)p1 * 64) + ql);
                uint4 v2 = *((const uint4*)(hwb + (size_t)p2 * 64) + ql);
                uint4 v3 = *((const uint4*)(hwb + (size_t)p3 * 64) + ql);
                acc8(a, v0); acc8(a, v1); acc8(a, v2); acc8(a, v3);
            }
            for (; i + 4 <= cnt; i += 4) {
                int p0 = sel4(qg, __builtin_amdgcn_readlane(myidx, i + 0),
                                  __builtin_amdgcn_readlane(myidx, i + 1),
                                  __builtin_amdgcn_readlane(myidx, i + 2),
                                  __builtin_amdgcn_readlane(myidx, i + 3));
                uint4 v0 = *((const uint4*)(hwb + (size_t)p0 * 64) + ql);
                acc8(a, v0);
            }
            int t = cnt - i;
            if (t > 0) {
                int lim = cnt - 1;
                int j1 = i + 1 <= lim ? i + 1 : lim;
                int j2 = i + 2 <= lim ? i + 2 : lim;
                int p0 = sel4(qg, __builtin_amdgcn_readlane(myidx, i),
                                  __builtin_amdgcn_readlane(myidx, j1),
                                  __builtin_amdgcn_readlane(myidx, j2),
                                  __builtin_amdgcn_readlane(myidx, lim));
                uint4 v0 = *((const uint4*)(hwb + (size_t)p0 * 64) + ql);
                float m = (qg < t) ? 1.f : 0.f;
                acc8m(a, v0, m);
            }
        }
        #pragma unroll
        for (int k = 0; k < 8; k++) {
            a[k] += __shfl_xor(a[k], 16);
            a[k] += __shfl_xor(a[k], 32);
        }
        if (lane < 16) {
            float ri = rin[n];
            float4* yv = (float4*)(y + (size_t)n * D);
            float4 r0 = yv[2 * lane], r1 = yv[2 * lane + 1];
            float o[8];
            o[0] = fmaxf(a[0] * ri + bv0.x, 0.f) + r0.x;
            o[1] = fmaxf(a[1] * ri + bv0.y, 0.f) + r0.y;
            o[2] = fmaxf(a[2] * ri + bv0.z, 0.f) + r0.z;
            o[3] = fmaxf(a[3] * ri + bv0.w, 0.f) + r0.w;
            o[4] = fmaxf(a[4] * ri + bv1.x, 0.f) + r1.x;
            o[5] = fmaxf(a[5] * ri + bv1.y, 0.f) + r1.y;
            o[6] = fmaxf(a[6] * ri + bv1.z, 0.f) + r1.z;
            o[7] = fmaxf(a[7] * ri + bv1.w, 0.f) + r1.w;
            yv[2 * lane]     = make_float4(o[0], o[1], o[2], o[3]);
            yv[2 * lane + 1] = make_float4(o[4], o[5], o[6], o[7]);
            #pragma unroll
            for (int k = 0; k < 8; k++) { s1[k] += o[k]; s2[k] += o[k] * o[k]; }
        }
    }
    if (lane < 16) {
        int c0 = lane * 8;
        #pragma unroll
        for (int k = 0; k < 8; k++) {
            red[wid * 256 + c0 + k]       = s1[k];
            red[wid * 256 + 128 + c0 + k] = s2[k];
        }
    }
    __syncthreads();
    if (tid < 256) {
        float v = red[tid] + red[256 + tid] + red[512 + tid] + red[768 + tid];
        parts[(size_t)blockIdx.x * 256 + tid] = v;
    }
}

// One block per channel: reduce AGG_BLOCKS partials, produce scale/shift.
__global__ __launch_bounds__(256) void bn_fin2(
        const float* __restrict__ parts, const float* __restrict__ gamma,
        const float* __restrict__ beta, float* __restrict__ scsh) {
    __shared__ float rs1[256], rs2[256];
    int c = blockIdx.x, t = threadIdx.x;
    float s1 = 0.f, s2 = 0.f;
    for (int b = t; b < AGG_BLOCKS; b += 256) {
        s1 += parts[(size_t)b * 256 + c];
        s2 += parts[(size_t)b * 256 + 128 + c];
    }
    rs1[t] = s1; rs2[t] = s2;
    __syncthreads();
    for (int off = 128; off > 0; off >>= 1) {
        if (t < off) { rs1[t] += rs1[t + off]; rs2[t] += rs2[t + off]; }
        __syncthreads();
    }
    if (t == 0) {
        const float invN = 1.0f / (float)N_NODES;
        float mean = rs1[0] * invN;
        float var  = rs2[0] * invN - mean * mean;
        float sc = gamma[c] * rsqrtf(var + BN_EPS);
        scsh[c] = sc;
        scsh[128 + c] = beta[c] - mean * sc;
    }
}

__global__ void norm_kernel(float* __restrict__ y, const float* __restrict__ scsh) {
    int i = blockIdx.x * blockDim.x + threadIdx.x;   // float4 index
    if (i < N_NODES * 32) {
        float4 v = ((float4*)y)[i];
        int c = (i & 31) * 4;
        v.x = v.x * scsh[c]     + scsh[128 + c];
        v.y = v.y * scsh[c + 1] + scsh[128 + c + 1];
        v.z = v.z * scsh[c + 2] + scsh[128 + c + 2];
        v.w = v.w * scsh[c + 3] + scsh[128 + c + 3];
        ((float4*)y)[i] = v;
    }
}

extern "C" void kernel_launch(void* const* d_in, const int* in_sizes, int n_in,
                              void* d_out, int out_size, void* d_ws, size_t ws_size,
                              hipStream_t stream) {
    const float* x     = (const float*)d_in[0];
    const int*   src   = (const int*)d_in[1];
    const int*   dst   = (const int*)d_in[2];
    const float* W     = (const float*)d_in[3];
    const float* b     = (const float*)d_in[4];
    const float* Wr    = (const float*)d_in[5];
    const float* br    = (const float*)d_in[6];
    const float* gamma = (const float*)d_in[7];
    const float* beta  = (const float*)d_in[8];
    float* out = (float*)d_out;

    char* ws = (char*)d_ws;
    int*   cnt_in  = (int*)(ws + 0);
    int*   cnt_out = (int*)(ws + 262144);
    int*   row_ptr = (int*)(ws + 524288);
    int*   cursor  = (int*)(ws + 786432);
    float* rin     = (float*)(ws + 1048576);
    float* rout    = (float*)(ws + 1310720);
    float* scsh    = (float*)(ws + 1576960);
    int*   blk_sum = (int*)(ws + 1579008);
    int*   csr_src = (int*)(ws + 1581056);
    unsigned int* hwb = (unsigned int*)(ws + 4800000);
    float* parts   = (float*)(ws + 17600000);

    zero_kernel<<<208, 256, 0, stream>>>(cnt_in, cnt_out);
    deg_kernel<<<(N_EDGES + 255) / 256, 256, 0, stream>>>(src, dst, cnt_out, cnt_in);
    scan1_kernel<<<SCAN_BLOCKS, 256, 0, stream>>>(cnt_in, row_ptr, blk_sum);
    scan2_kernel<<<1, 256, 0, stream>>>(blk_sum, row_ptr);
    scan3_kernel<<<SCAN_BLOCKS, 256, 0, stream>>>(cnt_in, cnt_out, blk_sum, row_ptr, cursor, rin, rout);
    fill_kernel<<<(N_EDGES + 255) / 256, 256, 0, stream>>>(src, dst, cursor, csr_src);
    gemm_kernel<<<(N_NODES + 63) / 64, 256, 0, stream>>>(x, W, Wr, br, rout, hwb, out);
    agg_kernel<<<AGG_BLOCKS, 256, 0, stream>>>(hwb, row_ptr, csr_src, rin, b, out, parts);
    bn_fin2<<<128, 256, 0, stream>>>(parts, gamma, beta, scsh);
    norm_kernel<<<(N_NODES * 32 + 255) / 256, 256, 0, stream>>>(out, scsh);
}

// Round 5
// 285.615 us; speedup vs baseline: 2.9935x; 1.1940x over previous
//
#include <hip/hip_runtime.h>

#define N_NODES 50000
#define N_EDGES 800000
#define D 128
#define BN_EPS 1e-5f
#define AGG_BLOCKS 2048
#define SCAN_BLOCKS 196   // 196*256 = 50176 >= N_NODES

typedef short bf16x8 __attribute__((ext_vector_type(8)));
typedef float f32x4  __attribute__((ext_vector_type(4)));

// ---------------- workspace layout (bytes) ----------------
// cnt_in  @ 0        cnt_out @ 262144   row_ptr @ 524288   cursor @ 786432
// rin     @ 1048576  rout    @ 1310720  scsh    @ 1576960  blk_sum @ 1579008
// csr_src @ 1581056 (3.2MB)  hwb(bf16 ushort[row][col]) @ 4800000 (12.8MB)
// parts   @ 17600000 (2MB)   pW @ 19697152 (32KB)  pWr @ 19729920 (32KB)

__global__ void zero_kernel(int* __restrict__ a, int* __restrict__ b) {
    int i = blockIdx.x * blockDim.x + threadIdx.x;
    if (i < 53248) { a[i] = 0; b[i] = 0; }
}

__global__ void deg_kernel(const int* __restrict__ src, const int* __restrict__ dst,
                           int* __restrict__ cnt_out, int* __restrict__ cnt_in) {
    int e = blockIdx.x * blockDim.x + threadIdx.x;
    if (e < N_EDGES) {
        atomicAdd(&cnt_out[src[e]], 1);
        atomicAdd(&cnt_in[dst[e]], 1);
    }
}

__global__ __launch_bounds__(256) void scan1_kernel(
        const int* __restrict__ cnt_in, int* __restrict__ row_ptr, int* __restrict__ blk_sum) {
    __shared__ int sh[256];
    int t = threadIdx.x;
    int i = blockIdx.x * 256 + t;
    int v = cnt_in[i];
    sh[t] = v;
    __syncthreads();
    int inc = v;
    #pragma unroll
    for (int off = 1; off < 256; off <<= 1) {
        int u = (t >= off) ? sh[t - off] : 0;
        __syncthreads();
        inc += u; sh[t] = inc;
        __syncthreads();
    }
    row_ptr[i] = inc - v;
    if (t == 255) blk_sum[blockIdx.x] = inc;
}

__global__ __launch_bounds__(256) void scan2_kernel(int* __restrict__ blk_sum, int* __restrict__ row_ptr) {
    __shared__ int sh[256];
    int t = threadIdx.x;
    int v = (t < SCAN_BLOCKS) ? blk_sum[t] : 0;
    sh[t] = v;
    __syncthreads();
    int inc = v;
    #pragma unroll
    for (int off = 1; off < 256; off <<= 1) {
        int u = (t >= off) ? sh[t - off] : 0;
        __syncthreads();
        inc += u; sh[t] = inc;
        __syncthreads();
    }
    if (t < SCAN_BLOCKS) blk_sum[t] = inc - v;
    if (t == 0) row_ptr[N_NODES] = N_EDGES;
}

__global__ __launch_bounds__(256) void scan3_kernel(
        const int* __restrict__ cnt_in, const int* __restrict__ cnt_out,
        const int* __restrict__ blk_sum, int* __restrict__ row_ptr,
        int* __restrict__ cursor, float* __restrict__ rin, float* __restrict__ rout) {
    int i = blockIdx.x * 256 + threadIdx.x;
    if (i < N_NODES) {
        int rp = row_ptr[i] + blk_sum[blockIdx.x];
        row_ptr[i] = rp;
        cursor[i]  = rp;
        int ci = cnt_in[i], co = cnt_out[i];
        rin[i]  = rsqrtf((float)(ci > 1 ? ci : 1));
        rout[i] = rsqrtf((float)(co > 1 ? co : 1));
    }
}

__global__ void fill_kernel(const int* __restrict__ src, const int* __restrict__ dst,
                            int* __restrict__ cursor, int* __restrict__ csr_src) {
    int e = blockIdx.x * blockDim.x + threadIdx.x;
    if (e < N_EDGES) {
        int d = dst[e];
        int p = atomicAdd(&cursor[d], 1);
        csr_src[p] = src[e];
    }
}

__device__ __forceinline__ unsigned int pack_rne(float a, float b) {
    unsigned int ua = __float_as_uint(a); ua += 0x7fffu + ((ua >> 16) & 1u);
    unsigned int ub = __float_as_uint(b); ub += 0x7fffu + ((ub >> 16) & 1u);
    return (ua >> 16) | (ub & 0xffff0000u);
}

// Pre-pack W and Wr into MFMA B-fragment order (bf16).
// Entry e=(ct*4+ks)*64+lane holds B[k=ks*32+quad*8+j][n=ct*16+(lane&15)], j=0..7.
__global__ __launch_bounds__(256) void pack_w(
        const float* __restrict__ W, const float* __restrict__ Wr,
        uint4* __restrict__ pW, uint4* __restrict__ pWr) {
    int t = blockIdx.x * 256 + threadIdx.x;      // 0..4095
    const float* S = (t & 2048) ? Wr : W;
    uint4* Dst     = (t & 2048) ? pWr : pW;
    int e = t & 2047;
    int lane = e & 63, ks = (e >> 6) & 3, ct = e >> 8;
    int n  = ct * 16 + (lane & 15);
    int k0 = ks * 32 + (lane >> 4) * 8;
    float v[8];
    #pragma unroll
    for (int j = 0; j < 8; j++) v[j] = S[(k0 + j) * D + n];
    uint4 r;
    r.x = pack_rne(v[0], v[1]); r.y = pack_rne(v[2], v[3]);
    r.z = pack_rne(v[4], v[5]); r.w = pack_rne(v[6], v[7]);
    Dst[e] = r;
}

// MFMA dual GEMM. Wave owns 16 node-rows, computes all 128 cols of both matrices.
// A-frags built from global fp32 x (no LDS). B-frags coalesced uint4 from packed.
// hwb = bf16( rout[r] * (x@W) ) as ushort[row][col]; res = relu(x@Wr+br) fp32.
__global__ __launch_bounds__(256) void gemm_mfma(
        const float* __restrict__ x, const uint4* __restrict__ pW,
        const uint4* __restrict__ pWr, const float* __restrict__ br,
        const float* __restrict__ rout, unsigned short* __restrict__ hwb,
        float* __restrict__ res) {
    int tid = threadIdx.x, wid = tid >> 6, lane = tid & 63;
    int quad = lane >> 4, l15 = lane & 15;
    int r0 = blockIdx.x * 64 + wid * 16;
    int arow = r0 + l15; if (arow > N_NODES - 1) arow = N_NODES - 1;
    union { bf16x8 v; uint4 u; } A[4];
    const float* xrow = x + (size_t)arow * D;
    #pragma unroll
    for (int ks = 0; ks < 4; ks++) {
        float4 f0 = *(const float4*)(xrow + ks * 32 + quad * 8);
        float4 f1 = *(const float4*)(xrow + ks * 32 + quad * 8 + 4);
        A[ks].u.x = pack_rne(f0.x, f0.y); A[ks].u.y = pack_rne(f0.z, f0.w);
        A[ks].u.z = pack_rne(f1.x, f1.y); A[ks].u.w = pack_rne(f1.z, f1.w);
    }
    f32x4 accW[8], accR[8];
    #pragma unroll
    for (int ct = 0; ct < 8; ct++) { accW[ct] = (f32x4)0.f; accR[ct] = (f32x4)0.f; }
    #pragma unroll
    for (int ct = 0; ct < 8; ct++) {
        #pragma unroll
        for (int ks = 0; ks < 4; ks++) {
            union { bf16x8 v; uint4 u; } Bw, Br2;
            Bw.u  = pW [(ct * 4 + ks) * 64 + lane];
            Br2.u = pWr[(ct * 4 + ks) * 64 + lane];
            accW[ct] = __builtin_amdgcn_mfma_f32_16x16x32_bf16(A[ks].v, Bw.v,  accW[ct], 0, 0, 0);
            accR[ct] = __builtin_amdgcn_mfma_f32_16x16x32_bf16(A[ks].v, Br2.v, accR[ct], 0, 0, 0);
        }
    }
    // C/D layout: col = ct*16 + (lane&15), row = r0 + quad*4 + reg
    float ro[4]; int rowok[4];
    #pragma unroll
    for (int reg = 0; reg < 4; reg++) {
        int row = r0 + quad * 4 + reg;
        rowok[reg] = row < N_NODES;
        ro[reg] = rout[rowok[reg] ? row : N_NODES - 1];
    }
    #pragma unroll
    for (int ct = 0; ct < 8; ct++) {
        int c = ct * 16 + l15;
        float brv = br[c];
        #pragma unroll
        for (int reg = 0; reg < 4; reg++) {
            int row = r0 + quad * 4 + reg;
            if (rowok[reg]) {
                float hv = accW[ct][reg] * ro[reg];
                unsigned int u = __float_as_uint(hv);
                u += 0x7fffu + ((u >> 16) & 1u);
                hwb[(size_t)row * D + c] = (unsigned short)(u >> 16);
                res[(size_t)row * D + c] = fmaxf(accR[ct][reg] + brv, 0.f);
            }
        }
    }
}

__device__ __forceinline__ float bf_lo(unsigned int v) { return __uint_as_float(v << 16); }
__device__ __forceinline__ float bf_hi(unsigned int v) { return __uint_as_float(v & 0xffff0000u); }

__device__ __forceinline__ void acc8(float* a, const uint4 v) {
    a[0] += bf_lo(v.x); a[1] += bf_hi(v.x);
    a[2] += bf_lo(v.y); a[3] += bf_hi(v.y);
    a[4] += bf_lo(v.z); a[5] += bf_hi(v.z);
    a[6] += bf_lo(v.w); a[7] += bf_hi(v.w);
}
__device__ __forceinline__ void acc8m(float* a, const uint4 v, float m) {
    a[0] = fmaf(m, bf_lo(v.x), a[0]); a[1] = fmaf(m, bf_hi(v.x), a[1]);
    a[2] = fmaf(m, bf_lo(v.y), a[2]); a[3] = fmaf(m, bf_hi(v.y), a[3]);
    a[4] = fmaf(m, bf_lo(v.z), a[4]); a[5] = fmaf(m, bf_hi(v.z), a[5]);
    a[6] = fmaf(m, bf_lo(v.w), a[6]); a[7] = fmaf(m, bf_hi(v.w), a[7]);
}

__device__ __forceinline__ int sel4(int qg, int i0, int i1, int i2, int i3) {
    int a = (qg & 1) ? i1 : i0;
    int b = (qg & 1) ? i3 : i2;
    return (qg & 2) ? b : a;
}

// Per-dst aggregation. Each gather instruction fetches FOUR rows (16 lanes x uint4
// = 64B per row, 256B total, coalesced). Up to 16 edges (4 loads) in flight.
// No global atomics: BN partials -> LDS -> parts[block][256].
__global__ __launch_bounds__(256) void agg_kernel(
        const unsigned int* __restrict__ hwb, const int* __restrict__ row_ptr,
        const int* __restrict__ csr_src, const float* __restrict__ rin,
        const float* __restrict__ bias, float* __restrict__ y,
        float* __restrict__ parts) {
    __shared__ float red[4 * 256];
    int tid = threadIdx.x;
    int lane = tid & 63, wid = tid >> 6;
    int wave = blockIdx.x * 4 + wid;
    int nw = AGG_BLOCKS * 4;
    int qg = lane >> 4;
    int ql = lane & 15;
    float s1[8] = {0,0,0,0,0,0,0,0}, s2[8] = {0,0,0,0,0,0,0,0};
    float4 bv0, bv1;
    if (lane < 16) {
        bv0 = ((const float4*)bias)[2 * lane];
        bv1 = ((const float4*)bias)[2 * lane + 1];
    }
    for (int n = wave; n < N_NODES; n += nw) {
        int e0 = row_ptr[n], e1 = row_ptr[n + 1];
        float a[8] = {0,0,0,0,0,0,0,0};
        for (int j0 = e0; j0 < e1; j0 += 64) {
            int cnt = e1 - j0; if (cnt > 64) cnt = 64;
            int myidx = (lane < cnt) ? csr_src[j0 + lane] : 0;
            int i = 0;
            for (; i + 16 <= cnt; i += 16) {
                int p0 = sel4(qg, __builtin_amdgcn_readlane(myidx, i + 0),
                                  __builtin_amdgcn_readlane(myidx, i + 1),
                                  __builtin_amdgcn_readlane(myidx, i + 2),
                                  __builtin_amdgcn_readlane(myidx, i + 3));
                int p1 = sel4(qg, __builtin_amdgcn_readlane(myidx, i + 4),
                                  __builtin_amdgcn_readlane(myidx, i + 5),
                                  __builtin_amdgcn_readlane(myidx, i + 6),
                                  __builtin_amdgcn_readlane(myidx, i + 7));
                int p2 = sel4(qg, __builtin_amdgcn_readlane(myidx, i + 8),
                                  __builtin_amdgcn_readlane(myidx, i + 9),
                                  __builtin_amdgcn_readlane(myidx, i + 10),
                                  __builtin_amdgcn_readlane(myidx, i + 11));
                int p3 = sel4(qg, __builtin_amdgcn_readlane(myidx, i + 12),
                                  __builtin_amdgcn_readlane(myidx, i + 13),
                                  __builtin_amdgcn_readlane(myidx, i + 14),
                                  __builtin_amdgcn_readlane(myidx, i + 15));
                uint4 v0 = *((const uint4*)(hwb + (size_t)p0 * 64) + ql);
                uint4 v1 = *((const uint4*)(hwb + (size_t)p1 * 64) + ql);
                uint4 v2 = *((const uint4*)(hwb + (size_t)p2 * 64) + ql);
                uint4 v3 = *((const uint4*)(hwb + (size_t)p3 * 64) + ql);
                acc8(a, v0); acc8(a, v1); acc8(a, v2); acc8(a, v3);
            }
            for (; i + 4 <= cnt; i += 4) {
                int p0 = sel4(qg, __builtin_amdgcn_readlane(myidx, i + 0),
                                  __builtin_amdgcn_readlane(myidx, i + 1),
                                  __builtin_amdgcn_readlane(myidx, i + 2),
                                  __builtin_amdgcn_readlane(myidx, i + 3));
                uint4 v0 = *((const uint4*)(hwb + (size_t)p0 * 64) + ql);
                acc8(a, v0);
            }
            int t = cnt - i;
            if (t > 0) {
                int lim = cnt - 1;
                int j1 = i + 1 <= lim ? i + 1 : lim;
                int j2 = i + 2 <= lim ? i + 2 : lim;
                int p0 = sel4(qg, __builtin_amdgcn_readlane(myidx, i),
                                  __builtin_amdgcn_readlane(myidx, j1),
                                  __builtin_amdgcn_readlane(myidx, j2),
                                  __builtin_amdgcn_readlane(myidx, lim));
                uint4 v0 = *((const uint4*)(hwb + (size_t)p0 * 64) + ql);
                float m = (qg < t) ? 1.f : 0.f;
                acc8m(a, v0, m);
            }
        }
        #pragma unroll
        for (int k = 0; k < 8; k++) {
            a[k] += __shfl_xor(a[k], 16);
            a[k] += __shfl_xor(a[k], 32);
        }
        if (lane < 16) {
            float ri = rin[n];
            float4* yv = (float4*)(y + (size_t)n * D);
            float4 r0 = yv[2 * lane], r1 = yv[2 * lane + 1];
            float o[8];
            o[0] = fmaxf(a[0] * ri + bv0.x, 0.f) + r0.x;
            o[1] = fmaxf(a[1] * ri + bv0.y, 0.f) + r0.y;
            o[2] = fmaxf(a[2] * ri + bv0.z, 0.f) + r0.z;
            o[3] = fmaxf(a[3] * ri + bv0.w, 0.f) + r0.w;
            o[4] = fmaxf(a[4] * ri + bv1.x, 0.f) + r1.x;
            o[5] = fmaxf(a[5] * ri + bv1.y, 0.f) + r1.y;
            o[6] = fmaxf(a[6] * ri + bv1.z, 0.f) + r1.z;
            o[7] = fmaxf(a[7] * ri + bv1.w, 0.f) + r1.w;
            yv[2 * lane]     = make_float4(o[0], o[1], o[2], o[3]);
            yv[2 * lane + 1] = make_float4(o[4], o[5], o[6], o[7]);
            #pragma unroll
            for (int k = 0; k < 8; k++) { s1[k] += o[k]; s2[k] += o[k] * o[k]; }
        }
    }
    if (lane < 16) {
        int c0 = lane * 8;
        #pragma unroll
        for (int k = 0; k < 8; k++) {
            red[wid * 256 + c0 + k]       = s1[k];
            red[wid * 256 + 128 + c0 + k] = s2[k];
        }
    }
    __syncthreads();
    if (tid < 256) {
        float v = red[tid] + red[256 + tid] + red[512 + tid] + red[768 + tid];
        parts[(size_t)blockIdx.x * 256 + tid] = v;
    }
}

__global__ __launch_bounds__(256) void bn_fin2(
        const float* __restrict__ parts, const float* __restrict__ gamma,
        const float* __restrict__ beta, float* __restrict__ scsh) {
    __shared__ float rs1[256], rs2[256];
    int c = blockIdx.x, t = threadIdx.x;
    float s1 = 0.f, s2 = 0.f;
    for (int b = t; b < AGG_BLOCKS; b += 256) {
        s1 += parts[(size_t)b * 256 + c];
        s2 += parts[(size_t)b * 256 + 128 + c];
    }
    rs1[t] = s1; rs2[t] = s2;
    __syncthreads();
    for (int off = 128; off > 0; off >>= 1) {
        if (t < off) { rs1[t] += rs1[t + off]; rs2[t] += rs2[t + off]; }
        __syncthreads();
    }
    if (t == 0) {
        const float invN = 1.0f / (float)N_NODES;
        float mean = rs1[0] * invN;
        float var  = rs2[0] * invN - mean * mean;
        float sc = gamma[c] * rsqrtf(var + BN_EPS);
        scsh[c] = sc;
        scsh[128 + c] = beta[c] - mean * sc;
    }
}

__global__ void norm_kernel(float* __restrict__ y, const float* __restrict__ scsh) {
    int i = blockIdx.x * blockDim.x + threadIdx.x;
    if (i < N_NODES * 32) {
        float4 v = ((float4*)y)[i];
        int c = (i & 31) * 4;
        v.x = v.x * scsh[c]     + scsh[128 + c];
        v.y = v.y * scsh[c + 1] + scsh[128 + c + 1];
        v.z = v.z * scsh[c + 2] + scsh[128 + c + 2];
        v.w = v.w * scsh[c + 3] + scsh[128 + c + 3];
        ((float4*)y)[i] = v;
    }
}

extern "C" void kernel_launch(void* const* d_in, const int* in_sizes, int n_in,
                              void* d_out, int out_size, void* d_ws, size_t ws_size,
                              hipStream_t stream) {
    const float* x     = (const float*)d_in[0];
    const int*   src   = (const int*)d_in[1];
    const int*   dst   = (const int*)d_in[2];
    const float* W     = (const float*)d_in[3];
    const float* b     = (const float*)d_in[4];
    const float* Wr    = (const float*)d_in[5];
    const float* br    = (const float*)d_in[6];
    const float* gamma = (const float*)d_in[7];
    const float* beta  = (const float*)d_in[8];
    float* out = (float*)d_out;

    char* ws = (char*)d_ws;
    int*   cnt_in  = (int*)(ws + 0);
    int*   cnt_out = (int*)(ws + 262144);
    int*   row_ptr = (int*)(ws + 524288);
    int*   cursor  = (int*)(ws + 786432);
    float* rin     = (float*)(ws + 1048576);
    float* rout    = (float*)(ws + 1310720);
    float* scsh    = (float*)(ws + 1576960);
    int*   blk_sum = (int*)(ws + 1579008);
    int*   csr_src = (int*)(ws + 1581056);
    unsigned short* hwb = (unsigned short*)(ws + 4800000);
    float* parts   = (float*)(ws + 17600000);
    uint4* pW      = (uint4*)(ws + 19697152);
    uint4* pWr     = (uint4*)(ws + 19729920);

    zero_kernel<<<208, 256, 0, stream>>>(cnt_in, cnt_out);
    deg_kernel<<<(N_EDGES + 255) / 256, 256, 0, stream>>>(src, dst, cnt_out, cnt_in);
    scan1_kernel<<<SCAN_BLOCKS, 256, 0, stream>>>(cnt_in, row_ptr, blk_sum);
    scan2_kernel<<<1, 256, 0, stream>>>(blk_sum, row_ptr);
    scan3_kernel<<<SCAN_BLOCKS, 256, 0, stream>>>(cnt_in, cnt_out, blk_sum, row_ptr, cursor, rin, rout);
    fill_kernel<<<(N_EDGES + 255) / 256, 256, 0, stream>>>(src, dst, cursor, csr_src);
    pack_w<<<16, 256, 0, stream>>>(W, Wr, pW, pWr);
    gemm_mfma<<<(N_NODES + 63) / 64, 256, 0, stream>>>(x, pW, pWr, br, rout, hwb, out);
    agg_kernel<<<AGG_BLOCKS, 256, 0, stream>>>((const unsigned int*)hwb, row_ptr, csr_src, rin, b, out, parts);
    bn_fin2<<<128, 256, 0, stream>>>(parts, gamma, beta, scsh);
    norm_kernel<<<(N_NODES * 32 + 255) / 256, 256, 0, stream>>>(out, scsh);
}

// Round 6
// 258.363 us; speedup vs baseline: 3.3093x; 1.1055x over previous
//
#include <hip/hip_runtime.h>

#define N_NODES 50000
#define N_EDGES 800000
#define D 128
#define BN_EPS 1e-5f
#define AGG_BLOCKS 2048
#define SCAN_BLOCKS 196   // 196*256 = 50176 >= N_NODES
#define CHUNKS 64
#define EPC (N_EDGES / CHUNKS)   // 12500 edges per chunk (< 65536: u16-safe)
#define HALF_BINS 25600          // node-range half
#define HALF_U32 12800           // u32 words per half (2 bins/word)

typedef short bf16x8 __attribute__((ext_vector_type(8)));
typedef float f32x4  __attribute__((ext_vector_type(4)));

// ---------------- workspace layout (bytes) ----------------
// cnt_in  @ 0        cnt_out @ 262144   row_ptr @ 524288   cursor @ 786432
// rin     @ 1048576  rout    @ 1310720  scsh    @ 1576960  blk_sum @ 1579008
// csr_src @ 1581056 (3.2MB)  hwb(bf16 ushort[row][col]) @ 4800000 (12.8MB)
// parts   @ 17600000 (2MB)   pW @ 19697152 (32KB)  pWr @ 19729920 (32KB)
// histD   @ 19762688 (6.55MB)  histS @ 26316288 (6.55MB)  [end ~33.1MB]

// Privatized LDS histogram: block (chunk c, range r) counts keys in
// [r*25600, (r+1)*25600) from its 12500-edge chunk. Bins packed 2-per-u32
// (u16 halves; max 12500 per half -> no carry). NO global atomics.
__global__ __launch_bounds__(256) void hist_kernel(
        const int* __restrict__ keys, unsigned int* __restrict__ hist) {
    __shared__ unsigned int h[HALF_U32];
    int tid = threadIdx.x;
    int c = blockIdx.x, r = blockIdx.y;
    for (int j = tid; j < HALF_U32; j += 256) h[j] = 0u;
    __syncthreads();
    int base = c * EPC;
    int lo = r * HALF_BINS;
    for (int i = tid; i < EPC; i += 256) {
        int b = keys[base + i] - lo;
        if ((unsigned)b < (unsigned)HALF_BINS)
            atomicAdd(&h[b >> 1], 1u << ((b & 1) * 16));
    }
    __syncthreads();
    unsigned int* out = hist + ((size_t)(r * CHUNKS + c)) * HALF_U32;
    for (int j = tid; j < HALF_U32; j += 256) out[j] = h[j];
}

// Sum the per-chunk histograms -> cnt arrays. Coalesced (adjacent threads
// read adjacent u32 within one chunk's histogram).
__global__ __launch_bounds__(256) void merge_kernel(
        const unsigned int* __restrict__ histD, const unsigned int* __restrict__ histS,
        int* __restrict__ cnt_in, int* __restrict__ cnt_out) {
    int q = blockIdx.x * 256 + threadIdx.x;      // 0..12799
    int r = blockIdx.y;                           // range half
    const unsigned int* hist = blockIdx.z ? histS : histD;
    int* cnt = blockIdx.z ? cnt_out : cnt_in;
    unsigned int lo = 0, hi = 0;
    #pragma unroll 4
    for (int c = 0; c < CHUNKS; c++) {
        unsigned int v = hist[((size_t)(r * CHUNKS + c)) * HALF_U32 + q];
        lo += v & 0xffffu; hi += v >> 16;
    }
    int n0 = r * HALF_BINS + q * 2;
    cnt[n0]     = (int)lo;
    cnt[n0 + 1] = (int)hi;
}

__global__ __launch_bounds__(256) void scan1_kernel(
        const int* __restrict__ cnt_in, int* __restrict__ row_ptr, int* __restrict__ blk_sum) {
    __shared__ int sh[256];
    int t = threadIdx.x;
    int i = blockIdx.x * 256 + t;
    int v = cnt_in[i];                 // merge writes bins 0..51199 >= 50176, safe
    sh[t] = v;
    __syncthreads();
    int inc = v;
    #pragma unroll
    for (int off = 1; off < 256; off <<= 1) {
        int u = (t >= off) ? sh[t - off] : 0;
        __syncthreads();
        inc += u; sh[t] = inc;
        __syncthreads();
    }
    row_ptr[i] = inc - v;
    if (t == 255) blk_sum[blockIdx.x] = inc;
}

__global__ __launch_bounds__(256) void scan2_kernel(int* __restrict__ blk_sum, int* __restrict__ row_ptr) {
    __shared__ int sh[256];
    int t = threadIdx.x;
    int v = (t < SCAN_BLOCKS) ? blk_sum[t] : 0;
    sh[t] = v;
    __syncthreads();
    int inc = v;
    #pragma unroll
    for (int off = 1; off < 256; off <<= 1) {
        int u = (t >= off) ? sh[t - off] : 0;
        __syncthreads();
        inc += u; sh[t] = inc;
        __syncthreads();
    }
    if (t < SCAN_BLOCKS) blk_sum[t] = inc - v;
    if (t == 0) row_ptr[N_NODES] = N_EDGES;
}

__global__ __launch_bounds__(256) void scan3_kernel(
        const int* __restrict__ cnt_in, const int* __restrict__ cnt_out,
        const int* __restrict__ blk_sum, int* __restrict__ row_ptr,
        int* __restrict__ cursor, float* __restrict__ rin, float* __restrict__ rout) {
    int i = blockIdx.x * 256 + threadIdx.x;
    if (i < N_NODES) {
        int rp = row_ptr[i] + blk_sum[blockIdx.x];
        row_ptr[i] = rp;
        cursor[i]  = rp;
        int ci = cnt_in[i], co = cnt_out[i];
        rin[i]  = rsqrtf((float)(ci > 1 ? ci : 1));
        rout[i] = rsqrtf((float)(co > 1 ? co : 1));
    }
}

__global__ void fill_kernel(const int* __restrict__ src, const int* __restrict__ dst,
                            int* __restrict__ cursor, int* __restrict__ csr_src) {
    int e = blockIdx.x * blockDim.x + threadIdx.x;
    if (e < N_EDGES) {
        int d = dst[e];
        int p = atomicAdd(&cursor[d], 1);
        csr_src[p] = src[e];
    }
}

__device__ __forceinline__ unsigned int pack_rne(float a, float b) {
    unsigned int ua = __float_as_uint(a); ua += 0x7fffu + ((ua >> 16) & 1u);
    unsigned int ub = __float_as_uint(b); ub += 0x7fffu + ((ub >> 16) & 1u);
    return (ua >> 16) | (ub & 0xffff0000u);
}

// Pre-pack W and Wr into MFMA B-fragment order (bf16).
__global__ __launch_bounds__(256) void pack_w(
        const float* __restrict__ W, const float* __restrict__ Wr,
        uint4* __restrict__ pW, uint4* __restrict__ pWr) {
    int t = blockIdx.x * 256 + threadIdx.x;      // 0..4095
    const float* S = (t & 2048) ? Wr : W;
    uint4* Dst     = (t & 2048) ? pWr : pW;
    int e = t & 2047;
    int lane = e & 63, ks = (e >> 6) & 3, ct = e >> 8;
    int n  = ct * 16 + (lane & 15);
    int k0 = ks * 32 + (lane >> 4) * 8;
    float v[8];
    #pragma unroll
    for (int j = 0; j < 8; j++) v[j] = S[(k0 + j) * D + n];
    uint4 r;
    r.x = pack_rne(v[0], v[1]); r.y = pack_rne(v[2], v[3]);
    r.z = pack_rne(v[4], v[5]); r.w = pack_rne(v[6], v[7]);
    Dst[e] = r;
}

// MFMA dual GEMM. Wave owns 16 node-rows, computes all 128 cols of both matrices.
__global__ __launch_bounds__(256) void gemm_mfma(
        const float* __restrict__ x, const uint4* __restrict__ pW,
        const uint4* __restrict__ pWr, const float* __restrict__ br,
        const float* __restrict__ rout, unsigned short* __restrict__ hwb,
        float* __restrict__ res) {
    int tid = threadIdx.x, wid = tid >> 6, lane = tid & 63;
    int quad = lane >> 4, l15 = lane & 15;
    int r0 = blockIdx.x * 64 + wid * 16;
    int arow = r0 + l15; if (arow > N_NODES - 1) arow = N_NODES - 1;
    union { bf16x8 v; uint4 u; } A[4];
    const float* xrow = x + (size_t)arow * D;
    #pragma unroll
    for (int ks = 0; ks < 4; ks++) {
        float4 f0 = *(const float4*)(xrow + ks * 32 + quad * 8);
        float4 f1 = *(const float4*)(xrow + ks * 32 + quad * 8 + 4);
        A[ks].u.x = pack_rne(f0.x, f0.y); A[ks].u.y = pack_rne(f0.z, f0.w);
        A[ks].u.z = pack_rne(f1.x, f1.y); A[ks].u.w = pack_rne(f1.z, f1.w);
    }
    f32x4 accW[8], accR[8];
    #pragma unroll
    for (int ct = 0; ct < 8; ct++) { accW[ct] = (f32x4)0.f; accR[ct] = (f32x4)0.f; }
    #pragma unroll
    for (int ct = 0; ct < 8; ct++) {
        #pragma unroll
        for (int ks = 0; ks < 4; ks++) {
            union { bf16x8 v; uint4 u; } Bw, Br2;
            Bw.u  = pW [(ct * 4 + ks) * 64 + lane];
            Br2.u = pWr[(ct * 4 + ks) * 64 + lane];
            accW[ct] = __builtin_amdgcn_mfma_f32_16x16x32_bf16(A[ks].v, Bw.v,  accW[ct], 0, 0, 0);
            accR[ct] = __builtin_amdgcn_mfma_f32_16x16x32_bf16(A[ks].v, Br2.v, accR[ct], 0, 0, 0);
        }
    }
    float ro[4]; int rowok[4];
    #pragma unroll
    for (int reg = 0; reg < 4; reg++) {
        int row = r0 + quad * 4 + reg;
        rowok[reg] = row < N_NODES;
        ro[reg] = rout[rowok[reg] ? row : N_NODES - 1];
    }
    #pragma unroll
    for (int ct = 0; ct < 8; ct++) {
        int c = ct * 16 + l15;
        float brv = br[c];
        #pragma unroll
        for (int reg = 0; reg < 4; reg++) {
            int row = r0 + quad * 4 + reg;
            if (rowok[reg]) {
                float hv = accW[ct][reg] * ro[reg];
                unsigned int u = __float_as_uint(hv);
                u += 0x7fffu + ((u >> 16) & 1u);
                hwb[(size_t)row * D + c] = (unsigned short)(u >> 16);
                res[(size_t)row * D + c] = fmaxf(accR[ct][reg] + brv, 0.f);
            }
        }
    }
}

__device__ __forceinline__ float bf_lo(unsigned int v) { return __uint_as_float(v << 16); }
__device__ __forceinline__ float bf_hi(unsigned int v) { return __uint_as_float(v & 0xffff0000u); }

__device__ __forceinline__ void acc8(float* a, const uint4 v) {
    a[0] += bf_lo(v.x); a[1] += bf_hi(v.x);
    a[2] += bf_lo(v.y); a[3] += bf_hi(v.y);
    a[4] += bf_lo(v.z); a[5] += bf_hi(v.z);
    a[6] += bf_lo(v.w); a[7] += bf_hi(v.w);
}
__device__ __forceinline__ void acc8m(float* a, const uint4 v, float m) {
    a[0] = fmaf(m, bf_lo(v.x), a[0]); a[1] = fmaf(m, bf_hi(v.x), a[1]);
    a[2] = fmaf(m, bf_lo(v.y), a[2]); a[3] = fmaf(m, bf_hi(v.y), a[3]);
    a[4] = fmaf(m, bf_lo(v.z), a[4]); a[5] = fmaf(m, bf_hi(v.z), a[5]);
    a[6] = fmaf(m, bf_lo(v.w), a[6]); a[7] = fmaf(m, bf_hi(v.w), a[7]);
}

__device__ __forceinline__ int sel4(int qg, int i0, int i1, int i2, int i3) {
    int a = (qg & 1) ? i1 : i0;
    int b = (qg & 1) ? i3 : i2;
    return (qg & 2) ? b : a;
}

// Per-dst aggregation; 4 rows per gather instruction, no global atomics.
__global__ __launch_bounds__(256) void agg_kernel(
        const unsigned int* __restrict__ hwb, const int* __restrict__ row_ptr,
        const int* __restrict__ csr_src, const float* __restrict__ rin,
        const float* __restrict__ bias, float* __restrict__ y,
        float* __restrict__ parts) {
    __shared__ float red[4 * 256];
    int tid = threadIdx.x;
    int lane = tid & 63, wid = tid >> 6;
    int wave = blockIdx.x * 4 + wid;
    int nw = AGG_BLOCKS * 4;
    int qg = lane >> 4;
    int ql = lane & 15;
    float s1[8] = {0,0,0,0,0,0,0,0}, s2[8] = {0,0,0,0,0,0,0,0};
    float4 bv0, bv1;
    if (lane < 16) {
        bv0 = ((const float4*)bias)[2 * lane];
        bv1 = ((const float4*)bias)[2 * lane + 1];
    }
    for (int n = wave; n < N_NODES; n += nw) {
        int e0 = row_ptr[n], e1 = row_ptr[n + 1];
        float a[8] = {0,0,0,0,0,0,0,0};
        for (int j0 = e0; j0 < e1; j0 += 64) {
            int cnt = e1 - j0; if (cnt > 64) cnt = 64;
            int myidx = (lane < cnt) ? csr_src[j0 + lane] : 0;
            int i = 0;
            for (; i + 16 <= cnt; i += 16) {
                int p0 = sel4(qg, __builtin_amdgcn_readlane(myidx, i + 0),
                                  __builtin_amdgcn_readlane(myidx, i + 1),
                                  __builtin_amdgcn_readlane(myidx, i + 2),
                                  __builtin_amdgcn_readlane(myidx, i + 3));
                int p1 = sel4(qg, __builtin_amdgcn_readlane(myidx, i + 4),
                                  __builtin_amdgcn_readlane(myidx, i + 5),
                                  __builtin_amdgcn_readlane(myidx, i + 6),
                                  __builtin_amdgcn_readlane(myidx, i + 7));
                int p2 = sel4(qg, __builtin_amdgcn_readlane(myidx, i + 8),
                                  __builtin_amdgcn_readlane(myidx, i + 9),
                                  __builtin_amdgcn_readlane(myidx, i + 10),
                                  __builtin_amdgcn_readlane(myidx, i + 11));
                int p3 = sel4(qg, __builtin_amdgcn_readlane(myidx, i + 12),
                                  __builtin_amdgcn_readlane(myidx, i + 13),
                                  __builtin_amdgcn_readlane(myidx, i + 14),
                                  __builtin_amdgcn_readlane(myidx, i + 15));
                uint4 v0 = *((const uint4*)(hwb + (size_t)p0 * 64) + ql);
                uint4 v1 = *((const uint4*)(hwb + (size_t)p1 * 64) + ql);
                uint4 v2 = *((const uint4*)(hwb + (size_t)p2 * 64) + ql);
                uint4 v3 = *((const uint4*)(hwb + (size_t)p3 * 64) + ql);
                acc8(a, v0); acc8(a, v1); acc8(a, v2); acc8(a, v3);
            }
            for (; i + 4 <= cnt; i += 4) {
                int p0 = sel4(qg, __builtin_amdgcn_readlane(myidx, i + 0),
                                  __builtin_amdgcn_readlane(myidx, i + 1),
                                  __builtin_amdgcn_readlane(myidx, i + 2),
                                  __builtin_amdgcn_readlane(myidx, i + 3));
                uint4 v0 = *((const uint4*)(hwb + (size_t)p0 * 64) + ql);
                acc8(a, v0);
            }
            int t = cnt - i;
            if (t > 0) {
                int lim = cnt - 1;
                int j1 = i + 1 <= lim ? i + 1 : lim;
                int j2 = i + 2 <= lim ? i + 2 : lim;
                int p0 = sel4(qg, __builtin_amdgcn_readlane(myidx, i),
                                  __builtin_amdgcn_readlane(myidx, j1),
                                  __builtin_amdgcn_readlane(myidx, j2),
                                  __builtin_amdgcn_readlane(myidx, lim));
                uint4 v0 = *((const uint4*)(hwb + (size_t)p0 * 64) + ql);
                float m = (qg < t) ? 1.f : 0.f;
                acc8m(a, v0, m);
            }
        }
        #pragma unroll
        for (int k = 0; k < 8; k++) {
            a[k] += __shfl_xor(a[k], 16);
            a[k] += __shfl_xor(a[k], 32);
        }
        if (lane < 16) {
            float ri = rin[n];
            float4* yv = (float4*)(y + (size_t)n * D);
            float4 r0 = yv[2 * lane], r1 = yv[2 * lane + 1];
            float o[8];
            o[0] = fmaxf(a[0] * ri + bv0.x, 0.f) + r0.x;
            o[1] = fmaxf(a[1] * ri + bv0.y, 0.f) + r0.y;
            o[2] = fmaxf(a[2] * ri + bv0.z, 0.f) + r0.z;
            o[3] = fmaxf(a[3] * ri + bv0.w, 0.f) + r0.w;
            o[4] = fmaxf(a[4] * ri + bv1.x, 0.f) + r1.x;
            o[5] = fmaxf(a[5] * ri + bv1.y, 0.f) + r1.y;
            o[6] = fmaxf(a[6] * ri + bv1.z, 0.f) + r1.z;
            o[7] = fmaxf(a[7] * ri + bv1.w, 0.f) + r1.w;
            yv[2 * lane]     = make_float4(o[0], o[1], o[2], o[3]);
            yv[2 * lane + 1] = make_float4(o[4], o[5], o[6], o[7]);
            #pragma unroll
            for (int k = 0; k < 8; k++) { s1[k] += o[k]; s2[k] += o[k] * o[k]; }
        }
    }
    if (lane < 16) {
        int c0 = lane * 8;
        #pragma unroll
        for (int k = 0; k < 8; k++) {
            red[wid * 256 + c0 + k]       = s1[k];
            red[wid * 256 + 128 + c0 + k] = s2[k];
        }
    }
    __syncthreads();
    if (tid < 256) {
        float v = red[tid] + red[256 + tid] + red[512 + tid] + red[768 + tid];
        parts[(size_t)blockIdx.x * 256 + tid] = v;
    }
}

__global__ __launch_bounds__(256) void bn_fin2(
        const float* __restrict__ parts, const float* __restrict__ gamma,
        const float* __restrict__ beta, float* __restrict__ scsh) {
    __shared__ float rs1[256], rs2[256];
    int c = blockIdx.x, t = threadIdx.x;
    float s1 = 0.f, s2 = 0.f;
    for (int b = t; b < AGG_BLOCKS; b += 256) {
        s1 += parts[(size_t)b * 256 + c];
        s2 += parts[(size_t)b * 256 + 128 + c];
    }
    rs1[t] = s1; rs2[t] = s2;
    __syncthreads();
    for (int off = 128; off > 0; off >>= 1) {
        if (t < off) { rs1[t] += rs1[t + off]; rs2[t] += rs2[t + off]; }
        __syncthreads();
    }
    if (t == 0) {
        const float invN = 1.0f / (float)N_NODES;
        float mean = rs1[0] * invN;
        float var  = rs2[0] * invN - mean * mean;
        float sc = gamma[c] * rsqrtf(var + BN_EPS);
        scsh[c] = sc;
        scsh[128 + c] = beta[c] - mean * sc;
    }
}

__global__ void norm_kernel(float* __restrict__ y, const float* __restrict__ scsh) {
    int i = blockIdx.x * blockDim.x + threadIdx.x;
    if (i < N_NODES * 32) {
        float4 v = ((float4*)y)[i];
        int c = (i & 31) * 4;
        v.x = v.x * scsh[c]     + scsh[128 + c];
        v.y = v.y * scsh[c + 1] + scsh[128 + c + 1];
        v.z = v.z * scsh[c + 2] + scsh[128 + c + 2];
        v.w = v.w * scsh[c + 3] + scsh[128 + c + 3];
        ((float4*)y)[i] = v;
    }
}

extern "C" void kernel_launch(void* const* d_in, const int* in_sizes, int n_in,
                              void* d_out, int out_size, void* d_ws, size_t ws_size,
                              hipStream_t stream) {
    const float* x     = (const float*)d_in[0];
    const int*   src   = (const int*)d_in[1];
    const int*   dst   = (const int*)d_in[2];
    const float* W     = (const float*)d_in[3];
    const float* b     = (const float*)d_in[4];
    const float* Wr    = (const float*)d_in[5];
    const float* br    = (const float*)d_in[6];
    const float* gamma = (const float*)d_in[7];
    const float* beta  = (const float*)d_in[8];
    float* out = (float*)d_out;

    char* ws = (char*)d_ws;
    int*   cnt_in  = (int*)(ws + 0);
    int*   cnt_out = (int*)(ws + 262144);
    int*   row_ptr = (int*)(ws + 524288);
    int*   cursor  = (int*)(ws + 786432);
    float* rin     = (float*)(ws + 1048576);
    float* rout    = (float*)(ws + 1310720);
    float* scsh    = (float*)(ws + 1576960);
    int*   blk_sum = (int*)(ws + 1579008);
    int*   csr_src = (int*)(ws + 1581056);
    unsigned short* hwb = (unsigned short*)(ws + 4800000);
    float* parts   = (float*)(ws + 17600000);
    uint4* pW      = (uint4*)(ws + 19697152);
    uint4* pWr     = (uint4*)(ws + 19729920);
    unsigned int* histD = (unsigned int*)(ws + 19762688);
    unsigned int* histS = (unsigned int*)(ws + 26316288);

    hist_kernel<<<dim3(CHUNKS, 2), 256, 0, stream>>>(dst, histD);
    hist_kernel<<<dim3(CHUNKS, 2), 256, 0, stream>>>(src, histS);
    merge_kernel<<<dim3(HALF_U32 / 256, 2, 2), 256, 0, stream>>>(histD, histS, cnt_in, cnt_out);
    scan1_kernel<<<SCAN_BLOCKS, 256, 0, stream>>>(cnt_in, row_ptr, blk_sum);
    scan2_kernel<<<1, 256, 0, stream>>>(blk_sum, row_ptr);
    scan3_kernel<<<SCAN_BLOCKS, 256, 0, stream>>>(cnt_in, cnt_out, blk_sum, row_ptr, cursor, rin, rout);
    fill_kernel<<<(N_EDGES + 255) / 256, 256, 0, stream>>>(src, dst, cursor, csr_src);
    pack_w<<<16, 256, 0, stream>>>(W, Wr, pW, pWr);
    gemm_mfma<<<(N_NODES + 63) / 64, 256, 0, stream>>>(x, pW, pWr, br, rout, hwb, out);
    agg_kernel<<<AGG_BLOCKS, 256, 0, stream>>>((const unsigned int*)hwb, row_ptr, csr_src, rin, b, out, parts);
    bn_fin2<<<128, 256, 0, stream>>>(parts, gamma, beta, scsh);
    norm_kernel<<<(N_NODES * 32 + 255) / 256, 256, 0, stream>>>(out, scsh);
}

// Round 7
// 254.408 us; speedup vs baseline: 3.3607x; 1.0155x over previous
//
#include <hip/hip_runtime.h>

#define N_NODES 50000
#define N_EDGES 800000
#define D 128
#define BN_EPS 1e-5f
#define AGG_BLOCKS 2048
#define SCAN_BLOCKS 196   // 196*256 = 50176 >= N_NODES
#define CHUNKS 64
#define EPC (N_EDGES / CHUNKS)   // 12500 edges per chunk (< 65536: u16-safe)
#define HALF_BINS 25600          // node-range half
#define HALF_U32 12800           // u32 words per half (2 bins/word)

typedef short bf16x8 __attribute__((ext_vector_type(8)));
typedef float f32x4  __attribute__((ext_vector_type(4)));

// ---------------- workspace layout (bytes) ----------------
// cnt_in  @ 0        cnt_out @ 262144   row_ptr @ 524288
// rin     @ 1048576  rout    @ 1310720  scsh    @ 1576960  blk_sum @ 1579008
// csr_src @ 1581056 (3.2MB)  hwb(bf16 ushort[row][col]) @ 4800000 (12.8MB)
// parts   @ 17600000 (2MB)   pW @ 19697152 (32KB)  pWr @ 19729920 (32KB)
// histD   @ 19762688 (6.55MB)  histS @ 26316288 (6.55MB)  [end ~33.1MB]

// Privatized LDS histogram: block (chunk c, range r) counts keys in
// [r*25600, (r+1)*25600). Bins packed 2-per-u32 (u16 halves). NO global atomics.
__global__ __launch_bounds__(256) void hist_kernel(
        const int* __restrict__ keys, unsigned int* __restrict__ hist) {
    __shared__ unsigned int h[HALF_U32];
    int tid = threadIdx.x;
    int c = blockIdx.x, r = blockIdx.y;
    for (int j = tid; j < HALF_U32; j += 256) h[j] = 0u;
    __syncthreads();
    int base = c * EPC;
    int lo = r * HALF_BINS;
    for (int i = tid; i < EPC; i += 256) {
        int b = keys[base + i] - lo;
        if ((unsigned)b < (unsigned)HALF_BINS)
            atomicAdd(&h[b >> 1], 1u << ((b & 1) * 16));
    }
    __syncthreads();
    unsigned int* out = hist + ((size_t)(r * CHUNKS + c)) * HALF_U32;
    for (int j = tid; j < HALF_U32; j += 256) out[j] = h[j];
}

// Sum per-chunk histograms -> cnt arrays, AND replace hist in place with the
// exclusive chunk-prefix per bin (packed u16: counting-sort base offsets).
__global__ __launch_bounds__(256) void merge_kernel(
        unsigned int* __restrict__ histD, unsigned int* __restrict__ histS,
        int* __restrict__ cnt_in, int* __restrict__ cnt_out) {
    int q = blockIdx.x * 256 + threadIdx.x;      // 0..12799
    int r = blockIdx.y;                           // range half
    unsigned int* hist = blockIdx.z ? histS : histD;
    int* cnt = blockIdx.z ? cnt_out : cnt_in;
    unsigned int lo = 0, hi = 0;
    for (int c = 0; c < CHUNKS; c++) {
        size_t idx = ((size_t)(r * CHUNKS + c)) * HALF_U32 + q;
        unsigned int v = hist[idx];
        hist[idx] = lo | (hi << 16);             // exclusive prefix (u16-safe)
        lo += v & 0xffffu; hi += v >> 16;
    }
    int n0 = r * HALF_BINS + q * 2;
    cnt[n0]     = (int)lo;
    cnt[n0 + 1] = (int)hi;
}

__global__ __launch_bounds__(256) void scan1_kernel(
        const int* __restrict__ cnt_in, int* __restrict__ row_ptr, int* __restrict__ blk_sum) {
    __shared__ int sh[256];
    int t = threadIdx.x;
    int i = blockIdx.x * 256 + t;
    int v = cnt_in[i];                 // merge writes bins 0..51199 >= 50176, safe
    sh[t] = v;
    __syncthreads();
    int inc = v;
    #pragma unroll
    for (int off = 1; off < 256; off <<= 1) {
        int u = (t >= off) ? sh[t - off] : 0;
        __syncthreads();
        inc += u; sh[t] = inc;
        __syncthreads();
    }
    row_ptr[i] = inc - v;
    if (t == 255) blk_sum[blockIdx.x] = inc;
}

__global__ __launch_bounds__(256) void scan2_kernel(int* __restrict__ blk_sum, int* __restrict__ row_ptr) {
    __shared__ int sh[256];
    int t = threadIdx.x;
    int v = (t < SCAN_BLOCKS) ? blk_sum[t] : 0;
    sh[t] = v;
    __syncthreads();
    int inc = v;
    #pragma unroll
    for (int off = 1; off < 256; off <<= 1) {
        int u = (t >= off) ? sh[t - off] : 0;
        __syncthreads();
        inc += u; sh[t] = inc;
        __syncthreads();
    }
    if (t < SCAN_BLOCKS) blk_sum[t] = inc - v;
    if (t == 0) row_ptr[N_NODES] = N_EDGES;
}

__global__ __launch_bounds__(256) void scan3_kernel(
        const int* __restrict__ cnt_in, const int* __restrict__ cnt_out,
        const int* __restrict__ blk_sum, int* __restrict__ row_ptr,
        float* __restrict__ rin, float* __restrict__ rout) {
    int i = blockIdx.x * 256 + threadIdx.x;
    if (i < N_NODES) {
        row_ptr[i] = row_ptr[i] + blk_sum[blockIdx.x];
        int ci = cnt_in[i], co = cnt_out[i];
        rin[i]  = rsqrtf((float)(ci > 1 ? ci : 1));
        rout[i] = rsqrtf((float)(co > 1 ? co : 1));
    }
}

// Counting-sort CSR fill: LDS rank counters (atomic-return, packed u16),
// position = row_ptr[d] + chunk_prefix[c][d] + rank. NO global atomics.
__global__ __launch_bounds__(512) void fill2_kernel(
        const int* __restrict__ src, const int* __restrict__ dst,
        const int* __restrict__ row_ptr, const unsigned int* __restrict__ histP,
        int* __restrict__ csr_src) {
    __shared__ unsigned int h[HALF_U32];
    int tid = threadIdx.x;
    int c = blockIdx.x;
    int base = c * EPC;
    for (int r = 0; r < 2; r++) {
        for (int j = tid; j < HALF_U32; j += 512) h[j] = 0u;
        __syncthreads();
        int lo = r * HALF_BINS;
        const unsigned int* pre_c = histP + ((size_t)(r * CHUNKS + c)) * HALF_U32;
        for (int i = tid; i < EPC; i += 512) {
            int d = dst[base + i];
            int b = d - lo;
            if ((unsigned)b < (unsigned)HALF_BINS) {
                int sh = (b & 1) * 16;
                unsigned int old = atomicAdd(&h[b >> 1], 1u << sh);
                unsigned int rank = (old >> sh) & 0xffffu;
                unsigned int pre = (pre_c[b >> 1] >> sh) & 0xffffu;
                int p = row_ptr[d] + (int)(pre + rank);
                csr_src[p] = src[base + i];
            }
        }
        __syncthreads();
    }
}

__device__ __forceinline__ unsigned int pack_rne(float a, float b) {
    unsigned int ua = __float_as_uint(a); ua += 0x7fffu + ((ua >> 16) & 1u);
    unsigned int ub = __float_as_uint(b); ub += 0x7fffu + ((ub >> 16) & 1u);
    return (ua >> 16) | (ub & 0xffff0000u);
}

// Pre-pack W and Wr into MFMA B-fragment order (bf16).
__global__ __launch_bounds__(256) void pack_w(
        const float* __restrict__ W, const float* __restrict__ Wr,
        uint4* __restrict__ pW, uint4* __restrict__ pWr) {
    int t = blockIdx.x * 256 + threadIdx.x;      // 0..4095
    const float* S = (t & 2048) ? Wr : W;
    uint4* Dst     = (t & 2048) ? pWr : pW;
    int e = t & 2047;
    int lane = e & 63, ks = (e >> 6) & 3, ct = e >> 8;
    int n  = ct * 16 + (lane & 15);
    int k0 = ks * 32 + (lane >> 4) * 8;
    float v[8];
    #pragma unroll
    for (int j = 0; j < 8; j++) v[j] = S[(k0 + j) * D + n];
    uint4 r;
    r.x = pack_rne(v[0], v[1]); r.y = pack_rne(v[2], v[3]);
    r.z = pack_rne(v[4], v[5]); r.w = pack_rne(v[6], v[7]);
    Dst[e] = r;
}

// MFMA dual GEMM. Wave owns 16 node-rows, computes all 128 cols of both matrices.
__global__ __launch_bounds__(256) void gemm_mfma(
        const float* __restrict__ x, const uint4* __restrict__ pW,
        const uint4* __restrict__ pWr, const float* __restrict__ br,
        const float* __restrict__ rout, unsigned short* __restrict__ hwb,
        float* __restrict__ res) {
    int tid = threadIdx.x, wid = tid >> 6, lane = tid & 63;
    int quad = lane >> 4, l15 = lane & 15;
    int r0 = blockIdx.x * 64 + wid * 16;
    int arow = r0 + l15; if (arow > N_NODES - 1) arow = N_NODES - 1;
    union { bf16x8 v; uint4 u; } A[4];
    const float* xrow = x + (size_t)arow * D;
    #pragma unroll
    for (int ks = 0; ks < 4; ks++) {
        float4 f0 = *(const float4*)(xrow + ks * 32 + quad * 8);
        float4 f1 = *(const float4*)(xrow + ks * 32 + quad * 8 + 4);
        A[ks].u.x = pack_rne(f0.x, f0.y); A[ks].u.y = pack_rne(f0.z, f0.w);
        A[ks].u.z = pack_rne(f1.x, f1.y); A[ks].u.w = pack_rne(f1.z, f1.w);
    }
    f32x4 accW[8], accR[8];
    #pragma unroll
    for (int ct = 0; ct < 8; ct++) { accW[ct] = (f32x4)0.f; accR[ct] = (f32x4)0.f; }
    #pragma unroll
    for (int ct = 0; ct < 8; ct++) {
        #pragma unroll
        for (int ks = 0; ks < 4; ks++) {
            union { bf16x8 v; uint4 u; } Bw, Br2;
            Bw.u  = pW [(ct * 4 + ks) * 64 + lane];
            Br2.u = pWr[(ct * 4 + ks) * 64 + lane];
            accW[ct] = __builtin_amdgcn_mfma_f32_16x16x32_bf16(A[ks].v, Bw.v,  accW[ct], 0, 0, 0);
            accR[ct] = __builtin_amdgcn_mfma_f32_16x16x32_bf16(A[ks].v, Br2.v, accR[ct], 0, 0, 0);
        }
    }
    float ro[4]; int rowok[4];
    #pragma unroll
    for (int reg = 0; reg < 4; reg++) {
        int row = r0 + quad * 4 + reg;
        rowok[reg] = row < N_NODES;
        ro[reg] = rout[rowok[reg] ? row : N_NODES - 1];
    }
    #pragma unroll
    for (int ct = 0; ct < 8; ct++) {
        int c = ct * 16 + l15;
        float brv = br[c];
        #pragma unroll
        for (int reg = 0; reg < 4; reg++) {
            int row = r0 + quad * 4 + reg;
            if (rowok[reg]) {
                float hv = accW[ct][reg] * ro[reg];
                unsigned int u = __float_as_uint(hv);
                u += 0x7fffu + ((u >> 16) & 1u);
                hwb[(size_t)row * D + c] = (unsigned short)(u >> 16);
                res[(size_t)row * D + c] = fmaxf(accR[ct][reg] + brv, 0.f);
            }
        }
    }
}

__device__ __forceinline__ float bf_lo(unsigned int v) { return __uint_as_float(v << 16); }
__device__ __forceinline__ float bf_hi(unsigned int v) { return __uint_as_float(v & 0xffff0000u); }

__device__ __forceinline__ void acc8(float* a, const uint4 v) {
    a[0] += bf_lo(v.x); a[1] += bf_hi(v.x);
    a[2] += bf_lo(v.y); a[3] += bf_hi(v.y);
    a[4] += bf_lo(v.z); a[5] += bf_hi(v.z);
    a[6] += bf_lo(v.w); a[7] += bf_hi(v.w);
}
__device__ __forceinline__ void acc8m(float* a, const uint4 v, float m) {
    a[0] = fmaf(m, bf_lo(v.x), a[0]); a[1] = fmaf(m, bf_hi(v.x), a[1]);
    a[2] = fmaf(m, bf_lo(v.y), a[2]); a[3] = fmaf(m, bf_hi(v.y), a[3]);
    a[4] = fmaf(m, bf_lo(v.z), a[4]); a[5] = fmaf(m, bf_hi(v.z), a[5]);
    a[6] = fmaf(m, bf_lo(v.w), a[6]); a[7] = fmaf(m, bf_hi(v.w), a[7]);
}

__device__ __forceinline__ int sel4(int qg, int i0, int i1, int i2, int i3) {
    int a = (qg & 1) ? i1 : i0;
    int b = (qg & 1) ? i3 : i2;
    return (qg & 2) ? b : a;
}

// Per-dst aggregation; 4 rows per gather instruction, no global atomics.
__global__ __launch_bounds__(256) void agg_kernel(
        const unsigned int* __restrict__ hwb, const int* __restrict__ row_ptr,
        const int* __restrict__ csr_src, const float* __restrict__ rin,
        const float* __restrict__ bias, float* __restrict__ y,
        float* __restrict__ parts) {
    __shared__ float red[4 * 256];
    int tid = threadIdx.x;
    int lane = tid & 63, wid = tid >> 6;
    int wave = blockIdx.x * 4 + wid;
    int nw = AGG_BLOCKS * 4;
    int qg = lane >> 4;
    int ql = lane & 15;
    float s1[8] = {0,0,0,0,0,0,0,0}, s2[8] = {0,0,0,0,0,0,0,0};
    float4 bv0, bv1;
    if (lane < 16) {
        bv0 = ((const float4*)bias)[2 * lane];
        bv1 = ((const float4*)bias)[2 * lane + 1];
    }
    for (int n = wave; n < N_NODES; n += nw) {
        int e0 = row_ptr[n], e1 = row_ptr[n + 1];
        float a[8] = {0,0,0,0,0,0,0,0};
        for (int j0 = e0; j0 < e1; j0 += 64) {
            int cnt = e1 - j0; if (cnt > 64) cnt = 64;
            int myidx = (lane < cnt) ? csr_src[j0 + lane] : 0;
            int i = 0;
            for (; i + 16 <= cnt; i += 16) {
                int p0 = sel4(qg, __builtin_amdgcn_readlane(myidx, i + 0),
                                  __builtin_amdgcn_readlane(myidx, i + 1),
                                  __builtin_amdgcn_readlane(myidx, i + 2),
                                  __builtin_amdgcn_readlane(myidx, i + 3));
                int p1 = sel4(qg, __builtin_amdgcn_readlane(myidx, i + 4),
                                  __builtin_amdgcn_readlane(myidx, i + 5),
                                  __builtin_amdgcn_readlane(myidx, i + 6),
                                  __builtin_amdgcn_readlane(myidx, i + 7));
                int p2 = sel4(qg, __builtin_amdgcn_readlane(myidx, i + 8),
                                  __builtin_amdgcn_readlane(myidx, i + 9),
                                  __builtin_amdgcn_readlane(myidx, i + 10),
                                  __builtin_amdgcn_readlane(myidx, i + 11));
                int p3 = sel4(qg, __builtin_amdgcn_readlane(myidx, i + 12),
                                  __builtin_amdgcn_readlane(myidx, i + 13),
                                  __builtin_amdgcn_readlane(myidx, i + 14),
                                  __builtin_amdgcn_readlane(myidx, i + 15));
                uint4 v0 = *((const uint4*)(hwb + (size_t)p0 * 64) + ql);
                uint4 v1 = *((const uint4*)(hwb + (size_t)p1 * 64) + ql);
                uint4 v2 = *((const uint4*)(hwb + (size_t)p2 * 64) + ql);
                uint4 v3 = *((const uint4*)(hwb + (size_t)p3 * 64) + ql);
                acc8(a, v0); acc8(a, v1); acc8(a, v2); acc8(a, v3);
            }
            for (; i + 4 <= cnt; i += 4) {
                int p0 = sel4(qg, __builtin_amdgcn_readlane(myidx, i + 0),
                                  __builtin_amdgcn_readlane(myidx, i + 1),
                                  __builtin_amdgcn_readlane(myidx, i + 2),
                                  __builtin_amdgcn_readlane(myidx, i + 3));
                uint4 v0 = *((const uint4*)(hwb + (size_t)p0 * 64) + ql);
                acc8(a, v0);
            }
            int t = cnt - i;
            if (t > 0) {
                int lim = cnt - 1;
                int j1 = i + 1 <= lim ? i + 1 : lim;
                int j2 = i + 2 <= lim ? i + 2 : lim;
                int p0 = sel4(qg, __builtin_amdgcn_readlane(myidx, i),
                                  __builtin_amdgcn_readlane(myidx, j1),
                                  __builtin_amdgcn_readlane(myidx, j2),
                                  __builtin_amdgcn_readlane(myidx, lim));
                uint4 v0 = *((const uint4*)(hwb + (size_t)p0 * 64) + ql);
                float m = (qg < t) ? 1.f : 0.f;
                acc8m(a, v0, m);
            }
        }
        #pragma unroll
        for (int k = 0; k < 8; k++) {
            a[k] += __shfl_xor(a[k], 16);
            a[k] += __shfl_xor(a[k], 32);
        }
        if (lane < 16) {
            float ri = rin[n];
            float4* yv = (float4*)(y + (size_t)n * D);
            float4 r0 = yv[2 * lane], r1 = yv[2 * lane + 1];
            float o[8];
            o[0] = fmaxf(a[0] * ri + bv0.x, 0.f) + r0.x;
            o[1] = fmaxf(a[1] * ri + bv0.y, 0.f) + r0.y;
            o[2] = fmaxf(a[2] * ri + bv0.z, 0.f) + r0.z;
            o[3] = fmaxf(a[3] * ri + bv0.w, 0.f) + r0.w;
            o[4] = fmaxf(a[4] * ri + bv1.x, 0.f) + r1.x;
            o[5] = fmaxf(a[5] * ri + bv1.y, 0.f) + r1.y;
            o[6] = fmaxf(a[6] * ri + bv1.z, 0.f) + r1.z;
            o[7] = fmaxf(a[7] * ri + bv1.w, 0.f) + r1.w;
            yv[2 * lane]     = make_float4(o[0], o[1], o[2], o[3]);
            yv[2 * lane + 1] = make_float4(o[4], o[5], o[6], o[7]);
            #pragma unroll
            for (int k = 0; k < 8; k++) { s1[k] += o[k]; s2[k] += o[k] * o[k]; }
        }
    }
    if (lane < 16) {
        int c0 = lane * 8;
        #pragma unroll
        for (int k = 0; k < 8; k++) {
            red[wid * 256 + c0 + k]       = s1[k];
            red[wid * 256 + 128 + c0 + k] = s2[k];
        }
    }
    __syncthreads();
    if (tid < 256) {
        float v = red[tid] + red[256 + tid] + red[512 + tid] + red[768 + tid];
        parts[(size_t)blockIdx.x * 256 + tid] = v;
    }
}

__global__ __launch_bounds__(256) void bn_fin2(
        const float* __restrict__ parts, const float* __restrict__ gamma,
        const float* __restrict__ beta, float* __restrict__ scsh) {
    __shared__ float rs1[256], rs2[256];
    int c = blockIdx.x, t = threadIdx.x;
    float s1 = 0.f, s2 = 0.f;
    for (int b = t; b < AGG_BLOCKS; b += 256) {
        s1 += parts[(size_t)b * 256 + c];
        s2 += parts[(size_t)b * 256 + 128 + c];
    }
    rs1[t] = s1; rs2[t] = s2;
    __syncthreads();
    for (int off = 128; off > 0; off >>= 1) {
        if (t < off) { rs1[t] += rs1[t + off]; rs2[t] += rs2[t + off]; }
        __syncthreads();
    }
    if (t == 0) {
        const float invN = 1.0f / (float)N_NODES;
        float mean = rs1[0] * invN;
        float var  = rs2[0] * invN - mean * mean;
        float sc = gamma[c] * rsqrtf(var + BN_EPS);
        scsh[c] = sc;
        scsh[128 + c] = beta[c] - mean * sc;
    }
}

__global__ void norm_kernel(float* __restrict__ y, const float* __restrict__ scsh) {
    int i = blockIdx.x * blockDim.x + threadIdx.x;
    if (i < N_NODES * 32) {
        float4 v = ((float4*)y)[i];
        int c = (i & 31) * 4;
        v.x = v.x * scsh[c]     + scsh[128 + c];
        v.y = v.y * scsh[c + 1] + scsh[128 + c + 1];
        v.z = v.z * scsh[c + 2] + scsh[128 + c + 2];
        v.w = v.w * scsh[c + 3] + scsh[128 + c + 3];
        ((float4*)y)[i] = v;
    }
}

extern "C" void kernel_launch(void* const* d_in, const int* in_sizes, int n_in,
                              void* d_out, int out_size, void* d_ws, size_t ws_size,
                              hipStream_t stream) {
    const float* x     = (const float*)d_in[0];
    const int*   src   = (const int*)d_in[1];
    const int*   dst   = (const int*)d_in[2];
    const float* W     = (const float*)d_in[3];
    const float* b     = (const float*)d_in[4];
    const float* Wr    = (const float*)d_in[5];
    const float* br    = (const float*)d_in[6];
    const float* gamma = (const float*)d_in[7];
    const float* beta  = (const float*)d_in[8];
    float* out = (float*)d_out;

    char* ws = (char*)d_ws;
    int*   cnt_in  = (int*)(ws + 0);
    int*   cnt_out = (int*)(ws + 262144);
    int*   row_ptr = (int*)(ws + 524288);
    float* rin     = (float*)(ws + 1048576);
    float* rout    = (float*)(ws + 1310720);
    float* scsh    = (float*)(ws + 1576960);
    int*   blk_sum = (int*)(ws + 1579008);
    int*   csr_src = (int*)(ws + 1581056);
    unsigned short* hwb = (unsigned short*)(ws + 4800000);
    float* parts   = (float*)(ws + 17600000);
    uint4* pW      = (uint4*)(ws + 19697152);
    uint4* pWr     = (uint4*)(ws + 19729920);
    unsigned int* histD = (unsigned int*)(ws + 19762688);
    unsigned int* histS = (unsigned int*)(ws + 26316288);

    hist_kernel<<<dim3(CHUNKS, 2), 256, 0, stream>>>(dst, histD);
    hist_kernel<<<dim3(CHUNKS, 2), 256, 0, stream>>>(src, histS);
    merge_kernel<<<dim3(HALF_U32 / 256, 2, 2), 256, 0, stream>>>(histD, histS, cnt_in, cnt_out);
    scan1_kernel<<<SCAN_BLOCKS, 256, 0, stream>>>(cnt_in, row_ptr, blk_sum);
    scan2_kernel<<<1, 256, 0, stream>>>(blk_sum, row_ptr);
    scan3_kernel<<<SCAN_BLOCKS, 256, 0, stream>>>(cnt_in, cnt_out, blk_sum, row_ptr, rin, rout);
    fill2_kernel<<<CHUNKS, 512, 0, stream>>>(src, dst, row_ptr, histD, csr_src);
    pack_w<<<16, 256, 0, stream>>>(W, Wr, pW, pWr);
    gemm_mfma<<<(N_NODES + 63) / 64, 256, 0, stream>>>(x, pW, pWr, br, rout, hwb, out);
    agg_kernel<<<AGG_BLOCKS, 256, 0, stream>>>((const unsigned int*)hwb, row_ptr, csr_src, rin, b, out, parts);
    bn_fin2<<<128, 256, 0, stream>>>(parts, gamma, beta, scsh);
    norm_kernel<<<(N_NODES * 32 + 255) / 256, 256, 0, stream>>>(out, scsh);
}

// Round 9
// 246.351 us; speedup vs baseline: 3.4706x; 1.0327x over previous
//
#include <hip/hip_runtime.h>

#define N_NODES 50000
#define N_EDGES 800000
#define D 128
#define BN_EPS 1e-5f
#define AGG_BLOCKS 2048
#define SCAN_BLOCKS 196   // 196*256 = 50176 >= N_NODES
#define CHUNKS 64
#define EPC (N_EDGES / CHUNKS)   // 12500 edges per chunk (< 65536: u16-safe)
#define HALF_BINS 25600          // node-range half
#define HALF_U32 12800           // u32 words per half (2 bins/word)

typedef short bf16x8 __attribute__((ext_vector_type(8)));
typedef float f32x4  __attribute__((ext_vector_type(4)));
typedef unsigned int u32x4 __attribute__((ext_vector_type(4)));   // native vec for nontemporal builtins

// ---------------- workspace layout (bytes) ----------------
// cnt_in  @ 0        cnt_out @ 262144   row_ptr @ 524288
// rin     @ 1048576  rout    @ 1310720  scsh    @ 1576960  blk_sum @ 1579008
// csr_src @ 1581056 (3.2MB)  hwb(bf16 ushort[row][col]) @ 4800000 (12.8MB)
// parts   @ 17600000 (2MB)   pW @ 19697152 (32KB)  pWr @ 19729920 (32KB)
// histD   @ 19762688 (6.55MB)  histS @ 26316288 (6.55MB)  [end ~33.1MB]
// resb(bf16 residual, 12.8MB) overlays histD/histS @ 19762688 (dead after fill2)

// Privatized LDS histogram, both keys in one launch: grid (chunk, range, key).
__global__ __launch_bounds__(256) void hist_kernel(
        const int* __restrict__ dst, const int* __restrict__ src,
        unsigned int* __restrict__ histD, unsigned int* __restrict__ histS) {
    __shared__ unsigned int h[HALF_U32];
    int tid = threadIdx.x;
    int c = blockIdx.x, r = blockIdx.y;
    const int* keys = blockIdx.z ? src : dst;
    unsigned int* hist = blockIdx.z ? histS : histD;
    for (int j = tid; j < HALF_U32; j += 256) h[j] = 0u;
    __syncthreads();
    int base = c * EPC;
    int lo = r * HALF_BINS;
    for (int i = tid; i < EPC; i += 256) {
        int b = keys[base + i] - lo;
        if ((unsigned)b < (unsigned)HALF_BINS)
            atomicAdd(&h[b >> 1], 1u << ((b & 1) * 16));
    }
    __syncthreads();
    unsigned int* out = hist + ((size_t)(r * CHUNKS + c)) * HALF_U32;
    for (int j = tid; j < HALF_U32; j += 256) out[j] = h[j];
}

// Sum per-chunk histograms -> cnt arrays, AND replace hist in place with the
// exclusive chunk-prefix per bin (packed u16: counting-sort base offsets).
__global__ __launch_bounds__(256) void merge_kernel(
        unsigned int* __restrict__ histD, unsigned int* __restrict__ histS,
        int* __restrict__ cnt_in, int* __restrict__ cnt_out) {
    int q = blockIdx.x * 256 + threadIdx.x;      // 0..12799
    int r = blockIdx.y;                           // range half
    unsigned int* hist = blockIdx.z ? histS : histD;
    int* cnt = blockIdx.z ? cnt_out : cnt_in;
    unsigned int lo = 0, hi = 0;
    for (int c = 0; c < CHUNKS; c++) {
        size_t idx = ((size_t)(r * CHUNKS + c)) * HALF_U32 + q;
        unsigned int v = hist[idx];
        hist[idx] = lo | (hi << 16);             // exclusive prefix (u16-safe)
        lo += v & 0xffffu; hi += v >> 16;
    }
    int n0 = r * HALF_BINS + q * 2;
    cnt[n0]     = (int)lo;
    cnt[n0 + 1] = (int)hi;
}

__global__ __launch_bounds__(256) void scan1_kernel(
        const int* __restrict__ cnt_in, int* __restrict__ row_ptr, int* __restrict__ blk_sum) {
    __shared__ int sh[256];
    int t = threadIdx.x;
    int i = blockIdx.x * 256 + t;
    int v = cnt_in[i];                 // merge writes bins 0..51199 >= 50176, safe
    sh[t] = v;
    __syncthreads();
    int inc = v;
    #pragma unroll
    for (int off = 1; off < 256; off <<= 1) {
        int u = (t >= off) ? sh[t - off] : 0;
        __syncthreads();
        inc += u; sh[t] = inc;
        __syncthreads();
    }
    row_ptr[i] = inc - v;
    if (t == 255) blk_sum[blockIdx.x] = inc;
}

__global__ __launch_bounds__(256) void scan2_kernel(int* __restrict__ blk_sum, int* __restrict__ row_ptr) {
    __shared__ int sh[256];
    int t = threadIdx.x;
    int v = (t < SCAN_BLOCKS) ? blk_sum[t] : 0;
    sh[t] = v;
    __syncthreads();
    int inc = v;
    #pragma unroll
    for (int off = 1; off < 256; off <<= 1) {
        int u = (t >= off) ? sh[t - off] : 0;
        __syncthreads();
        inc += u; sh[t] = inc;
        __syncthreads();
    }
    if (t < SCAN_BLOCKS) blk_sum[t] = inc - v;
    if (t == 0) row_ptr[N_NODES] = N_EDGES;
}

__global__ __launch_bounds__(256) void scan3_kernel(
        const int* __restrict__ cnt_in, const int* __restrict__ cnt_out,
        const int* __restrict__ blk_sum, int* __restrict__ row_ptr,
        float* __restrict__ rin, float* __restrict__ rout) {
    int i = blockIdx.x * 256 + threadIdx.x;
    if (i < N_NODES) {
        row_ptr[i] = row_ptr[i] + blk_sum[blockIdx.x];
        int ci = cnt_in[i], co = cnt_out[i];
        rin[i]  = rsqrtf((float)(ci > 1 ? ci : 1));
        rout[i] = rsqrtf((float)(co > 1 ? co : 1));
    }
}

// Counting-sort CSR fill: LDS rank counters (atomic-return, packed u16),
// position = row_ptr[d] + chunk_prefix[c][d] + rank. NO global atomics.
__global__ __launch_bounds__(512) void fill2_kernel(
        const int* __restrict__ src, const int* __restrict__ dst,
        const int* __restrict__ row_ptr, const unsigned int* __restrict__ histP,
        int* __restrict__ csr_src) {
    __shared__ unsigned int h[HALF_U32];
    int tid = threadIdx.x;
    int c = blockIdx.x;
    int base = c * EPC;
    for (int r = 0; r < 2; r++) {
        for (int j = tid; j < HALF_U32; j += 512) h[j] = 0u;
        __syncthreads();
        int lo = r * HALF_BINS;
        const unsigned int* pre_c = histP + ((size_t)(r * CHUNKS + c)) * HALF_U32;
        for (int i = tid; i < EPC; i += 512) {
            int d = dst[base + i];
            int b = d - lo;
            if ((unsigned)b < (unsigned)HALF_BINS) {
                int sh = (b & 1) * 16;
                unsigned int old = atomicAdd(&h[b >> 1], 1u << sh);
                unsigned int rank = (old >> sh) & 0xffffu;
                unsigned int pre = (pre_c[b >> 1] >> sh) & 0xffffu;
                int p = row_ptr[d] + (int)(pre + rank);
                csr_src[p] = src[base + i];
            }
        }
        __syncthreads();
    }
}

__device__ __forceinline__ unsigned int pack_rne(float a, float b) {
    unsigned int ua = __float_as_uint(a); ua += 0x7fffu + ((ua >> 16) & 1u);
    unsigned int ub = __float_as_uint(b); ub += 0x7fffu + ((ub >> 16) & 1u);
    return (ua >> 16) | (ub & 0xffff0000u);
}
__device__ __forceinline__ unsigned short pack1_rne(float a) {
    unsigned int ua = __float_as_uint(a); ua += 0x7fffu + ((ua >> 16) & 1u);
    return (unsigned short)(ua >> 16);
}

// Pre-pack W and Wr into MFMA B-fragment order (bf16).
__global__ __launch_bounds__(256) void pack_w(
        const float* __restrict__ W, const float* __restrict__ Wr,
        uint4* __restrict__ pW, uint4* __restrict__ pWr) {
    int t = blockIdx.x * 256 + threadIdx.x;      // 0..4095
    const float* S = (t & 2048) ? Wr : W;
    uint4* Dst     = (t & 2048) ? pWr : pW;
    int e = t & 2047;
    int lane = e & 63, ks = (e >> 6) & 3, ct = e >> 8;
    int n  = ct * 16 + (lane & 15);
    int k0 = ks * 32 + (lane >> 4) * 8;
    float v[8];
    #pragma unroll
    for (int j = 0; j < 8; j++) v[j] = S[(k0 + j) * D + n];
    uint4 r;
    r.x = pack_rne(v[0], v[1]); r.y = pack_rne(v[2], v[3]);
    r.z = pack_rne(v[4], v[5]); r.w = pack_rne(v[6], v[7]);
    Dst[e] = r;
}

// MFMA dual GEMM, coalesced A-staging through LDS (bf16).
// hwb = bf16(rout*(x@W)); resb = bf16(relu(x@Wr+br)). Both ushort[row][col].
__global__ __launch_bounds__(256) void gemm_mfma(
        const float* __restrict__ x, const uint4* __restrict__ pW,
        const uint4* __restrict__ pWr, const float* __restrict__ br,
        const float* __restrict__ rout, unsigned short* __restrict__ hwb,
        unsigned short* __restrict__ resb) {
    __shared__ unsigned short xs[64][136];       // +8 pad: row stride 272B -> 2-way banks (free)
    int tid = threadIdx.x, wid = tid >> 6, lane = tid & 63;
    int quad = lane >> 4, l15 = lane & 15;
    int r0b = blockIdx.x * 64;
    const float4* xg = (const float4*)(x + (size_t)r0b * D);
    int maxidx = (N_NODES - r0b) * (D / 4);
    #pragma unroll
    for (int i = 0; i < 8; i++) {
        int idx = tid + 256 * i;                 // coalesced float4 over 64 rows
        float4 v = (idx < maxidx) ? xg[idx] : make_float4(0.f, 0.f, 0.f, 0.f);
        int row = idx >> 5, c0 = (idx & 31) * 4;
        *(unsigned int*)&xs[row][c0]     = pack_rne(v.x, v.y);
        *(unsigned int*)&xs[row][c0 + 2] = pack_rne(v.z, v.w);
    }
    __syncthreads();
    int wrow0 = wid * 16;
    bf16x8 A[4];
    #pragma unroll
    for (int ks = 0; ks < 4; ks++)
        A[ks] = *(const bf16x8*)&xs[wrow0 + l15][ks * 32 + quad * 8];
    f32x4 accW[8], accR[8];
    #pragma unroll
    for (int ct = 0; ct < 8; ct++) { accW[ct] = (f32x4)0.f; accR[ct] = (f32x4)0.f; }
    #pragma unroll
    for (int ct = 0; ct < 8; ct++) {
        #pragma unroll
        for (int ks = 0; ks < 4; ks++) {
            union { bf16x8 v; uint4 u; } Bw, Br2;
            Bw.u  = pW [(ct * 4 + ks) * 64 + lane];
            Br2.u = pWr[(ct * 4 + ks) * 64 + lane];
            accW[ct] = __builtin_amdgcn_mfma_f32_16x16x32_bf16(A[ks], Bw.v,  accW[ct], 0, 0, 0);
            accR[ct] = __builtin_amdgcn_mfma_f32_16x16x32_bf16(A[ks], Br2.v, accR[ct], 0, 0, 0);
        }
    }
    // C/D layout: col = ct*16 + l15, row = r0 + quad*4 + reg
    int r0 = r0b + wrow0;
    float ro[4]; int rowok[4];
    #pragma unroll
    for (int reg = 0; reg < 4; reg++) {
        int row = r0 + quad * 4 + reg;
        rowok[reg] = row < N_NODES;
        ro[reg] = rout[rowok[reg] ? row : N_NODES - 1];
    }
    #pragma unroll
    for (int ct = 0; ct < 8; ct++) {
        int c = ct * 16 + l15;
        float brv = br[c];
        #pragma unroll
        for (int reg = 0; reg < 4; reg++) {
            int row = r0 + quad * 4 + reg;
            if (rowok[reg]) {
                hwb [(size_t)row * D + c] = pack1_rne(accW[ct][reg] * ro[reg]);
                resb[(size_t)row * D + c] = pack1_rne(fmaxf(accR[ct][reg] + brv, 0.f));
            }
        }
    }
}

__device__ __forceinline__ float bf_lo(unsigned int v) { return __uint_as_float(v << 16); }
__device__ __forceinline__ float bf_hi(unsigned int v) { return __uint_as_float(v & 0xffff0000u); }

__device__ __forceinline__ void acc8(float* a, const uint4 v) {
    a[0] += bf_lo(v.x); a[1] += bf_hi(v.x);
    a[2] += bf_lo(v.y); a[3] += bf_hi(v.y);
    a[4] += bf_lo(v.z); a[5] += bf_hi(v.z);
    a[6] += bf_lo(v.w); a[7] += bf_hi(v.w);
}
__device__ __forceinline__ void acc8m(float* a, const uint4 v, float m) {
    a[0] = fmaf(m, bf_lo(v.x), a[0]); a[1] = fmaf(m, bf_hi(v.x), a[1]);
    a[2] = fmaf(m, bf_lo(v.y), a[2]); a[3] = fmaf(m, bf_hi(v.y), a[3]);
    a[4] = fmaf(m, bf_lo(v.z), a[4]); a[5] = fmaf(m, bf_hi(v.z), a[5]);
    a[6] = fmaf(m, bf_lo(v.w), a[6]); a[7] = fmaf(m, bf_hi(v.w), a[7]);
}

__device__ __forceinline__ int sel4(int qg, int i0, int i1, int i2, int i3) {
    int a = (qg & 1) ? i1 : i0;
    int b = (qg & 1) ? i3 : i2;
    return (qg & 2) ? b : a;
}

// Per-dst aggregation; 4 rows per gather instruction, no global atomics.
// Residual read early (bf16, nontemporal); csr stream nontemporal to keep
// L2 for the hwb gather working set.
__global__ __launch_bounds__(256) void agg_kernel(
        const unsigned int* __restrict__ hwb, const int* __restrict__ row_ptr,
        const int* __restrict__ csr_src, const float* __restrict__ rin,
        const float* __restrict__ bias, const unsigned short* __restrict__ resb,
        float* __restrict__ y, float* __restrict__ parts) {
    __shared__ float red[4 * 256];
    int tid = threadIdx.x;
    int lane = tid & 63, wid = tid >> 6;
    int wave = blockIdx.x * 4 + wid;
    int nw = AGG_BLOCKS * 4;
    int qg = lane >> 4;
    int ql = lane & 15;
    float s1[8] = {0,0,0,0,0,0,0,0}, s2[8] = {0,0,0,0,0,0,0,0};
    float4 bv0, bv1;
    if (lane < 16) {
        bv0 = ((const float4*)bias)[2 * lane];
        bv1 = ((const float4*)bias)[2 * lane + 1];
    }
    for (int n = wave; n < N_NODES; n += nw) {
        int e0 = row_ptr[n], e1 = row_ptr[n + 1];
        u32x4 rv4 = (u32x4)0u;
        if (lane < 16)
            rv4 = __builtin_nontemporal_load((const u32x4*)(resb + (size_t)n * D) + lane);
        float a[8] = {0,0,0,0,0,0,0,0};
        for (int j0 = e0; j0 < e1; j0 += 64) {
            int cnt = e1 - j0; if (cnt > 64) cnt = 64;
            int myidx = (lane < cnt) ? __builtin_nontemporal_load(csr_src + j0 + lane) : 0;
            int i = 0;
            for (; i + 16 <= cnt; i += 16) {
                int p0 = sel4(qg, __builtin_amdgcn_readlane(myidx, i + 0),
                                  __builtin_amdgcn_readlane(myidx, i + 1),
                                  __builtin_amdgcn_readlane(myidx, i + 2),
                                  __builtin_amdgcn_readlane(myidx, i + 3));
                int p1 = sel4(qg, __builtin_amdgcn_readlane(myidx, i + 4),
                                  __builtin_amdgcn_readlane(myidx, i + 5),
                                  __builtin_amdgcn_readlane(myidx, i + 6),
                                  __builtin_amdgcn_readlane(myidx, i + 7));
                int p2 = sel4(qg, __builtin_amdgcn_readlane(myidx, i + 8),
                                  __builtin_amdgcn_readlane(myidx, i + 9),
                                  __builtin_amdgcn_readlane(myidx, i + 10),
                                  __builtin_amdgcn_readlane(myidx, i + 11));
                int p3 = sel4(qg, __builtin_amdgcn_readlane(myidx, i + 12),
                                  __builtin_amdgcn_readlane(myidx, i + 13),
                                  __builtin_amdgcn_readlane(myidx, i + 14),
                                  __builtin_amdgcn_readlane(myidx, i + 15));
                uint4 v0 = *((const uint4*)(hwb + (size_t)p0 * 64) + ql);
                uint4 v1 = *((const uint4*)(hwb + (size_t)p1 * 64) + ql);
                uint4 v2 = *((const uint4*)(hwb + (size_t)p2 * 64) + ql);
                uint4 v3 = *((const uint4*)(hwb + (size_t)p3 * 64) + ql);
                acc8(a, v0); acc8(a, v1); acc8(a, v2); acc8(a, v3);
            }
            for (; i + 4 <= cnt; i += 4) {
                int p0 = sel4(qg, __builtin_amdgcn_readlane(myidx, i + 0),
                                  __builtin_amdgcn_readlane(myidx, i + 1),
                                  __builtin_amdgcn_readlane(myidx, i + 2),
                                  __builtin_amdgcn_readlane(myidx, i + 3));
                uint4 v0 = *((const uint4*)(hwb + (size_t)p0 * 64) + ql);
                acc8(a, v0);
            }
            int t = cnt - i;
            if (t > 0) {
                int lim = cnt - 1;
                int j1 = i + 1 <= lim ? i + 1 : lim;
                int j2 = i + 2 <= lim ? i + 2 : lim;
                int p0 = sel4(qg, __builtin_amdgcn_readlane(myidx, i),
                                  __builtin_amdgcn_readlane(myidx, j1),
                                  __builtin_amdgcn_readlane(myidx, j2),
                                  __builtin_amdgcn_readlane(myidx, lim));
                uint4 v0 = *((const uint4*)(hwb + (size_t)p0 * 64) + ql);
                float m = (qg < t) ? 1.f : 0.f;
                acc8m(a, v0, m);
            }
        }
        #pragma unroll
        for (int k = 0; k < 8; k++) {
            a[k] += __shfl_xor(a[k], 16);
            a[k] += __shfl_xor(a[k], 32);
        }
        if (lane < 16) {
            float ri = rin[n];
            float o[8];
            o[0] = fmaxf(a[0] * ri + bv0.x, 0.f) + bf_lo(rv4.x);
            o[1] = fmaxf(a[1] * ri + bv0.y, 0.f) + bf_hi(rv4.x);
            o[2] = fmaxf(a[2] * ri + bv0.z, 0.f) + bf_lo(rv4.y);
            o[3] = fmaxf(a[3] * ri + bv0.w, 0.f) + bf_hi(rv4.y);
            o[4] = fmaxf(a[4] * ri + bv1.x, 0.f) + bf_lo(rv4.z);
            o[5] = fmaxf(a[5] * ri + bv1.y, 0.f) + bf_hi(rv4.z);
            o[6] = fmaxf(a[6] * ri + bv1.z, 0.f) + bf_lo(rv4.w);
            o[7] = fmaxf(a[7] * ri + bv1.w, 0.f) + bf_hi(rv4.w);
            float4* yv = (float4*)(y + (size_t)n * D);
            yv[2 * lane]     = make_float4(o[0], o[1], o[2], o[3]);
            yv[2 * lane + 1] = make_float4(o[4], o[5], o[6], o[7]);
            #pragma unroll
            for (int k = 0; k < 8; k++) { s1[k] += o[k]; s2[k] += o[k] * o[k]; }
        }
    }
    if (lane < 16) {
        int c0 = lane * 8;
        #pragma unroll
        for (int k = 0; k < 8; k++) {
            red[wid * 256 + c0 + k]       = s1[k];
            red[wid * 256 + 128 + c0 + k] = s2[k];
        }
    }
    __syncthreads();
    if (tid < 256) {
        float v = red[tid] + red[256 + tid] + red[512 + tid] + red[768 + tid];
        parts[(size_t)blockIdx.x * 256 + tid] = v;
    }
}

__global__ __launch_bounds__(256) void bn_fin2(
        const float* __restrict__ parts, const float* __restrict__ gamma,
        const float* __restrict__ beta, float* __restrict__ scsh) {
    __shared__ float rs1[256], rs2[256];
    int c = blockIdx.x, t = threadIdx.x;
    float s1 = 0.f, s2 = 0.f;
    for (int b = t; b < AGG_BLOCKS; b += 256) {
        s1 += parts[(size_t)b * 256 + c];
        s2 += parts[(size_t)b * 256 + 128 + c];
    }
    rs1[t] = s1; rs2[t] = s2;
    __syncthreads();
    for (int off = 128; off > 0; off >>= 1) {
        if (t < off) { rs1[t] += rs1[t + off]; rs2[t] += rs2[t + off]; }
        __syncthreads();
    }
    if (t == 0) {
        const float invN = 1.0f / (float)N_NODES;
        float mean = rs1[0] * invN;
        float var  = rs2[0] * invN - mean * mean;
        float sc = gamma[c] * rsqrtf(var + BN_EPS);
        scsh[c] = sc;
        scsh[128 + c] = beta[c] - mean * sc;
    }
}

__global__ void norm_kernel(float* __restrict__ y, const float* __restrict__ scsh) {
    int i = blockIdx.x * blockDim.x + threadIdx.x;
    if (i < N_NODES * 32) {
        float4 v = ((float4*)y)[i];
        int c = (i & 31) * 4;
        v.x = v.x * scsh[c]     + scsh[128 + c];
        v.y = v.y * scsh[c + 1] + scsh[128 + c + 1];
        v.z = v.z * scsh[c + 2] + scsh[128 + c + 2];
        v.w = v.w * scsh[c + 3] + scsh[128 + c + 3];
        ((float4*)y)[i] = v;
    }
}

extern "C" void kernel_launch(void* const* d_in, const int* in_sizes, int n_in,
                              void* d_out, int out_size, void* d_ws, size_t ws_size,
                              hipStream_t stream) {
    const float* x     = (const float*)d_in[0];
    const int*   src   = (const int*)d_in[1];
    const int*   dst   = (const int*)d_in[2];
    const float* W     = (const float*)d_in[3];
    const float* b     = (const float*)d_in[4];
    const float* Wr    = (const float*)d_in[5];
    const float* br    = (const float*)d_in[6];
    const float* gamma = (const float*)d_in[7];
    const float* beta  = (const float*)d_in[8];
    float* out = (float*)d_out;

    char* ws = (char*)d_ws;
    int*   cnt_in  = (int*)(ws + 0);
    int*   cnt_out = (int*)(ws + 262144);
    int*   row_ptr = (int*)(ws + 524288);
    float* rin     = (float*)(ws + 1048576);
    float* rout    = (float*)(ws + 1310720);
    float* scsh    = (float*)(ws + 1576960);
    int*   blk_sum = (int*)(ws + 1579008);
    int*   csr_src = (int*)(ws + 1581056);
    unsigned short* hwb = (unsigned short*)(ws + 4800000);
    float* parts   = (float*)(ws + 17600000);
    uint4* pW      = (uint4*)(ws + 19697152);
    uint4* pWr     = (uint4*)(ws + 19729920);
    unsigned int* histD = (unsigned int*)(ws + 19762688);
    unsigned int* histS = (unsigned int*)(ws + 26316288);
    unsigned short* resb = (unsigned short*)(ws + 19762688);  // overlays hists (dead after fill2)

    hist_kernel<<<dim3(CHUNKS, 2, 2), 256, 0, stream>>>(dst, src, histD, histS);
    merge_kernel<<<dim3(HALF_U32 / 256, 2, 2), 256, 0, stream>>>(histD, histS, cnt_in, cnt_out);
    scan1_kernel<<<SCAN_BLOCKS, 256, 0, stream>>>(cnt_in, row_ptr, blk_sum);
    scan2_kernel<<<1, 256, 0, stream>>>(blk_sum, row_ptr);
    scan3_kernel<<<SCAN_BLOCKS, 256, 0, stream>>>(cnt_in, cnt_out, blk_sum, row_ptr, rin, rout);
    fill2_kernel<<<CHUNKS, 512, 0, stream>>>(src, dst, row_ptr, histD, csr_src);
    pack_w<<<16, 256, 0, stream>>>(W, Wr, pW, pWr);
    gemm_mfma<<<(N_NODES + 63) / 64, 256, 0, stream>>>(x, pW, pWr, br, rout, hwb, resb);
    agg_kernel<<<AGG_BLOCKS, 256, 0, stream>>>((const unsigned int*)hwb, row_ptr, csr_src, rin, b, resb, out, parts);
    bn_fin2<<<128, 256, 0, stream>>>(parts, gamma, beta, scsh);
    norm_kernel<<<(N_NODES * 32 + 255) / 256, 256, 0, stream>>>(out, scsh);
}

// Round 10
// 238.999 us; speedup vs baseline: 3.5774x; 1.0308x over previous
//
#include <hip/hip_runtime.h>

#define N_NODES 50000
#define N_EDGES 800000
#define D 128
#define BN_EPS 1e-5f
#define AGG_BLOCKS 2048
#define SCAN_BLOCKS 196   // 196*256 = 50176 >= N_NODES
#define CHUNKS 64
#define EPC (N_EDGES / CHUNKS)   // 12500 edges per chunk (< 65536: u16-safe)
#define HALF_BINS 25600          // node-range half
#define HALF_U32 12800           // u32 words per half (2 bins/word)

typedef short bf16x8 __attribute__((ext_vector_type(8)));
typedef float f32x4  __attribute__((ext_vector_type(4)));
typedef unsigned int u32x4 __attribute__((ext_vector_type(4)));   // native vec for nontemporal builtins

// ---------------- workspace layout (bytes) ----------------
// cnt_in  @ 0        cnt_out @ 262144   row_ptr @ 524288
// rin     @ 1048576  rout    @ 1310720  scsh    @ 1576960  blk_sum @ 1579008
// csr_src @ 1581056 (3.2MB)  hwb(bf16 ushort[row][col]) @ 4800000 (12.8MB)
// parts   @ 17600000 (2MB)   pW @ 19697152 (32KB)  pWr @ 19729920 (32KB)
// histD   @ 19762688 (6.55MB)  histS @ 26316288 (6.55MB)  [end ~33.1MB]
// resb(bf16 residual, 12.8MB) overlays histD/histS @ 19762688 (dead after fill2)

__device__ __forceinline__ unsigned int pack_rne(float a, float b) {
    unsigned int ua = __float_as_uint(a); ua += 0x7fffu + ((ua >> 16) & 1u);
    unsigned int ub = __float_as_uint(b); ub += 0x7fffu + ((ub >> 16) & 1u);
    return (ua >> 16) | (ub & 0xffff0000u);
}
__device__ __forceinline__ unsigned short pack1_rne(float a) {
    unsigned int ua = __float_as_uint(a); ua += 0x7fffu + ((ua >> 16) & 1u);
    return (unsigned short)(ua >> 16);
}

// Privatized LDS histogram, both keys in one launch: grid (chunk[+pack], range, key).
// Blocks with x >= CHUNKS (y==0,z==0) do the W/Wr MFMA-fragment pre-pack instead.
__global__ __launch_bounds__(256) void hist_kernel(
        const int* __restrict__ dst, const int* __restrict__ src,
        unsigned int* __restrict__ histD, unsigned int* __restrict__ histS,
        const float* __restrict__ W, const float* __restrict__ Wr,
        uint4* __restrict__ pW, uint4* __restrict__ pWr) {
    __shared__ unsigned int h[HALF_U32];
    int tid = threadIdx.x;
    int c = blockIdx.x, r = blockIdx.y;
    if (c >= CHUNKS) {
        if (r != 0 || blockIdx.z != 0) return;
        // ---- pack_w work (16 blocks x 256 threads = 4096) ----
        int t = (c - CHUNKS) * 256 + tid;
        const float* S = (t & 2048) ? Wr : W;
        uint4* Dst     = (t & 2048) ? pWr : pW;
        int e = t & 2047;
        int lane = e & 63, ks = (e >> 6) & 3, ct = e >> 8;
        int n  = ct * 16 + (lane & 15);
        int k0 = ks * 32 + (lane >> 4) * 8;
        float v[8];
        #pragma unroll
        for (int j = 0; j < 8; j++) v[j] = S[(k0 + j) * D + n];
        uint4 rr;
        rr.x = pack_rne(v[0], v[1]); rr.y = pack_rne(v[2], v[3]);
        rr.z = pack_rne(v[4], v[5]); rr.w = pack_rne(v[6], v[7]);
        Dst[e] = rr;
        return;
    }
    const int* keys = blockIdx.z ? src : dst;
    unsigned int* hist = blockIdx.z ? histS : histD;
    for (int j = tid; j < HALF_U32; j += 256) h[j] = 0u;
    __syncthreads();
    int base = c * EPC;
    int lo = r * HALF_BINS;
    for (int i = tid; i < EPC; i += 256) {
        int b = keys[base + i] - lo;
        if ((unsigned)b < (unsigned)HALF_BINS)
            atomicAdd(&h[b >> 1], 1u << ((b & 1) * 16));
    }
    __syncthreads();
    unsigned int* out = hist + ((size_t)(r * CHUNKS + c)) * HALF_U32;
    for (int j = tid; j < HALF_U32; j += 256) out[j] = h[j];
}

// Sum per-chunk histograms -> cnt arrays, AND replace hist in place with the
// exclusive chunk-prefix per bin (packed u16: counting-sort base offsets).
__global__ __launch_bounds__(256) void merge_kernel(
        unsigned int* __restrict__ histD, unsigned int* __restrict__ histS,
        int* __restrict__ cnt_in, int* __restrict__ cnt_out) {
    int q = blockIdx.x * 256 + threadIdx.x;      // 0..12799
    int r = blockIdx.y;                           // range half
    unsigned int* hist = blockIdx.z ? histS : histD;
    int* cnt = blockIdx.z ? cnt_out : cnt_in;
    unsigned int lo = 0, hi = 0;
    for (int c = 0; c < CHUNKS; c++) {
        size_t idx = ((size_t)(r * CHUNKS + c)) * HALF_U32 + q;
        unsigned int v = hist[idx];
        hist[idx] = lo | (hi << 16);             // exclusive prefix (u16-safe)
        lo += v & 0xffffu; hi += v >> 16;
    }
    int n0 = r * HALF_BINS + q * 2;
    cnt[n0]     = (int)lo;
    cnt[n0 + 1] = (int)hi;
}

__global__ __launch_bounds__(256) void scan1_kernel(
        const int* __restrict__ cnt_in, int* __restrict__ row_ptr, int* __restrict__ blk_sum) {
    __shared__ int sh[256];
    int t = threadIdx.x;
    int i = blockIdx.x * 256 + t;
    int v = cnt_in[i];                 // merge writes bins 0..51199 >= 50176, safe
    sh[t] = v;
    __syncthreads();
    int inc = v;
    #pragma unroll
    for (int off = 1; off < 256; off <<= 1) {
        int u = (t >= off) ? sh[t - off] : 0;
        __syncthreads();
        inc += u; sh[t] = inc;
        __syncthreads();
    }
    row_ptr[i] = inc - v;
    if (t == 255) blk_sum[blockIdx.x] = inc;   // block TOTAL (scan3 re-scans)
}

// scan3: each block locally scans the 196 block totals (cheap), adds its
// exclusive offset, emits final row_ptr + rsqrt norms. scan2 launch eliminated.
__global__ __launch_bounds__(256) void scan3_kernel(
        const int* __restrict__ cnt_in, const int* __restrict__ cnt_out,
        const int* __restrict__ blk_sum, int* __restrict__ row_ptr,
        float* __restrict__ rin, float* __restrict__ rout) {
    __shared__ int sh[256];
    int t = threadIdx.x;
    int v = (t < SCAN_BLOCKS) ? blk_sum[t] : 0;
    sh[t] = v;
    __syncthreads();
    int inc = v;
    #pragma unroll
    for (int off = 1; off < 256; off <<= 1) {
        int u = (t >= off) ? sh[t - off] : 0;
        __syncthreads();
        inc += u; sh[t] = inc;
        __syncthreads();
    }
    int boff = (blockIdx.x == 0) ? 0 : sh[blockIdx.x - 1];
    int i = blockIdx.x * 256 + t;
    if (i < N_NODES) {
        row_ptr[i] = row_ptr[i] + boff;
        int ci = cnt_in[i], co = cnt_out[i];
        rin[i]  = rsqrtf((float)(ci > 1 ? ci : 1));
        rout[i] = rsqrtf((float)(co > 1 ? co : 1));
    }
    if (blockIdx.x == SCAN_BLOCKS - 1 && t == 0) row_ptr[N_NODES] = N_EDGES;
}

// Counting-sort CSR fill: LDS rank counters (atomic-return, packed u16),
// position = row_ptr[d] + chunk_prefix[c][d] + rank. NO global atomics.
__global__ __launch_bounds__(512) void fill2_kernel(
        const int* __restrict__ src, const int* __restrict__ dst,
        const int* __restrict__ row_ptr, const unsigned int* __restrict__ histP,
        int* __restrict__ csr_src) {
    __shared__ unsigned int h[HALF_U32];
    int tid = threadIdx.x;
    int c = blockIdx.x;
    int base = c * EPC;
    for (int r = 0; r < 2; r++) {
        for (int j = tid; j < HALF_U32; j += 512) h[j] = 0u;
        __syncthreads();
        int lo = r * HALF_BINS;
        const unsigned int* pre_c = histP + ((size_t)(r * CHUNKS + c)) * HALF_U32;
        for (int i = tid; i < EPC; i += 512) {
            int d = dst[base + i];
            int b = d - lo;
            if ((unsigned)b < (unsigned)HALF_BINS) {
                int sh = (b & 1) * 16;
                unsigned int old = atomicAdd(&h[b >> 1], 1u << sh);
                unsigned int rank = (old >> sh) & 0xffffu;
                unsigned int pre = (pre_c[b >> 1] >> sh) & 0xffffu;
                int p = row_ptr[d] + (int)(pre + rank);
                csr_src[p] = src[base + i];
            }
        }
        __syncthreads();
    }
}

// MFMA dual GEMM, coalesced A-staging through LDS (bf16).
// hwb = bf16(rout*(x@W)); resb = bf16(relu(x@Wr+br)). Both ushort[row][col].
__global__ __launch_bounds__(256) void gemm_mfma(
        const float* __restrict__ x, const uint4* __restrict__ pW,
        const uint4* __restrict__ pWr, const float* __restrict__ br,
        const float* __restrict__ rout, unsigned short* __restrict__ hwb,
        unsigned short* __restrict__ resb) {
    __shared__ unsigned short xs[64][136];       // +8 pad: row stride 272B -> 2-way banks (free)
    int tid = threadIdx.x, wid = tid >> 6, lane = tid & 63;
    int quad = lane >> 4, l15 = lane & 15;
    int r0b = blockIdx.x * 64;
    const float4* xg = (const float4*)(x + (size_t)r0b * D);
    int maxidx = (N_NODES - r0b) * (D / 4);
    #pragma unroll
    for (int i = 0; i < 8; i++) {
        int idx = tid + 256 * i;                 // coalesced float4 over 64 rows
        float4 v = (idx < maxidx) ? xg[idx] : make_float4(0.f, 0.f, 0.f, 0.f);
        int row = idx >> 5, c0 = (idx & 31) * 4;
        *(unsigned int*)&xs[row][c0]     = pack_rne(v.x, v.y);
        *(unsigned int*)&xs[row][c0 + 2] = pack_rne(v.z, v.w);
    }
    __syncthreads();
    int wrow0 = wid * 16;
    bf16x8 A[4];
    #pragma unroll
    for (int ks = 0; ks < 4; ks++)
        A[ks] = *(const bf16x8*)&xs[wrow0 + l15][ks * 32 + quad * 8];
    f32x4 accW[8], accR[8];
    #pragma unroll
    for (int ct = 0; ct < 8; ct++) { accW[ct] = (f32x4)0.f; accR[ct] = (f32x4)0.f; }
    #pragma unroll
    for (int ct = 0; ct < 8; ct++) {
        #pragma unroll
        for (int ks = 0; ks < 4; ks++) {
            union { bf16x8 v; uint4 u; } Bw, Br2;
            Bw.u  = pW [(ct * 4 + ks) * 64 + lane];
            Br2.u = pWr[(ct * 4 + ks) * 64 + lane];
            accW[ct] = __builtin_amdgcn_mfma_f32_16x16x32_bf16(A[ks], Bw.v,  accW[ct], 0, 0, 0);
            accR[ct] = __builtin_amdgcn_mfma_f32_16x16x32_bf16(A[ks], Br2.v, accR[ct], 0, 0, 0);
        }
    }
    // C/D layout: col = ct*16 + l15, row = r0 + quad*4 + reg
    int r0 = r0b + wrow0;
    float ro[4]; int rowok[4];
    #pragma unroll
    for (int reg = 0; reg < 4; reg++) {
        int row = r0 + quad * 4 + reg;
        rowok[reg] = row < N_NODES;
        ro[reg] = rout[rowok[reg] ? row : N_NODES - 1];
    }
    #pragma unroll
    for (int ct = 0; ct < 8; ct++) {
        int c = ct * 16 + l15;
        float brv = br[c];
        #pragma unroll
        for (int reg = 0; reg < 4; reg++) {
            int row = r0 + quad * 4 + reg;
            if (rowok[reg]) {
                hwb [(size_t)row * D + c] = pack1_rne(accW[ct][reg] * ro[reg]);
                resb[(size_t)row * D + c] = pack1_rne(fmaxf(accR[ct][reg] + brv, 0.f));
            }
        }
    }
}

__device__ __forceinline__ float bf_lo(unsigned int v) { return __uint_as_float(v << 16); }
__device__ __forceinline__ float bf_hi(unsigned int v) { return __uint_as_float(v & 0xffff0000u); }

__device__ __forceinline__ void acc8(float* a, const uint4 v) {
    a[0] += bf_lo(v.x); a[1] += bf_hi(v.x);
    a[2] += bf_lo(v.y); a[3] += bf_hi(v.y);
    a[4] += bf_lo(v.z); a[5] += bf_hi(v.z);
    a[6] += bf_lo(v.w); a[7] += bf_hi(v.w);
}
__device__ __forceinline__ void acc8m(float* a, const uint4 v, float m) {
    a[0] = fmaf(m, bf_lo(v.x), a[0]); a[1] = fmaf(m, bf_hi(v.x), a[1]);
    a[2] = fmaf(m, bf_lo(v.y), a[2]); a[3] = fmaf(m, bf_hi(v.y), a[3]);
    a[4] = fmaf(m, bf_lo(v.z), a[4]); a[5] = fmaf(m, bf_hi(v.z), a[5]);
    a[6] = fmaf(m, bf_lo(v.w), a[6]); a[7] = fmaf(m, bf_hi(v.w), a[7]);
}

__device__ __forceinline__ int sel4(int qg, int i0, int i1, int i2, int i3) {
    int a = (qg & 1) ? i1 : i0;
    int b = (qg & 1) ? i3 : i2;
    return (qg & 2) ? b : a;
}

// gather+accumulate one <=64-edge window (myidx preloaded per-lane indices)
__device__ __forceinline__ void gather_accum(
        const unsigned int* __restrict__ hwb, int myidx, int cnt,
        int qg, int ql, float* a) {
    int i = 0;
    for (; i + 16 <= cnt; i += 16) {
        int p0 = sel4(qg, __builtin_amdgcn_readlane(myidx, i + 0),
                          __builtin_amdgcn_readlane(myidx, i + 1),
                          __builtin_amdgcn_readlane(myidx, i + 2),
                          __builtin_amdgcn_readlane(myidx, i + 3));
        int p1 = sel4(qg, __builtin_amdgcn_readlane(myidx, i + 4),
                          __builtin_amdgcn_readlane(myidx, i + 5),
                          __builtin_amdgcn_readlane(myidx, i + 6),
                          __builtin_amdgcn_readlane(myidx, i + 7));
        int p2 = sel4(qg, __builtin_amdgcn_readlane(myidx, i + 8),
                          __builtin_amdgcn_readlane(myidx, i + 9),
                          __builtin_amdgcn_readlane(myidx, i + 10),
                          __builtin_amdgcn_readlane(myidx, i + 11));
        int p3 = sel4(qg, __builtin_amdgcn_readlane(myidx, i + 12),
                          __builtin_amdgcn_readlane(myidx, i + 13),
                          __builtin_amdgcn_readlane(myidx, i + 14),
                          __builtin_amdgcn_readlane(myidx, i + 15));
        uint4 v0 = *((const uint4*)(hwb + (size_t)p0 * 64) + ql);
        uint4 v1 = *((const uint4*)(hwb + (size_t)p1 * 64) + ql);
        uint4 v2 = *((const uint4*)(hwb + (size_t)p2 * 64) + ql);
        uint4 v3 = *((const uint4*)(hwb + (size_t)p3 * 64) + ql);
        acc8(a, v0); acc8(a, v1); acc8(a, v2); acc8(a, v3);
    }
    for (; i + 4 <= cnt; i += 4) {
        int p0 = sel4(qg, __builtin_amdgcn_readlane(myidx, i + 0),
                          __builtin_amdgcn_readlane(myidx, i + 1),
                          __builtin_amdgcn_readlane(myidx, i + 2),
                          __builtin_amdgcn_readlane(myidx, i + 3));
        uint4 v0 = *((const uint4*)(hwb + (size_t)p0 * 64) + ql);
        acc8(a, v0);
    }
    int t = cnt - i;
    if (t > 0) {
        int lim = cnt - 1;
        int j1 = i + 1 <= lim ? i + 1 : lim;
        int j2 = i + 2 <= lim ? i + 2 : lim;
        int p0 = sel4(qg, __builtin_amdgcn_readlane(myidx, i),
                          __builtin_amdgcn_readlane(myidx, j1),
                          __builtin_amdgcn_readlane(myidx, j2),
                          __builtin_amdgcn_readlane(myidx, lim));
        uint4 v0 = *((const uint4*)(hwb + (size_t)p0 * 64) + ql);
        float m = (qg < t) ? 1.f : 0.f;
        acc8m(a, v0, m);
    }
}

// Per-dst aggregation; 4 rows per gather instruction, no global atomics.
// 2-node software pipeline: next node's header (row_ptr, resb row, first csr
// window) is issued before the current node's gather/accumulate, hiding the
// ~800-cycle header dependency chain.
__global__ __launch_bounds__(256) void agg_kernel(
        const unsigned int* __restrict__ hwb, const int* __restrict__ row_ptr,
        const int* __restrict__ csr_src, const float* __restrict__ rin,
        const float* __restrict__ bias, const unsigned short* __restrict__ resb,
        float* __restrict__ y, float* __restrict__ parts) {
    __shared__ float red[4 * 256];
    int tid = threadIdx.x;
    int lane = tid & 63, wid = tid >> 6;
    int wave = blockIdx.x * 4 + wid;
    int nw = AGG_BLOCKS * 4;
    int qg = lane >> 4;
    int ql = lane & 15;
    float s1[8] = {0,0,0,0,0,0,0,0}, s2[8] = {0,0,0,0,0,0,0,0};
    float4 bv0, bv1;
    if (lane < 16) {
        bv0 = ((const float4*)bias)[2 * lane];
        bv1 = ((const float4*)bias)[2 * lane + 1];
    }
    // ---- preload first node's header ----
    int n = wave;
    int e0 = 0, e1 = 0, mi = 0;
    u32x4 rv4 = (u32x4)0u;
    float ri = 0.f;
    if (n < N_NODES) {
        e0 = row_ptr[n]; e1 = row_ptr[n + 1];
        ri = rin[n];
        if (lane < 16) rv4 = __builtin_nontemporal_load((const u32x4*)(resb + (size_t)n * D) + lane);
        int c0 = e1 - e0; if (c0 > 64) c0 = 64;
        mi = (lane < c0) ? __builtin_nontemporal_load(csr_src + e0 + lane) : 0;
    }
    while (n < N_NODES) {
        // ---- issue next node's header before gathering current ----
        int nn = n + nw;
        int ne0 = 0, ne1 = 0, nmi = 0;
        u32x4 nrv = (u32x4)0u;
        float nri = 0.f;
        if (nn < N_NODES) {
            ne0 = row_ptr[nn]; ne1 = row_ptr[nn + 1];
            nri = rin[nn];
            if (lane < 16) nrv = __builtin_nontemporal_load((const u32x4*)(resb + (size_t)nn * D) + lane);
            int nc = ne1 - ne0; if (nc > 64) nc = 64;
            nmi = (lane < nc) ? __builtin_nontemporal_load(csr_src + ne0 + lane) : 0;
        }
        // ---- gather/accumulate current node ----
        float a[8] = {0,0,0,0,0,0,0,0};
        {
            int cnt = e1 - e0; if (cnt > 64) cnt = 64;
            gather_accum(hwb, mi, cnt, qg, ql, a);
        }
        for (int j0 = e0 + 64; j0 < e1; j0 += 64) {
            int cnt = e1 - j0; if (cnt > 64) cnt = 64;
            int mw = (lane < cnt) ? __builtin_nontemporal_load(csr_src + j0 + lane) : 0;
            gather_accum(hwb, mw, cnt, qg, ql, a);
        }
        #pragma unroll
        for (int k = 0; k < 8; k++) {
            a[k] += __shfl_xor(a[k], 16);
            a[k] += __shfl_xor(a[k], 32);
        }
        if (lane < 16) {
            float o[8];
            o[0] = fmaxf(a[0] * ri + bv0.x, 0.f) + bf_lo(rv4.x);
            o[1] = fmaxf(a[1] * ri + bv0.y, 0.f) + bf_hi(rv4.x);
            o[2] = fmaxf(a[2] * ri + bv0.z, 0.f) + bf_lo(rv4.y);
            o[3] = fmaxf(a[3] * ri + bv0.w, 0.f) + bf_hi(rv4.y);
            o[4] = fmaxf(a[4] * ri + bv1.x, 0.f) + bf_lo(rv4.z);
            o[5] = fmaxf(a[5] * ri + bv1.y, 0.f) + bf_hi(rv4.z);
            o[6] = fmaxf(a[6] * ri + bv1.z, 0.f) + bf_lo(rv4.w);
            o[7] = fmaxf(a[7] * ri + bv1.w, 0.f) + bf_hi(rv4.w);
            float4* yv = (float4*)(y + (size_t)n * D);
            yv[2 * lane]     = make_float4(o[0], o[1], o[2], o[3]);
            yv[2 * lane + 1] = make_float4(o[4], o[5], o[6], o[7]);
            #pragma unroll
            for (int k = 0; k < 8; k++) { s1[k] += o[k]; s2[k] += o[k] * o[k]; }
        }
        n = nn; e0 = ne0; e1 = ne1; mi = nmi; rv4 = nrv; ri = nri;
    }
    if (lane < 16) {
        int c0 = lane * 8;
        #pragma unroll
        for (int k = 0; k < 8; k++) {
            red[wid * 256 + c0 + k]       = s1[k];
            red[wid * 256 + 128 + c0 + k] = s2[k];
        }
    }
    __syncthreads();
    if (tid < 256) {
        float v = red[tid] + red[256 + tid] + red[512 + tid] + red[768 + tid];
        parts[(size_t)blockIdx.x * 256 + tid] = v;
    }
}

__global__ __launch_bounds__(256) void bn_fin2(
        const float* __restrict__ parts, const float* __restrict__ gamma,
        const float* __restrict__ beta, float* __restrict__ scsh) {
    __shared__ float rs1[256], rs2[256];
    int c = blockIdx.x, t = threadIdx.x;
    float s1 = 0.f, s2 = 0.f;
    for (int b = t; b < AGG_BLOCKS; b += 256) {
        s1 += parts[(size_t)b * 256 + c];
        s2 += parts[(size_t)b * 256 + 128 + c];
    }
    rs1[t] = s1; rs2[t] = s2;
    __syncthreads();
    for (int off = 128; off > 0; off >>= 1) {
        if (t < off) { rs1[t] += rs1[t + off]; rs2[t] += rs2[t + off]; }
        __syncthreads();
    }
    if (t == 0) {
        const float invN = 1.0f / (float)N_NODES;
        float mean = rs1[0] * invN;
        float var  = rs2[0] * invN - mean * mean;
        float sc = gamma[c] * rsqrtf(var + BN_EPS);
        scsh[c] = sc;
        scsh[128 + c] = beta[c] - mean * sc;
    }
}

__global__ void norm_kernel(float* __restrict__ y, const float* __restrict__ scsh) {
    int i = blockIdx.x * blockDim.x + threadIdx.x;
    if (i < N_NODES * 32) {
        float4 v = ((float4*)y)[i];
        int c = (i & 31) * 4;
        v.x = v.x * scsh[c]     + scsh[128 + c];
        v.y = v.y * scsh[c + 1] + scsh[128 + c + 1];
        v.z = v.z * scsh[c + 2] + scsh[128 + c + 2];
        v.w = v.w * scsh[c + 3] + scsh[128 + c + 3];
        ((float4*)y)[i] = v;
    }
}

extern "C" void kernel_launch(void* const* d_in, const int* in_sizes, int n_in,
                              void* d_out, int out_size, void* d_ws, size_t ws_size,
                              hipStream_t stream) {
    const float* x     = (const float*)d_in[0];
    const int*   src   = (const int*)d_in[1];
    const int*   dst   = (const int*)d_in[2];
    const float* W     = (const float*)d_in[3];
    const float* b     = (const float*)d_in[4];
    const float* Wr    = (const float*)d_in[5];
    const float* br    = (const float*)d_in[6];
    const float* gamma = (const float*)d_in[7];
    const float* beta  = (const float*)d_in[8];
    float* out = (float*)d_out;

    char* ws = (char*)d_ws;
    int*   cnt_in  = (int*)(ws + 0);
    int*   cnt_out = (int*)(ws + 262144);
    int*   row_ptr = (int*)(ws + 524288);
    float* rin     = (float*)(ws + 1048576);
    float* rout    = (float*)(ws + 1310720);
    float* scsh    = (float*)(ws + 1576960);
    int*   blk_sum = (int*)(ws + 1579008);
    int*   csr_src = (int*)(ws + 1581056);
    unsigned short* hwb = (unsigned short*)(ws + 4800000);
    float* parts   = (float*)(ws + 17600000);
    uint4* pW      = (uint4*)(ws + 19697152);
    uint4* pWr     = (uint4*)(ws + 19729920);
    unsigned int* histD = (unsigned int*)(ws + 19762688);
    unsigned int* histS = (unsigned int*)(ws + 26316288);
    unsigned short* resb = (unsigned short*)(ws + 19762688);  // overlays hists (dead after fill2)

    hist_kernel<<<dim3(CHUNKS + 16, 2, 2), 256, 0, stream>>>(dst, src, histD, histS, W, Wr, pW, pWr);
    merge_kernel<<<dim3(HALF_U32 / 256, 2, 2), 256, 0, stream>>>(histD, histS, cnt_in, cnt_out);
    scan1_kernel<<<SCAN_BLOCKS, 256, 0, stream>>>(cnt_in, row_ptr, blk_sum);
    scan3_kernel<<<SCAN_BLOCKS, 256, 0, stream>>>(cnt_in, cnt_out, blk_sum, row_ptr, rin, rout);
    fill2_kernel<<<CHUNKS, 512, 0, stream>>>(src, dst, row_ptr, histD, csr_src);
    gemm_mfma<<<(N_NODES + 63) / 64, 256, 0, stream>>>(x, pW, pWr, br, rout, hwb, resb);
    agg_kernel<<<AGG_BLOCKS, 256, 0, stream>>>((const unsigned int*)hwb, row_ptr, csr_src, rin, b, resb, out, parts);
    bn_fin2<<<128, 256, 0, stream>>>(parts, gamma, beta, scsh);
    norm_kernel<<<(N_NODES * 32 + 255) / 256, 256, 0, stream>>>(out, scsh);
}

// Round 11
// 219.707 us; speedup vs baseline: 3.8915x; 1.0878x over previous
//
#include <hip/hip_runtime.h>

#define N_NODES 50000
#define N_EDGES 800000
#define D 128
#define BN_EPS 1e-5f
#define AGG_BLOCKS 2048
#define SCAN_BLOCKS 196   // 196*256 = 50176 >= N_NODES
#define CHUNKS 64
#define EPC (N_EDGES / CHUNKS)   // 12500 edges per chunk (< 65536: u16-safe)
#define HALF_BINS 25600          // node-range half
#define HALF_U32 12800           // u32 words per half (2 bins/word)

typedef short bf16x8 __attribute__((ext_vector_type(8)));
typedef float f32x4  __attribute__((ext_vector_type(4)));
typedef float f32x2  __attribute__((ext_vector_type(2)));
typedef unsigned int u32x4 __attribute__((ext_vector_type(4)));   // native vec for nontemporal builtins

// ---------------- workspace layout (bytes) ----------------
// cnt_in @0  cnt_out @262144  row_ptr @524288  rin @786432  rout @1048576
// scsh @1310720  blk_sum @1312768  csr_src @1576960 (3.2MB)
// hwb8(fp8 e4m3 [row][col]) @4800000 (6.4MB)   resb(bf16) @11200000 (12.8MB)
// yb(bf16 pre-BN y) @24000000 (12.8MB)  parts @36800000 (2.1MB)
// pW @38897152 (32KB)  pWr @38929920 (32KB)
// histD @38962688 (6.55MB)  histS @45516288 (6.55MB)  [end ~52MB]

__device__ __forceinline__ unsigned int pack_rne(float a, float b) {
    unsigned int ua = __float_as_uint(a); ua += 0x7fffu + ((ua >> 16) & 1u);
    unsigned int ub = __float_as_uint(b); ub += 0x7fffu + ((ub >> 16) & 1u);
    return (ua >> 16) | (ub & 0xffff0000u);
}
__device__ __forceinline__ unsigned short pack1_rne(float a) {
    unsigned int ua = __float_as_uint(a); ua += 0x7fffu + ((ua >> 16) & 1u);
    return (unsigned short)(ua >> 16);
}
__device__ __forceinline__ unsigned char pack1_fp8(float a) {
    unsigned int u = __builtin_amdgcn_cvt_pk_fp8_f32(a, a, 0, false);
    return (unsigned char)(u & 0xffu);
}

// Privatized LDS histogram, both keys in one launch: grid (chunk[+pack], range, key).
// Blocks with x >= CHUNKS (y==0,z==0) do the W/Wr MFMA-fragment pre-pack instead.
__global__ __launch_bounds__(256) void hist_kernel(
        const int* __restrict__ dst, const int* __restrict__ src,
        unsigned int* __restrict__ histD, unsigned int* __restrict__ histS,
        const float* __restrict__ W, const float* __restrict__ Wr,
        uint4* __restrict__ pW, uint4* __restrict__ pWr) {
    __shared__ unsigned int h[HALF_U32];
    int tid = threadIdx.x;
    int c = blockIdx.x, r = blockIdx.y;
    if (c >= CHUNKS) {
        if (r != 0 || blockIdx.z != 0) return;
        int t = (c - CHUNKS) * 256 + tid;
        const float* S = (t & 2048) ? Wr : W;
        uint4* Dst     = (t & 2048) ? pWr : pW;
        int e = t & 2047;
        int lane = e & 63, ks = (e >> 6) & 3, ct = e >> 8;
        int n  = ct * 16 + (lane & 15);
        int k0 = ks * 32 + (lane >> 4) * 8;
        float v[8];
        #pragma unroll
        for (int j = 0; j < 8; j++) v[j] = S[(k0 + j) * D + n];
        uint4 rr;
        rr.x = pack_rne(v[0], v[1]); rr.y = pack_rne(v[2], v[3]);
        rr.z = pack_rne(v[4], v[5]); rr.w = pack_rne(v[6], v[7]);
        Dst[e] = rr;
        return;
    }
    const int* keys = blockIdx.z ? src : dst;
    unsigned int* hist = blockIdx.z ? histS : histD;
    for (int j = tid; j < HALF_U32; j += 256) h[j] = 0u;
    __syncthreads();
    int base = c * EPC;
    int lo = r * HALF_BINS;
    for (int i = tid; i < EPC; i += 256) {
        int b = keys[base + i] - lo;
        if ((unsigned)b < (unsigned)HALF_BINS)
            atomicAdd(&h[b >> 1], 1u << ((b & 1) * 16));
    }
    __syncthreads();
    unsigned int* out = hist + ((size_t)(r * CHUNKS + c)) * HALF_U32;
    for (int j = tid; j < HALF_U32; j += 256) out[j] = h[j];
}

// Sum per-chunk histograms -> cnt arrays, AND replace hist in place with the
// exclusive chunk-prefix per bin (packed u16: counting-sort base offsets).
__global__ __launch_bounds__(256) void merge_kernel(
        unsigned int* __restrict__ histD, unsigned int* __restrict__ histS,
        int* __restrict__ cnt_in, int* __restrict__ cnt_out) {
    int q = blockIdx.x * 256 + threadIdx.x;      // 0..12799
    int r = blockIdx.y;                           // range half
    unsigned int* hist = blockIdx.z ? histS : histD;
    int* cnt = blockIdx.z ? cnt_out : cnt_in;
    unsigned int lo = 0, hi = 0;
    for (int c = 0; c < CHUNKS; c++) {
        size_t idx = ((size_t)(r * CHUNKS + c)) * HALF_U32 + q;
        unsigned int v = hist[idx];
        hist[idx] = lo | (hi << 16);             // exclusive prefix (u16-safe)
        lo += v & 0xffffu; hi += v >> 16;
    }
    int n0 = r * HALF_BINS + q * 2;
    cnt[n0]     = (int)lo;
    cnt[n0 + 1] = (int)hi;
}

__global__ __launch_bounds__(256) void scan1_kernel(
        const int* __restrict__ cnt_in, int* __restrict__ row_ptr, int* __restrict__ blk_sum) {
    __shared__ int sh[256];
    int t = threadIdx.x;
    int i = blockIdx.x * 256 + t;
    int v = cnt_in[i];                 // merge writes bins 0..51199 >= 50176, safe
    sh[t] = v;
    __syncthreads();
    int inc = v;
    #pragma unroll
    for (int off = 1; off < 256; off <<= 1) {
        int u = (t >= off) ? sh[t - off] : 0;
        __syncthreads();
        inc += u; sh[t] = inc;
        __syncthreads();
    }
    row_ptr[i] = inc - v;
    if (t == 255) blk_sum[blockIdx.x] = inc;   // block TOTAL (scan3 re-scans)
}

// scan3: each block locally scans the 196 block totals, adds its exclusive
// offset, emits final row_ptr + rsqrt norms. (scan2 launch eliminated.)
__global__ __launch_bounds__(256) void scan3_kernel(
        const int* __restrict__ cnt_in, const int* __restrict__ cnt_out,
        const int* __restrict__ blk_sum, int* __restrict__ row_ptr,
        float* __restrict__ rin, float* __restrict__ rout) {
    __shared__ int sh[256];
    int t = threadIdx.x;
    int v = (t < SCAN_BLOCKS) ? blk_sum[t] : 0;
    sh[t] = v;
    __syncthreads();
    int inc = v;
    #pragma unroll
    for (int off = 1; off < 256; off <<= 1) {
        int u = (t >= off) ? sh[t - off] : 0;
        __syncthreads();
        inc += u; sh[t] = inc;
        __syncthreads();
    }
    int boff = (blockIdx.x == 0) ? 0 : sh[blockIdx.x - 1];
    int i = blockIdx.x * 256 + t;
    if (i < N_NODES) {
        row_ptr[i] = row_ptr[i] + boff;
        int ci = cnt_in[i], co = cnt_out[i];
        rin[i]  = rsqrtf((float)(ci > 1 ? ci : 1));
        rout[i] = rsqrtf((float)(co > 1 ? co : 1));
    }
    if (blockIdx.x == SCAN_BLOCKS - 1 && t == 0) row_ptr[N_NODES] = N_EDGES;
}

// Counting-sort CSR fill, grid (chunk, range-half): LDS rank counters
// (atomic-return, packed u16). NO global atomics.
__global__ __launch_bounds__(512) void fill2_kernel(
        const int* __restrict__ src, const int* __restrict__ dst,
        const int* __restrict__ row_ptr, const unsigned int* __restrict__ histP,
        int* __restrict__ csr_src) {
    __shared__ unsigned int h[HALF_U32];
    int tid = threadIdx.x;
    int c = blockIdx.x, r = blockIdx.y;
    int base = c * EPC;
    for (int j = tid; j < HALF_U32; j += 512) h[j] = 0u;
    __syncthreads();
    int lo = r * HALF_BINS;
    const unsigned int* pre_c = histP + ((size_t)(r * CHUNKS + c)) * HALF_U32;
    for (int i = tid; i < EPC; i += 512) {
        int d = dst[base + i];
        int b = d - lo;
        if ((unsigned)b < (unsigned)HALF_BINS) {
            int sh = (b & 1) * 16;
            unsigned int old = atomicAdd(&h[b >> 1], 1u << sh);
            unsigned int rank = (old >> sh) & 0xffffu;
            unsigned int pre = (pre_c[b >> 1] >> sh) & 0xffffu;
            int p = row_ptr[d] + (int)(pre + rank);
            csr_src[p] = src[base + i];
        }
    }
}

// MFMA dual GEMM, coalesced A-staging through LDS (bf16).
// hwb8 = fp8e4m3(rout*(x@W)) [row][col]; resb = bf16(relu(x@Wr+br)).
__global__ __launch_bounds__(256) void gemm_mfma(
        const float* __restrict__ x, const uint4* __restrict__ pW,
        const uint4* __restrict__ pWr, const float* __restrict__ br,
        const float* __restrict__ rout, unsigned char* __restrict__ hwb8,
        unsigned short* __restrict__ resb) {
    __shared__ unsigned short xs[64][136];       // +8 pad: 2-way banks only (free)
    int tid = threadIdx.x, wid = tid >> 6, lane = tid & 63;
    int quad = lane >> 4, l15 = lane & 15;
    int r0b = blockIdx.x * 64;
    const float4* xg = (const float4*)(x + (size_t)r0b * D);
    int maxidx = (N_NODES - r0b) * (D / 4);
    #pragma unroll
    for (int i = 0; i < 8; i++) {
        int idx = tid + 256 * i;                 // coalesced float4 over 64 rows
        float4 v = (idx < maxidx) ? xg[idx] : make_float4(0.f, 0.f, 0.f, 0.f);
        int row = idx >> 5, c0 = (idx & 31) * 4;
        *(unsigned int*)&xs[row][c0]     = pack_rne(v.x, v.y);
        *(unsigned int*)&xs[row][c0 + 2] = pack_rne(v.z, v.w);
    }
    __syncthreads();
    int wrow0 = wid * 16;
    bf16x8 A[4];
    #pragma unroll
    for (int ks = 0; ks < 4; ks++)
        A[ks] = *(const bf16x8*)&xs[wrow0 + l15][ks * 32 + quad * 8];
    f32x4 accW[8], accR[8];
    #pragma unroll
    for (int ct = 0; ct < 8; ct++) { accW[ct] = (f32x4)0.f; accR[ct] = (f32x4)0.f; }
    #pragma unroll
    for (int ct = 0; ct < 8; ct++) {
        #pragma unroll
        for (int ks = 0; ks < 4; ks++) {
            union { bf16x8 v; uint4 u; } Bw, Br2;
            Bw.u  = pW [(ct * 4 + ks) * 64 + lane];
            Br2.u = pWr[(ct * 4 + ks) * 64 + lane];
            accW[ct] = __builtin_amdgcn_mfma_f32_16x16x32_bf16(A[ks], Bw.v,  accW[ct], 0, 0, 0);
            accR[ct] = __builtin_amdgcn_mfma_f32_16x16x32_bf16(A[ks], Br2.v, accR[ct], 0, 0, 0);
        }
    }
    // C/D layout: col = ct*16 + l15, row = r0 + quad*4 + reg
    int r0 = r0b + wrow0;
    float ro[4]; int rowok[4];
    #pragma unroll
    for (int reg = 0; reg < 4; reg++) {
        int row = r0 + quad * 4 + reg;
        rowok[reg] = row < N_NODES;
        ro[reg] = rout[rowok[reg] ? row : N_NODES - 1];
    }
    #pragma unroll
    for (int ct = 0; ct < 8; ct++) {
        int c = ct * 16 + l15;
        float brv = br[c];
        #pragma unroll
        for (int reg = 0; reg < 4; reg++) {
            int row = r0 + quad * 4 + reg;
            if (rowok[reg]) {
                hwb8[(size_t)row * D + c] = pack1_fp8(accW[ct][reg] * ro[reg]);
                resb[(size_t)row * D + c] = pack1_rne(fmaxf(accR[ct][reg] + brv, 0.f));
            }
        }
    }
}

__device__ __forceinline__ float bf_lo(unsigned int v) { return __uint_as_float(v << 16); }
__device__ __forceinline__ float bf_hi(unsigned int v) { return __uint_as_float(v & 0xffff0000u); }

__device__ __forceinline__ void acc8f8(float* a, const uint2 v) {
    f32x2 p0 = __builtin_amdgcn_cvt_pk_f32_fp8(v.x, false);
    f32x2 p1 = __builtin_amdgcn_cvt_pk_f32_fp8(v.x, true);
    f32x2 p2 = __builtin_amdgcn_cvt_pk_f32_fp8(v.y, false);
    f32x2 p3 = __builtin_amdgcn_cvt_pk_f32_fp8(v.y, true);
    a[0] += p0.x; a[1] += p0.y; a[2] += p1.x; a[3] += p1.y;
    a[4] += p2.x; a[5] += p2.y; a[6] += p3.x; a[7] += p3.y;
}
__device__ __forceinline__ void acc8f8m(float* a, const uint2 v, float m) {
    f32x2 p0 = __builtin_amdgcn_cvt_pk_f32_fp8(v.x, false);
    f32x2 p1 = __builtin_amdgcn_cvt_pk_f32_fp8(v.x, true);
    f32x2 p2 = __builtin_amdgcn_cvt_pk_f32_fp8(v.y, false);
    f32x2 p3 = __builtin_amdgcn_cvt_pk_f32_fp8(v.y, true);
    a[0] = fmaf(m, p0.x, a[0]); a[1] = fmaf(m, p0.y, a[1]);
    a[2] = fmaf(m, p1.x, a[2]); a[3] = fmaf(m, p1.y, a[3]);
    a[4] = fmaf(m, p2.x, a[4]); a[5] = fmaf(m, p2.y, a[5]);
    a[6] = fmaf(m, p3.x, a[6]); a[7] = fmaf(m, p3.y, a[7]);
}

__device__ __forceinline__ int sel4(int qg, int i0, int i1, int i2, int i3) {
    int a = (qg & 1) ? i1 : i0;
    int b = (qg & 1) ? i3 : i2;
    return (qg & 2) ? b : a;
}

// gather+accumulate one <=64-edge window (fp8 rows: 16 lanes x uint2 = 128B/row,
// 4 rows per 512B instruction)
__device__ __forceinline__ void gather_accum(
        const unsigned char* __restrict__ hwb8, int myidx, int cnt,
        int qg, int ql, float* a) {
    int i = 0;
    for (; i + 16 <= cnt; i += 16) {
        int p0 = sel4(qg, __builtin_amdgcn_readlane(myidx, i + 0),
                          __builtin_amdgcn_readlane(myidx, i + 1),
                          __builtin_amdgcn_readlane(myidx, i + 2),
                          __builtin_amdgcn_readlane(myidx, i + 3));
        int p1 = sel4(qg, __builtin_amdgcn_readlane(myidx, i + 4),
                          __builtin_amdgcn_readlane(myidx, i + 5),
                          __builtin_amdgcn_readlane(myidx, i + 6),
                          __builtin_amdgcn_readlane(myidx, i + 7));
        int p2 = sel4(qg, __builtin_amdgcn_readlane(myidx, i + 8),
                          __builtin_amdgcn_readlane(myidx, i + 9),
                          __builtin_amdgcn_readlane(myidx, i + 10),
                          __builtin_amdgcn_readlane(myidx, i + 11));
        int p3 = sel4(qg, __builtin_amdgcn_readlane(myidx, i + 12),
                          __builtin_amdgcn_readlane(myidx, i + 13),
                          __builtin_amdgcn_readlane(myidx, i + 14),
                          __builtin_amdgcn_readlane(myidx, i + 15));
        uint2 v0 = *((const uint2*)(hwb8 + (size_t)p0 * 128) + ql);
        uint2 v1 = *((const uint2*)(hwb8 + (size_t)p1 * 128) + ql);
        uint2 v2 = *((const uint2*)(hwb8 + (size_t)p2 * 128) + ql);
        uint2 v3 = *((const uint2*)(hwb8 + (size_t)p3 * 128) + ql);
        acc8f8(a, v0); acc8f8(a, v1); acc8f8(a, v2); acc8f8(a, v3);
    }
    for (; i + 4 <= cnt; i += 4) {
        int p0 = sel4(qg, __builtin_amdgcn_readlane(myidx, i + 0),
                          __builtin_amdgcn_readlane(myidx, i + 1),
                          __builtin_amdgcn_readlane(myidx, i + 2),
                          __builtin_amdgcn_readlane(myidx, i + 3));
        uint2 v0 = *((const uint2*)(hwb8 + (size_t)p0 * 128) + ql);
        acc8f8(a, v0);
    }
    int t = cnt - i;
    if (t > 0) {
        int lim = cnt - 1;
        int j1 = i + 1 <= lim ? i + 1 : lim;
        int j2 = i + 2 <= lim ? i + 2 : lim;
        int p0 = sel4(qg, __builtin_amdgcn_readlane(myidx, i),
                          __builtin_amdgcn_readlane(myidx, j1),
                          __builtin_amdgcn_readlane(myidx, j2),
                          __builtin_amdgcn_readlane(myidx, lim));
        uint2 v0 = *((const uint2*)(hwb8 + (size_t)p0 * 128) + ql);
        float m = (qg < t) ? 1.f : 0.f;
        acc8f8m(a, v0, m);
    }
}

// Per-dst aggregation (fp8 gathers), 2-node software pipeline, no global
// atomics. Writes pre-BN y as bf16 to yb.
__global__ __launch_bounds__(256) void agg_kernel(
        const unsigned char* __restrict__ hwb8, const int* __restrict__ row_ptr,
        const int* __restrict__ csr_src, const float* __restrict__ rin,
        const float* __restrict__ bias, const unsigned short* __restrict__ resb,
        unsigned short* __restrict__ yb, float* __restrict__ parts) {
    __shared__ float red[4 * 256];
    int tid = threadIdx.x;
    int lane = tid & 63, wid = tid >> 6;
    int wave = blockIdx.x * 4 + wid;
    int nw = AGG_BLOCKS * 4;
    int qg = lane >> 4;
    int ql = lane & 15;
    float s1[8] = {0,0,0,0,0,0,0,0}, s2[8] = {0,0,0,0,0,0,0,0};
    float4 bv0, bv1;
    if (lane < 16) {
        bv0 = ((const float4*)bias)[2 * lane];
        bv1 = ((const float4*)bias)[2 * lane + 1];
    }
    int n = wave;
    int e0 = 0, e1 = 0, mi = 0;
    u32x4 rv4 = (u32x4)0u;
    float ri = 0.f;
    if (n < N_NODES) {
        e0 = row_ptr[n]; e1 = row_ptr[n + 1];
        ri = rin[n];
        if (lane < 16) rv4 = __builtin_nontemporal_load((const u32x4*)(resb + (size_t)n * D) + lane);
        int c0 = e1 - e0; if (c0 > 64) c0 = 64;
        mi = (lane < c0) ? __builtin_nontemporal_load(csr_src + e0 + lane) : 0;
    }
    while (n < N_NODES) {
        int nn = n + nw;
        int ne0 = 0, ne1 = 0, nmi = 0;
        u32x4 nrv = (u32x4)0u;
        float nri = 0.f;
        if (nn < N_NODES) {
            ne0 = row_ptr[nn]; ne1 = row_ptr[nn + 1];
            nri = rin[nn];
            if (lane < 16) nrv = __builtin_nontemporal_load((const u32x4*)(resb + (size_t)nn * D) + lane);
            int nc = ne1 - ne0; if (nc > 64) nc = 64;
            nmi = (lane < nc) ? __builtin_nontemporal_load(csr_src + ne0 + lane) : 0;
        }
        float a[8] = {0,0,0,0,0,0,0,0};
        {
            int cnt = e1 - e0; if (cnt > 64) cnt = 64;
            gather_accum(hwb8, mi, cnt, qg, ql, a);
        }
        for (int j0 = e0 + 64; j0 < e1; j0 += 64) {
            int cnt = e1 - j0; if (cnt > 64) cnt = 64;
            int mw = (lane < cnt) ? __builtin_nontemporal_load(csr_src + j0 + lane) : 0;
            gather_accum(hwb8, mw, cnt, qg, ql, a);
        }
        #pragma unroll
        for (int k = 0; k < 8; k++) {
            a[k] += __shfl_xor(a[k], 16);
            a[k] += __shfl_xor(a[k], 32);
        }
        if (lane < 16) {
            float o[8];
            o[0] = fmaxf(a[0] * ri + bv0.x, 0.f) + bf_lo(rv4.x);
            o[1] = fmaxf(a[1] * ri + bv0.y, 0.f) + bf_hi(rv4.x);
            o[2] = fmaxf(a[2] * ri + bv0.z, 0.f) + bf_lo(rv4.y);
            o[3] = fmaxf(a[3] * ri + bv0.w, 0.f) + bf_hi(rv4.y);
            o[4] = fmaxf(a[4] * ri + bv1.x, 0.f) + bf_lo(rv4.z);
            o[5] = fmaxf(a[5] * ri + bv1.y, 0.f) + bf_hi(rv4.z);
            o[6] = fmaxf(a[6] * ri + bv1.z, 0.f) + bf_lo(rv4.w);
            o[7] = fmaxf(a[7] * ri + bv1.w, 0.f) + bf_hi(rv4.w);
            uint4 w;
            w.x = pack_rne(o[0], o[1]); w.y = pack_rne(o[2], o[3]);
            w.z = pack_rne(o[4], o[5]); w.w = pack_rne(o[6], o[7]);
            *((uint4*)(yb + (size_t)n * D) + lane) = w;
            #pragma unroll
            for (int k = 0; k < 8; k++) { s1[k] += o[k]; s2[k] += o[k] * o[k]; }
        }
        n = nn; e0 = ne0; e1 = ne1; mi = nmi; rv4 = nrv; ri = nri;
    }
    if (lane < 16) {
        int c0 = lane * 8;
        #pragma unroll
        for (int k = 0; k < 8; k++) {
            red[wid * 256 + c0 + k]       = s1[k];
            red[wid * 256 + 128 + c0 + k] = s2[k];
        }
    }
    __syncthreads();
    if (tid < 256) {
        float v = red[tid] + red[256 + tid] + red[512 + tid] + red[768 + tid];
        parts[(size_t)blockIdx.x * 256 + tid] = v;
    }
}

__global__ __launch_bounds__(256) void bn_fin2(
        const float* __restrict__ parts, const float* __restrict__ gamma,
        const float* __restrict__ beta, float* __restrict__ scsh) {
    __shared__ float rs1[256], rs2[256];
    int c = blockIdx.x, t = threadIdx.x;
    float s1 = 0.f, s2 = 0.f;
    for (int b = t; b < AGG_BLOCKS; b += 256) {
        s1 += parts[(size_t)b * 256 + c];
        s2 += parts[(size_t)b * 256 + 128 + c];
    }
    rs1[t] = s1; rs2[t] = s2;
    __syncthreads();
    for (int off = 128; off > 0; off >>= 1) {
        if (t < off) { rs1[t] += rs1[t + off]; rs2[t] += rs2[t + off]; }
        __syncthreads();
    }
    if (t == 0) {
        const float invN = 1.0f / (float)N_NODES;
        float mean = rs1[0] * invN;
        float var  = rs2[0] * invN - mean * mean;
        float sc = gamma[c] * rsqrtf(var + BN_EPS);
        scsh[c] = sc;
        scsh[128 + c] = beta[c] - mean * sc;
    }
}

// Read bf16 y, apply BN scale/shift, write fp32 out.
__global__ void norm_kernel(const unsigned short* __restrict__ yb,
                            const float* __restrict__ scsh, float* __restrict__ out) {
    int i = blockIdx.x * blockDim.x + threadIdx.x;   // 8-channel group
    if (i < N_NODES * 16) {
        uint4 v = ((const uint4*)yb)[i];
        int c = (i & 15) * 8;
        float4 o0, o1;
        o0.x = bf_lo(v.x) * scsh[c]     + scsh[128 + c];
        o0.y = bf_hi(v.x) * scsh[c + 1] + scsh[128 + c + 1];
        o0.z = bf_lo(v.y) * scsh[c + 2] + scsh[128 + c + 2];
        o0.w = bf_hi(v.y) * scsh[c + 3] + scsh[128 + c + 3];
        o1.x = bf_lo(v.z) * scsh[c + 4] + scsh[128 + c + 4];
        o1.y = bf_hi(v.z) * scsh[c + 5] + scsh[128 + c + 5];
        o1.z = bf_lo(v.w) * scsh[c + 6] + scsh[128 + c + 6];
        o1.w = bf_hi(v.w) * scsh[c + 7] + scsh[128 + c + 7];
        float4* ov = (float4*)out + (size_t)i * 2;
        ov[0] = o0; ov[1] = o1;
    }
}

extern "C" void kernel_launch(void* const* d_in, const int* in_sizes, int n_in,
                              void* d_out, int out_size, void* d_ws, size_t ws_size,
                              hipStream_t stream) {
    const float* x     = (const float*)d_in[0];
    const int*   src   = (const int*)d_in[1];
    const int*   dst   = (const int*)d_in[2];
    const float* W     = (const float*)d_in[3];
    const float* b     = (const float*)d_in[4];
    const float* Wr    = (const float*)d_in[5];
    const float* br    = (const float*)d_in[6];
    const float* gamma = (const float*)d_in[7];
    const float* beta  = (const float*)d_in[8];
    float* out = (float*)d_out;

    char* ws = (char*)d_ws;
    int*   cnt_in  = (int*)(ws + 0);
    int*   cnt_out = (int*)(ws + 262144);
    int*   row_ptr = (int*)(ws + 524288);
    float* rin     = (float*)(ws + 786432);
    float* rout    = (float*)(ws + 1048576);
    float* scsh    = (float*)(ws + 1310720);
    int*   blk_sum = (int*)(ws + 1312768);
    int*   csr_src = (int*)(ws + 1576960);
    unsigned char*  hwb8 = (unsigned char*)(ws + 4800000);
    unsigned short* resb = (unsigned short*)(ws + 11200000);
    unsigned short* yb   = (unsigned short*)(ws + 24000000);
    float* parts   = (float*)(ws + 36800000);
    uint4* pW      = (uint4*)(ws + 38897152);
    uint4* pWr     = (uint4*)(ws + 38929920);
    unsigned int* histD = (unsigned int*)(ws + 38962688);
    unsigned int* histS = (unsigned int*)(ws + 45516288);

    hist_kernel<<<dim3(CHUNKS + 16, 2, 2), 256, 0, stream>>>(dst, src, histD, histS, W, Wr, pW, pWr);
    merge_kernel<<<dim3(HALF_U32 / 256, 2, 2), 256, 0, stream>>>(histD, histS, cnt_in, cnt_out);
    scan1_kernel<<<SCAN_BLOCKS, 256, 0, stream>>>(cnt_in, row_ptr, blk_sum);
    scan3_kernel<<<SCAN_BLOCKS, 256, 0, stream>>>(cnt_in, cnt_out, blk_sum, row_ptr, rin, rout);
    fill2_kernel<<<dim3(CHUNKS, 2), 512, 0, stream>>>(src, dst, row_ptr, histD, csr_src);
    gemm_mfma<<<(N_NODES + 63) / 64, 256, 0, stream>>>(x, pW, pWr, br, rout, hwb8, resb);
    agg_kernel<<<AGG_BLOCKS, 256, 0, stream>>>(hwb8, row_ptr, csr_src, rin, b, resb, yb, parts);
    bn_fin2<<<128, 256, 0, stream>>>(parts, gamma, beta, scsh);
    norm_kernel<<<(N_NODES * 16 + 255) / 256, 256, 0, stream>>>(yb, scsh, out);
}

// Round 12
// 217.465 us; speedup vs baseline: 3.9316x; 1.0103x over previous
//
#include <hip/hip_runtime.h>

#define N_NODES 50000
#define N_EDGES 800000
#define D 128
#define BN_EPS 1e-5f
#define AGG_BLOCKS 2048
#define SCAN_BLOCKS 196   // 196*256 = 50176 >= N_NODES
#define CHUNKS 64
#define EPC (N_EDGES / CHUNKS)   // 12500 edges per chunk (< 65536: u16-safe)
#define HALF_BINS 25600          // node-range half
#define HALF_U32 12800           // u32 words per half (2 bins/word)

typedef short bf16x8 __attribute__((ext_vector_type(8)));
typedef float f32x4  __attribute__((ext_vector_type(4)));
typedef float f32x2  __attribute__((ext_vector_type(2)));
typedef unsigned int u32x4 __attribute__((ext_vector_type(4)));   // native vec for nontemporal builtins

// ---------------- workspace layout (bytes) ----------------
// cnt_in @0  cnt_out @262144  row_ptr @524288  rin @786432  rout @1048576
// scsh @1310720  blk_sum @1312768  csr_src @1576960 (3.2MB)
// hwb8(fp8 e4m3 [row][col]) @4800000 (6.4MB)   resb(bf16) @11200000 (12.8MB)
// yb(bf16 pre-BN y) @24000000 (12.8MB)  parts @36800000 (2.1MB)
// pW @38897152 (32KB)  pWr @38929920 (32KB)
// histD @38962688 (6.55MB)  histS @45516288 (6.55MB)  [end ~52MB]

__device__ __forceinline__ unsigned int pack_rne(float a, float b) {
    unsigned int ua = __float_as_uint(a); ua += 0x7fffu + ((ua >> 16) & 1u);
    unsigned int ub = __float_as_uint(b); ub += 0x7fffu + ((ub >> 16) & 1u);
    return (ua >> 16) | (ub & 0xffff0000u);
}
__device__ __forceinline__ unsigned short pack1_rne(float a) {
    unsigned int ua = __float_as_uint(a); ua += 0x7fffu + ((ua >> 16) & 1u);
    return (unsigned short)(ua >> 16);
}
__device__ __forceinline__ unsigned char pack1_fp8(float a) {
    unsigned int u = __builtin_amdgcn_cvt_pk_fp8_f32(a, a, 0, false);
    return (unsigned char)(u & 0xffu);
}

// Privatized LDS histogram, both keys in one launch: grid (chunk[+pack], range, key).
// Blocks with x >= CHUNKS (y==0,z==0) do the W/Wr MFMA-fragment pre-pack instead.
__global__ __launch_bounds__(256) void hist_kernel(
        const int* __restrict__ dst, const int* __restrict__ src,
        unsigned int* __restrict__ histD, unsigned int* __restrict__ histS,
        const float* __restrict__ W, const float* __restrict__ Wr,
        uint4* __restrict__ pW, uint4* __restrict__ pWr) {
    __shared__ unsigned int h[HALF_U32];
    int tid = threadIdx.x;
    int c = blockIdx.x, r = blockIdx.y;
    if (c >= CHUNKS) {
        if (r != 0 || blockIdx.z != 0) return;
        int t = (c - CHUNKS) * 256 + tid;
        const float* S = (t & 2048) ? Wr : W;
        uint4* Dst     = (t & 2048) ? pWr : pW;
        int e = t & 2047;
        int lane = e & 63, ks = (e >> 6) & 3, ct = e >> 8;
        int n  = ct * 16 + (lane & 15);
        int k0 = ks * 32 + (lane >> 4) * 8;
        float v[8];
        #pragma unroll
        for (int j = 0; j < 8; j++) v[j] = S[(k0 + j) * D + n];
        uint4 rr;
        rr.x = pack_rne(v[0], v[1]); rr.y = pack_rne(v[2], v[3]);
        rr.z = pack_rne(v[4], v[5]); rr.w = pack_rne(v[6], v[7]);
        Dst[e] = rr;
        return;
    }
    const int* keys = blockIdx.z ? src : dst;
    unsigned int* hist = blockIdx.z ? histS : histD;
    for (int j = tid; j < HALF_U32; j += 256) h[j] = 0u;
    __syncthreads();
    int base = c * EPC;
    int lo = r * HALF_BINS;
    for (int i = tid; i < EPC; i += 256) {
        int b = keys[base + i] - lo;
        if ((unsigned)b < (unsigned)HALF_BINS)
            atomicAdd(&h[b >> 1], 1u << ((b & 1) * 16));
    }
    __syncthreads();
    unsigned int* out = hist + ((size_t)(r * CHUNKS + c)) * HALF_U32;
    for (int j = tid; j < HALF_U32; j += 256) out[j] = h[j];
}

// Sum per-chunk histograms -> cnt arrays, AND replace hist in place with the
// exclusive chunk-prefix per bin (packed u16: counting-sort base offsets).
__global__ __launch_bounds__(256) void merge_kernel(
        unsigned int* __restrict__ histD, unsigned int* __restrict__ histS,
        int* __restrict__ cnt_in, int* __restrict__ cnt_out) {
    int q = blockIdx.x * 256 + threadIdx.x;      // 0..12799
    int r = blockIdx.y;                           // range half
    unsigned int* hist = blockIdx.z ? histS : histD;
    int* cnt = blockIdx.z ? cnt_out : cnt_in;
    unsigned int lo = 0, hi = 0;
    for (int c = 0; c < CHUNKS; c++) {
        size_t idx = ((size_t)(r * CHUNKS + c)) * HALF_U32 + q;
        unsigned int v = hist[idx];
        hist[idx] = lo | (hi << 16);             // exclusive prefix (u16-safe)
        lo += v & 0xffffu; hi += v >> 16;
    }
    int n0 = r * HALF_BINS + q * 2;
    cnt[n0]     = (int)lo;
    cnt[n0 + 1] = (int)hi;
}

__global__ __launch_bounds__(256) void scan1_kernel(
        const int* __restrict__ cnt_in, int* __restrict__ row_ptr, int* __restrict__ blk_sum) {
    __shared__ int sh[256];
    int t = threadIdx.x;
    int i = blockIdx.x * 256 + t;
    int v = cnt_in[i];                 // merge writes bins 0..51199 >= 50176, safe
    sh[t] = v;
    __syncthreads();
    int inc = v;
    #pragma unroll
    for (int off = 1; off < 256; off <<= 1) {
        int u = (t >= off) ? sh[t - off] : 0;
        __syncthreads();
        inc += u; sh[t] = inc;
        __syncthreads();
    }
    row_ptr[i] = inc - v;
    if (t == 255) blk_sum[blockIdx.x] = inc;   // block TOTAL (scan3 re-scans)
}

// scan3: each block locally scans the 196 block totals, adds its exclusive
// offset, emits final row_ptr + rsqrt norms. (scan2 launch eliminated.)
__global__ __launch_bounds__(256) void scan3_kernel(
        const int* __restrict__ cnt_in, const int* __restrict__ cnt_out,
        const int* __restrict__ blk_sum, int* __restrict__ row_ptr,
        float* __restrict__ rin, float* __restrict__ rout) {
    __shared__ int sh[256];
    int t = threadIdx.x;
    int v = (t < SCAN_BLOCKS) ? blk_sum[t] : 0;
    sh[t] = v;
    __syncthreads();
    int inc = v;
    #pragma unroll
    for (int off = 1; off < 256; off <<= 1) {
        int u = (t >= off) ? sh[t - off] : 0;
        __syncthreads();
        inc += u; sh[t] = inc;
        __syncthreads();
    }
    int boff = (blockIdx.x == 0) ? 0 : sh[blockIdx.x - 1];
    int i = blockIdx.x * 256 + t;
    if (i < N_NODES) {
        row_ptr[i] = row_ptr[i] + boff;
        int ci = cnt_in[i], co = cnt_out[i];
        rin[i]  = rsqrtf((float)(ci > 1 ? ci : 1));
        rout[i] = rsqrtf((float)(co > 1 ? co : 1));
    }
    if (blockIdx.x == SCAN_BLOCKS - 1 && t == 0) row_ptr[N_NODES] = N_EDGES;
}

// Counting-sort CSR fill, grid (chunk, range-half): LDS rank counters
// (atomic-return, packed u16). NO global atomics.
__global__ __launch_bounds__(512) void fill2_kernel(
        const int* __restrict__ src, const int* __restrict__ dst,
        const int* __restrict__ row_ptr, const unsigned int* __restrict__ histP,
        int* __restrict__ csr_src) {
    __shared__ unsigned int h[HALF_U32];
    int tid = threadIdx.x;
    int c = blockIdx.x, r = blockIdx.y;
    int base = c * EPC;
    for (int j = tid; j < HALF_U32; j += 512) h[j] = 0u;
    __syncthreads();
    int lo = r * HALF_BINS;
    const unsigned int* pre_c = histP + ((size_t)(r * CHUNKS + c)) * HALF_U32;
    for (int i = tid; i < EPC; i += 512) {
        int d = dst[base + i];
        int b = d - lo;
        if ((unsigned)b < (unsigned)HALF_BINS) {
            int sh = (b & 1) * 16;
            unsigned int old = atomicAdd(&h[b >> 1], 1u << sh);
            unsigned int rank = (old >> sh) & 0xffffu;
            unsigned int pre = (pre_c[b >> 1] >> sh) & 0xffffu;
            int p = row_ptr[d] + (int)(pre + rank);
            csr_src[p] = src[base + i];
        }
    }
}

// MFMA dual GEMM, coalesced A-staging through LDS (bf16).
// hwb8 = fp8e4m3(rout*(x@W)) [row][col]; resb = bf16(relu(x@Wr+br)).
__global__ __launch_bounds__(256) void gemm_mfma(
        const float* __restrict__ x, const uint4* __restrict__ pW,
        const uint4* __restrict__ pWr, const float* __restrict__ br,
        const float* __restrict__ rout, unsigned char* __restrict__ hwb8,
        unsigned short* __restrict__ resb) {
    __shared__ unsigned short xs[64][136];       // +8 pad: 2-way banks only (free)
    int tid = threadIdx.x, wid = tid >> 6, lane = tid & 63;
    int quad = lane >> 4, l15 = lane & 15;
    int r0b = blockIdx.x * 64;
    const float4* xg = (const float4*)(x + (size_t)r0b * D);
    int maxidx = (N_NODES - r0b) * (D / 4);
    #pragma unroll
    for (int i = 0; i < 8; i++) {
        int idx = tid + 256 * i;                 // coalesced float4 over 64 rows
        float4 v = (idx < maxidx) ? xg[idx] : make_float4(0.f, 0.f, 0.f, 0.f);
        int row = idx >> 5, c0 = (idx & 31) * 4;
        *(unsigned int*)&xs[row][c0]     = pack_rne(v.x, v.y);
        *(unsigned int*)&xs[row][c0 + 2] = pack_rne(v.z, v.w);
    }
    __syncthreads();
    int wrow0 = wid * 16;
    bf16x8 A[4];
    #pragma unroll
    for (int ks = 0; ks < 4; ks++)
        A[ks] = *(const bf16x8*)&xs[wrow0 + l15][ks * 32 + quad * 8];
    f32x4 accW[8], accR[8];
    #pragma unroll
    for (int ct = 0; ct < 8; ct++) { accW[ct] = (f32x4)0.f; accR[ct] = (f32x4)0.f; }
    #pragma unroll
    for (int ct = 0; ct < 8; ct++) {
        #pragma unroll
        for (int ks = 0; ks < 4; ks++) {
            union { bf16x8 v; uint4 u; } Bw, Br2;
            Bw.u  = pW [(ct * 4 + ks) * 64 + lane];
            Br2.u = pWr[(ct * 4 + ks) * 64 + lane];
            accW[ct] = __builtin_amdgcn_mfma_f32_16x16x32_bf16(A[ks], Bw.v,  accW[ct], 0, 0, 0);
            accR[ct] = __builtin_amdgcn_mfma_f32_16x16x32_bf16(A[ks], Br2.v, accR[ct], 0, 0, 0);
        }
    }
    // C/D layout: col = ct*16 + l15, row = r0 + quad*4 + reg
    int r0 = r0b + wrow0;
    float ro[4]; int rowok[4];
    #pragma unroll
    for (int reg = 0; reg < 4; reg++) {
        int row = r0 + quad * 4 + reg;
        rowok[reg] = row < N_NODES;
        ro[reg] = rout[rowok[reg] ? row : N_NODES - 1];
    }
    #pragma unroll
    for (int ct = 0; ct < 8; ct++) {
        int c = ct * 16 + l15;
        float brv = br[c];
        #pragma unroll
        for (int reg = 0; reg < 4; reg++) {
            int row = r0 + quad * 4 + reg;
            if (rowok[reg]) {
                hwb8[(size_t)row * D + c] = pack1_fp8(accW[ct][reg] * ro[reg]);
                resb[(size_t)row * D + c] = pack1_rne(fmaxf(accR[ct][reg] + brv, 0.f));
            }
        }
    }
}

__device__ __forceinline__ float bf_lo(unsigned int v) { return __uint_as_float(v << 16); }
__device__ __forceinline__ float bf_hi(unsigned int v) { return __uint_as_float(v & 0xffff0000u); }

// packed f32x2 accumulate of 8 fp8 values (4 cvt + 4 pk_add)
__device__ __forceinline__ void acc8f8(f32x2* a, const uint2 v) {
    a[0] += __builtin_amdgcn_cvt_pk_f32_fp8(v.x, false);
    a[1] += __builtin_amdgcn_cvt_pk_f32_fp8(v.x, true);
    a[2] += __builtin_amdgcn_cvt_pk_f32_fp8(v.y, false);
    a[3] += __builtin_amdgcn_cvt_pk_f32_fp8(v.y, true);
}
__device__ __forceinline__ void acc8f8m(f32x2* a, const uint2 v, float m) {
    f32x2 m2 = {m, m};
    a[0] += m2 * __builtin_amdgcn_cvt_pk_f32_fp8(v.x, false);
    a[1] += m2 * __builtin_amdgcn_cvt_pk_f32_fp8(v.x, true);
    a[2] += m2 * __builtin_amdgcn_cvt_pk_f32_fp8(v.y, false);
    a[3] += m2 * __builtin_amdgcn_cvt_pk_f32_fp8(v.y, true);
}

// gather+accumulate one <=64-edge window. Index broadcast: lane takes edge
// (i + qg) via ONE __shfl (ds_bpermute) per 4-edge group — replaces the
// readlane+cndmask select tree. fp8 rows: 16 lanes x uint2 = 128B/row.
__device__ __forceinline__ void gather_accum(
        const unsigned char* __restrict__ hwb8, int myidx, int cnt,
        int qg, int ql, f32x2* a) {
    int i = 0;
    for (; i + 16 <= cnt; i += 16) {
        int p0 = __shfl(myidx, i + qg);
        int p1 = __shfl(myidx, i + 4 + qg);
        int p2 = __shfl(myidx, i + 8 + qg);
        int p3 = __shfl(myidx, i + 12 + qg);
        uint2 v0 = *((const uint2*)(hwb8 + (size_t)p0 * 128) + ql);
        uint2 v1 = *((const uint2*)(hwb8 + (size_t)p1 * 128) + ql);
        uint2 v2 = *((const uint2*)(hwb8 + (size_t)p2 * 128) + ql);
        uint2 v3 = *((const uint2*)(hwb8 + (size_t)p3 * 128) + ql);
        acc8f8(a, v0); acc8f8(a, v1); acc8f8(a, v2); acc8f8(a, v3);
    }
    for (; i + 4 <= cnt; i += 4) {
        int p0 = __shfl(myidx, i + qg);
        uint2 v0 = *((const uint2*)(hwb8 + (size_t)p0 * 128) + ql);
        acc8f8(a, v0);
    }
    int t = cnt - i;
    if (t > 0) {
        int j = i + qg; if (j > cnt - 1) j = cnt - 1;
        int p0 = __shfl(myidx, j);
        uint2 v0 = *((const uint2*)(hwb8 + (size_t)p0 * 128) + ql);
        float m = (qg < t) ? 1.f : 0.f;
        acc8f8m(a, v0, m);
    }
}

// Per-dst aggregation (fp8 gathers), 2-node software pipeline, no global
// atomics. Writes pre-BN y as bf16 to yb.
__global__ __launch_bounds__(256) void agg_kernel(
        const unsigned char* __restrict__ hwb8, const int* __restrict__ row_ptr,
        const int* __restrict__ csr_src, const float* __restrict__ rin,
        const float* __restrict__ bias, const unsigned short* __restrict__ resb,
        unsigned short* __restrict__ yb, float* __restrict__ parts) {
    __shared__ float red[4 * 256];
    int tid = threadIdx.x;
    int lane = tid & 63, wid = tid >> 6;
    int wave = blockIdx.x * 4 + wid;
    int nw = AGG_BLOCKS * 4;
    int qg = lane >> 4;
    int ql = lane & 15;
    float s1[8] = {0,0,0,0,0,0,0,0}, s2[8] = {0,0,0,0,0,0,0,0};
    float4 bv0, bv1;
    if (lane < 16) {
        bv0 = ((const float4*)bias)[2 * lane];
        bv1 = ((const float4*)bias)[2 * lane + 1];
    }
    int n = wave;
    int e0 = 0, e1 = 0, mi = 0;
    u32x4 rv4 = (u32x4)0u;
    float ri = 0.f;
    if (n < N_NODES) {
        e0 = row_ptr[n]; e1 = row_ptr[n + 1];
        ri = rin[n];
        if (lane < 16) rv4 = __builtin_nontemporal_load((const u32x4*)(resb + (size_t)n * D) + lane);
        int c0 = e1 - e0; if (c0 > 64) c0 = 64;
        mi = (lane < c0) ? __builtin_nontemporal_load(csr_src + e0 + lane) : 0;
    }
    while (n < N_NODES) {
        int nn = n + nw;
        int ne0 = 0, ne1 = 0, nmi = 0;
        u32x4 nrv = (u32x4)0u;
        float nri = 0.f;
        if (nn < N_NODES) {
            ne0 = row_ptr[nn]; ne1 = row_ptr[nn + 1];
            nri = rin[nn];
            if (lane < 16) nrv = __builtin_nontemporal_load((const u32x4*)(resb + (size_t)nn * D) + lane);
            int nc = ne1 - ne0; if (nc > 64) nc = 64;
            nmi = (lane < nc) ? __builtin_nontemporal_load(csr_src + ne0 + lane) : 0;
        }
        f32x2 av[4];
        av[0] = (f32x2)0.f; av[1] = (f32x2)0.f; av[2] = (f32x2)0.f; av[3] = (f32x2)0.f;
        {
            int cnt = e1 - e0; if (cnt > 64) cnt = 64;
            gather_accum(hwb8, mi, cnt, qg, ql, av);
        }
        for (int j0 = e0 + 64; j0 < e1; j0 += 64) {
            int cnt = e1 - j0; if (cnt > 64) cnt = 64;
            int mw = (lane < cnt) ? __builtin_nontemporal_load(csr_src + j0 + lane) : 0;
            gather_accum(hwb8, mw, cnt, qg, ql, av);
        }
        float a[8] = { av[0].x, av[0].y, av[1].x, av[1].y, av[2].x, av[2].y, av[3].x, av[3].y };
        #pragma unroll
        for (int k = 0; k < 8; k++) {
            a[k] += __shfl_xor(a[k], 16);
            a[k] += __shfl_xor(a[k], 32);
        }
        if (lane < 16) {
            float o[8];
            o[0] = fmaxf(a[0] * ri + bv0.x, 0.f) + bf_lo(rv4.x);
            o[1] = fmaxf(a[1] * ri + bv0.y, 0.f) + bf_hi(rv4.x);
            o[2] = fmaxf(a[2] * ri + bv0.z, 0.f) + bf_lo(rv4.y);
            o[3] = fmaxf(a[3] * ri + bv0.w, 0.f) + bf_hi(rv4.y);
            o[4] = fmaxf(a[4] * ri + bv1.x, 0.f) + bf_lo(rv4.z);
            o[5] = fmaxf(a[5] * ri + bv1.y, 0.f) + bf_hi(rv4.z);
            o[6] = fmaxf(a[6] * ri + bv1.z, 0.f) + bf_lo(rv4.w);
            o[7] = fmaxf(a[7] * ri + bv1.w, 0.f) + bf_hi(rv4.w);
            uint4 w;
            w.x = pack_rne(o[0], o[1]); w.y = pack_rne(o[2], o[3]);
            w.z = pack_rne(o[4], o[5]); w.w = pack_rne(o[6], o[7]);
            *((uint4*)(yb + (size_t)n * D) + lane) = w;
            #pragma unroll
            for (int k = 0; k < 8; k++) { s1[k] += o[k]; s2[k] += o[k] * o[k]; }
        }
        n = nn; e0 = ne0; e1 = ne1; mi = nmi; rv4 = nrv; ri = nri;
    }
    if (lane < 16) {
        int c0 = lane * 8;
        #pragma unroll
        for (int k = 0; k < 8; k++) {
            red[wid * 256 + c0 + k]       = s1[k];
            red[wid * 256 + 128 + c0 + k] = s2[k];
        }
    }
    __syncthreads();
    if (tid < 256) {
        float v = red[tid] + red[256 + tid] + red[512 + tid] + red[768 + tid];
        parts[(size_t)blockIdx.x * 256 + tid] = v;
    }
}

__global__ __launch_bounds__(256) void bn_fin2(
        const float* __restrict__ parts, const float* __restrict__ gamma,
        const float* __restrict__ beta, float* __restrict__ scsh) {
    __shared__ float rs1[256], rs2[256];
    int c = blockIdx.x, t = threadIdx.x;
    float s1 = 0.f, s2 = 0.f;
    for (int b = t; b < AGG_BLOCKS; b += 256) {
        s1 += parts[(size_t)b * 256 + c];
        s2 += parts[(size_t)b * 256 + 128 + c];
    }
    rs1[t] = s1; rs2[t] = s2;
    __syncthreads();
    for (int off = 128; off > 0; off >>= 1) {
        if (t < off) { rs1[t] += rs1[t + off]; rs2[t] += rs2[t + off]; }
        __syncthreads();
    }
    if (t == 0) {
        const float invN = 1.0f / (float)N_NODES;
        float mean = rs1[0] * invN;
        float var  = rs2[0] * invN - mean * mean;
        float sc = gamma[c] * rsqrtf(var + BN_EPS);
        scsh[c] = sc;
        scsh[128 + c] = beta[c] - mean * sc;
    }
}

// Read bf16 y, apply BN scale/shift, write fp32 out (nontemporal).
__global__ void norm_kernel(const unsigned short* __restrict__ yb,
                            const float* __restrict__ scsh, float* __restrict__ out) {
    int i = blockIdx.x * blockDim.x + threadIdx.x;   // 8-channel group
    if (i < N_NODES * 16) {
        uint4 v = ((const uint4*)yb)[i];
        int c = (i & 15) * 8;
        f32x4 o0, o1;
        o0[0] = bf_lo(v.x) * scsh[c]     + scsh[128 + c];
        o0[1] = bf_hi(v.x) * scsh[c + 1] + scsh[128 + c + 1];
        o0[2] = bf_lo(v.y) * scsh[c + 2] + scsh[128 + c + 2];
        o0[3] = bf_hi(v.y) * scsh[c + 3] + scsh[128 + c + 3];
        o1[0] = bf_lo(v.z) * scsh[c + 4] + scsh[128 + c + 4];
        o1[1] = bf_hi(v.z) * scsh[c + 5] + scsh[128 + c + 5];
        o1[2] = bf_lo(v.w) * scsh[c + 6] + scsh[128 + c + 6];
        o1[3] = bf_hi(v.w) * scsh[c + 7] + scsh[128 + c + 7];
        f32x4* ov = (f32x4*)out + (size_t)i * 2;
        __builtin_nontemporal_store(o0, ov);
        __builtin_nontemporal_store(o1, ov + 1);
    }
}

extern "C" void kernel_launch(void* const* d_in, const int* in_sizes, int n_in,
                              void* d_out, int out_size, void* d_ws, size_t ws_size,
                              hipStream_t stream) {
    const float* x     = (const float*)d_in[0];
    const int*   src   = (const int*)d_in[1];
    const int*   dst   = (const int*)d_in[2];
    const float* W     = (const float*)d_in[3];
    const float* b     = (const float*)d_in[4];
    const float* Wr    = (const float*)d_in[5];
    const float* br    = (const float*)d_in[6];
    const float* gamma = (const float*)d_in[7];
    const float* beta  = (const float*)d_in[8];
    float* out = (float*)d_out;

    char* ws = (char*)d_ws;
    int*   cnt_in  = (int*)(ws + 0);
    int*   cnt_out = (int*)(ws + 262144);
    int*   row_ptr = (int*)(ws + 524288);
    float* rin     = (float*)(ws + 786432);
    float* rout    = (float*)(ws + 1048576);
    float* scsh    = (float*)(ws + 1310720);
    int*   blk_sum = (int*)(ws + 1312768);
    int*   csr_src = (int*)(ws + 1576960);
    unsigned char*  hwb8 = (unsigned char*)(ws + 4800000);
    unsigned short* resb = (unsigned short*)(ws + 11200000);
    unsigned short* yb   = (unsigned short*)(ws + 24000000);
    float* parts   = (float*)(ws + 36800000);
    uint4* pW      = (uint4*)(ws + 38897152);
    uint4* pWr     = (uint4*)(ws + 38929920);
    unsigned int* histD = (unsigned int*)(ws + 38962688);
    unsigned int* histS = (unsigned int*)(ws + 45516288);

    hist_kernel<<<dim3(CHUNKS + 16, 2, 2), 256, 0, stream>>>(dst, src, histD, histS, W, Wr, pW, pWr);
    merge_kernel<<<dim3(HALF_U32 / 256, 2, 2), 256, 0, stream>>>(histD, histS, cnt_in, cnt_out);
    scan1_kernel<<<SCAN_BLOCKS, 256, 0, stream>>>(cnt_in, row_ptr, blk_sum);
    scan3_kernel<<<SCAN_BLOCKS, 256, 0, stream>>>(cnt_in, cnt_out, blk_sum, row_ptr, rin, rout);
    fill2_kernel<<<dim3(CHUNKS, 2), 512, 0, stream>>>(src, dst, row_ptr, histD, csr_src);
    gemm_mfma<<<(N_NODES + 63) / 64, 256, 0, stream>>>(x, pW, pWr, br, rout, hwb8, resb);
    agg_kernel<<<AGG_BLOCKS, 256, 0, stream>>>(hwb8, row_ptr, csr_src, rin, b, resb, yb, parts);
    bn_fin2<<<128, 256, 0, stream>>>(parts, gamma, beta, scsh);
    norm_kernel<<<(N_NODES * 16 + 255) / 256, 256, 0, stream>>>(yb, scsh, out);
}